// Round 1
// baseline (1432.205 us; speedup 1.0000x reference)
//
#include <hip/hip_runtime.h>
#include <cstdint>
#include <cstddef>

typedef _Float16 f16;
typedef _Float16 f16x8 __attribute__((ext_vector_type(8)));
typedef float    f32x4 __attribute__((ext_vector_type(4)));

// ---------------- problem constants ----------------
constexpr int BATCH  = 128;
constexpr int NTOKC  = 197;
constexpr int TTOK   = BATCH * NTOKC;     // 25216
constexpr int MPATCH = BATCH * 196;       // 25088
constexpr int EMB    = 384;
constexpr int HID    = 1536;
constexpr int QKVD   = 1152;
constexpr int CHROWS = 12608;             // TTOK/2 (qkv batch-chunk rows)

// ---------------- workspace layout (bytes) ----------------
constexpr size_t SZ_CONVW   = (size_t)384 * 768 * 2;
constexpr size_t SZ_INPW    = (size_t)1152 * 384 * 2;
constexpr size_t SZ_OUTPW   = (size_t)384 * 384 * 2;
constexpr size_t SZ_EWT     = (size_t)4 * 1536 * 384 * 2;
constexpr size_t SZ_MASKW   = (size_t)TTOK * 4 * 4;
constexpr size_t SZ_TE_F32  = (size_t)TTOK * EMB * 4;   // 38,731,776
constexpr size_t SZ_TE_F16  = (size_t)TTOK * EMB * 2;   // 19,365,888
constexpr size_t SZ_EH      = (size_t)TTOK * HID * 2;   // 77,463,552 (>= qkv chunk 58,097,664)

constexpr size_t OFF_CONVW_HI = 0;
constexpr size_t OFF_CONVW_LO = OFF_CONVW_HI + SZ_CONVW;
constexpr size_t OFF_INPW_HI  = OFF_CONVW_LO + SZ_CONVW;
constexpr size_t OFF_INPW_LO  = OFF_INPW_HI + SZ_INPW;
constexpr size_t OFF_OUTPW_HI = OFF_INPW_LO + SZ_INPW;
constexpr size_t OFF_OUTPW_LO = OFF_OUTPW_HI + SZ_OUTPW;
constexpr size_t OFF_EW1T     = OFF_OUTPW_LO + SZ_OUTPW;
constexpr size_t OFF_EW2T     = OFF_EW1T + SZ_EWT;
constexpr size_t OFF_MASKW    = OFF_EW2T + SZ_EWT;
constexpr size_t OFF_H        = OFF_MASKW + SZ_MASKW;   // f32 [T][384]: h0 / o2 / moe_acc
constexpr size_t OFF_P        = OFF_H + SZ_TE_F32;      // attn-out pairs, later h f32
constexpr size_t OFF_XHI      = OFF_P + SZ_TE_F32;      // hn_hi pairs, later h f16
constexpr size_t OFF_XLO      = OFF_XHI + SZ_TE_F16;
constexpr size_t OFF_Q        = OFF_XLO + SZ_TE_F16;    // qkv chunk f32 / eh f16
constexpr size_t WS_NEEDED    = OFF_Q + SZ_EH;          // ~207 MB

// ---------------- prep kernels ----------------
__global__ __launch_bounds__(256) void split_pairs_k(
    const float* __restrict__ in, f16* __restrict__ hi, f16* __restrict__ lo, int n) {
  int i = blockIdx.x * 256 + threadIdx.x;
  if (i < n) {
    float v = in[i];
    f16 h = (f16)v;
    hi[i] = h;
    lo[i] = (f16)(v - (float)h);
  }
}

// in f32 [R][C] -> out f16 [C][R] (per blockIdx.z slice of size R*C)
__global__ __launch_bounds__(256) void transpose_cast_k(
    const float* __restrict__ in, f16* __restrict__ outp, int R, int C) {
  __shared__ float tile[32][33];
  int e = blockIdx.z;
  const float* pin = in + (size_t)e * R * C;
  f16* pout = outp + (size_t)e * R * C;
  int c0 = blockIdx.x * 32, r0 = blockIdx.y * 32;
  int tx = threadIdx.x & 31, ty = threadIdx.x >> 5;
#pragma unroll
  for (int i = 0; i < 4; i++)
    tile[ty + 8 * i][tx] = pin[(size_t)(r0 + ty + 8 * i) * C + c0 + tx];
  __syncthreads();
#pragma unroll
  for (int i = 0; i < 4; i++)
    pout[(size_t)(c0 + ty + 8 * i) * R + r0 + tx] = (f16)tile[tx][ty + 8 * i];
}

__global__ void cls_init_k(const float* __restrict__ cls, const float* __restrict__ posw,
                           float* __restrict__ h0) {
  int b = blockIdx.x, c = threadIdx.x;  // block = 384 threads
  h0[(size_t)b * NTOKC * EMB + c] = cls[c] + posw[c];
}

// ---------------- fp16x2 (split) GEMM:  C = A * B^T  ----------------
// A: [M][K] as hi/lo planes (or fused patch-gather from image when MODE==0)
// B: [N][K] hi/lo planes. 128x128 tile, BK=32, 16x16x32 MFMA, 3 products (hh,hl,lh).
template <int MODE>  // 0 = embed (A gathered from NCHW image), 1 = generic
__global__ __launch_bounds__(256) void gemm_x2_k(
    const f16* __restrict__ Ahi, const f16* __restrict__ Alo,
    const float* __restrict__ Ximg,
    const f16* __restrict__ Bhi, const f16* __restrict__ Blo,
    const float* __restrict__ bias, const float* __restrict__ posw,
    float* __restrict__ Cout,
    int K, int N, int mTile0, int rowLo, int rowHi, int rowOff) {
  __shared__ f16 As[2][128 * 40];
  __shared__ f16 Bs[2][128 * 40];
  const int tid = threadIdx.x;
  const int m0 = (mTile0 + (int)blockIdx.y) * 128;
  const int n0 = (int)blockIdx.x * 128;
  const int lr = tid >> 1;
  const int lc = (tid & 1) * 16;
  const int lane = tid & 63;
  const int wave = tid >> 6;
  const int wm = (wave >> 1) * 64;
  const int wn = (wave & 1) * 64;
  const int fr = lane & 15;
  const int fq = lane >> 4;

  f32x4 acc[4][4];
#pragma unroll
  for (int i = 0; i < 4; i++)
#pragma unroll
    for (int j = 0; j < 4; j++) acc[i][j] = f32x4{0.f, 0.f, 0.f, 0.f};

  // fixed per-thread row geometry
  const f16* ahi_row = nullptr;
  const f16* alo_row = nullptr;
  const float* srcbase = nullptr;
  if (MODE == 0) {
    int rp = m0 + lr;
    int bimg = rp / 196;
    int p = rp - bimg * 196;
    int py = p / 14, px = p - py * 14;
    srcbase = Ximg + (size_t)(bimg * 3) * 50176 + (py * 16) * 224 + px * 16;
  } else {
    ahi_row = Ahi + (size_t)(m0 + lr) * K + lc;
    alo_row = Alo + (size_t)(m0 + lr) * K + lc;
  }
  const f16* bhi_row = Bhi + (size_t)(n0 + lr) * K + lc;
  const f16* blo_row = Blo + (size_t)(n0 + lr) * K + lc;
  f16* asd_h = &As[0][lr * 40 + lc];
  f16* asd_l = &As[1][lr * 40 + lc];
  f16* bsd_h = &Bs[0][lr * 40 + lc];
  f16* bsd_l = &Bs[1][lr * 40 + lc];

  for (int k0 = 0; k0 < K; k0 += 32) {
    {  // B staging
      uint4 h0v = *(const uint4*)(bhi_row + k0);
      uint4 h1v = *(const uint4*)(bhi_row + k0 + 8);
      uint4 l0v = *(const uint4*)(blo_row + k0);
      uint4 l1v = *(const uint4*)(blo_row + k0 + 8);
      ((uint4*)bsd_h)[0] = h0v; ((uint4*)bsd_h)[1] = h1v;
      ((uint4*)bsd_l)[0] = l0v; ((uint4*)bsd_l)[1] = l1v;
    }
    if (MODE == 0) {  // A staging: gather 16 contiguous pixels, split in-register
      int kg = k0 + lc;                 // multiple of 16
      int cch = kg >> 8;                // channel
      int ky = (kg & 255) >> 4;         // kernel row
      const float* src = srcbase + (size_t)cch * 50176 + ky * 224;
      float vals[16] __attribute__((aligned(16)));
      ((float4*)vals)[0] = ((const float4*)src)[0];
      ((float4*)vals)[1] = ((const float4*)src)[1];
      ((float4*)vals)[2] = ((const float4*)src)[2];
      ((float4*)vals)[3] = ((const float4*)src)[3];
      f16 hv[16] __attribute__((aligned(16)));
      f16 lv[16] __attribute__((aligned(16)));
#pragma unroll
      for (int t = 0; t < 16; t++) {
        f16 hh = (f16)vals[t];
        hv[t] = hh;
        lv[t] = (f16)(vals[t] - (float)hh);
      }
      ((uint4*)asd_h)[0] = ((uint4*)hv)[0]; ((uint4*)asd_h)[1] = ((uint4*)hv)[1];
      ((uint4*)asd_l)[0] = ((uint4*)lv)[0]; ((uint4*)asd_l)[1] = ((uint4*)lv)[1];
    } else {
      uint4 h0v = *(const uint4*)(ahi_row + k0);
      uint4 h1v = *(const uint4*)(ahi_row + k0 + 8);
      uint4 l0v = *(const uint4*)(alo_row + k0);
      uint4 l1v = *(const uint4*)(alo_row + k0 + 8);
      ((uint4*)asd_h)[0] = h0v; ((uint4*)asd_h)[1] = h1v;
      ((uint4*)asd_l)[0] = l0v; ((uint4*)asd_l)[1] = l1v;
    }
    __syncthreads();

    f16x8 ah[4], al[4], bh[4], bl[4];
#pragma unroll
    for (int i = 0; i < 4; i++) {
      int ra = (wm + i * 16 + fr) * 40 + fq * 8;
      ah[i] = *(const f16x8*)&As[0][ra];
      al[i] = *(const f16x8*)&As[1][ra];
      int rb = (wn + i * 16 + fr) * 40 + fq * 8;
      bh[i] = *(const f16x8*)&Bs[0][rb];
      bl[i] = *(const f16x8*)&Bs[1][rb];
    }
#pragma unroll
    for (int i = 0; i < 4; i++)
#pragma unroll
      for (int j = 0; j < 4; j++) {
        acc[i][j] = __builtin_amdgcn_mfma_f32_16x16x32_f16(ah[i], bh[j], acc[i][j], 0, 0, 0);
        acc[i][j] = __builtin_amdgcn_mfma_f32_16x16x32_f16(ah[i], bl[j], acc[i][j], 0, 0, 0);
        acc[i][j] = __builtin_amdgcn_mfma_f32_16x16x32_f16(al[i], bh[j], acc[i][j], 0, 0, 0);
      }
    __syncthreads();
  }

#pragma unroll
  for (int i = 0; i < 4; i++)
#pragma unroll
    for (int j = 0; j < 4; j++)
#pragma unroll
      for (int rg = 0; rg < 4; rg++) {
        int gm = m0 + wm + i * 16 + fq * 4 + rg;
        int gn = n0 + wn + j * 16 + fr;
        float v = acc[i][j][rg];
        if (MODE == 0) {
          int bb = gm / 196;
          int p = gm - bb * 196;
          Cout[((size_t)bb * NTOKC + p + 1) * EMB + gn] =
              v + bias[gn] + posw[(size_t)(p + 1) * EMB + gn];
        } else {
          if (gm >= rowLo && gm < rowHi)
            Cout[(size_t)(gm - rowOff) * N + gn] = v + bias[gn];
        }
      }
}

// ---------------- plain fp16 GEMM (MoE):  C = A * B^T ----------------
template <int MODE>  // 0 = GELU -> f16 out, 1 = MoE2 masked f32 accumulate
__global__ __launch_bounds__(256) void gemm_x1_k(
    const f16* __restrict__ A, const f16* __restrict__ Bm,
    const float* __restrict__ bias, const float* __restrict__ maskw,
    float* __restrict__ Cf, f16* __restrict__ Ch,
    int K, int N, int eidx, int beta) {
  __shared__ f16 As[128 * 40];
  __shared__ f16 Bs[128 * 40];
  const int tid = threadIdx.x;
  const int m0 = (int)blockIdx.y * 128;
  const int n0 = (int)blockIdx.x * 128;
  const int lr = tid >> 1;
  const int lc = (tid & 1) * 16;
  const int lane = tid & 63;
  const int wave = tid >> 6;
  const int wm = (wave >> 1) * 64;
  const int wn = (wave & 1) * 64;
  const int fr = lane & 15;
  const int fq = lane >> 4;

  f32x4 acc[4][4];
#pragma unroll
  for (int i = 0; i < 4; i++)
#pragma unroll
    for (int j = 0; j < 4; j++) acc[i][j] = f32x4{0.f, 0.f, 0.f, 0.f};

  const f16* arow = A + (size_t)(m0 + lr) * K + lc;
  const f16* brow = Bm + (size_t)(n0 + lr) * K + lc;
  f16* asd = &As[lr * 40 + lc];
  f16* bsd = &Bs[lr * 40 + lc];

  for (int k0 = 0; k0 < K; k0 += 32) {
    uint4 a0 = *(const uint4*)(arow + k0);
    uint4 a1 = *(const uint4*)(arow + k0 + 8);
    uint4 b0 = *(const uint4*)(brow + k0);
    uint4 b1 = *(const uint4*)(brow + k0 + 8);
    ((uint4*)asd)[0] = a0; ((uint4*)asd)[1] = a1;
    ((uint4*)bsd)[0] = b0; ((uint4*)bsd)[1] = b1;
    __syncthreads();
    f16x8 af[4], bf[4];
#pragma unroll
    for (int i = 0; i < 4; i++) {
      af[i] = *(const f16x8*)&As[(wm + i * 16 + fr) * 40 + fq * 8];
      bf[i] = *(const f16x8*)&Bs[(wn + i * 16 + fr) * 40 + fq * 8];
    }
#pragma unroll
    for (int i = 0; i < 4; i++)
#pragma unroll
      for (int j = 0; j < 4; j++)
        acc[i][j] = __builtin_amdgcn_mfma_f32_16x16x32_f16(af[i], bf[j], acc[i][j], 0, 0, 0);
    __syncthreads();
  }

#pragma unroll
  for (int i = 0; i < 4; i++)
#pragma unroll
    for (int j = 0; j < 4; j++)
#pragma unroll
      for (int rg = 0; rg < 4; rg++) {
        int gm = m0 + wm + i * 16 + fq * 4 + rg;
        int gn = n0 + wn + j * 16 + fr;
        float v = acc[i][j][rg] + bias[gn];
        if (MODE == 0) {
          float g = 0.5f * v * (1.0f + erff(v * 0.70710678118654752f));  // exact GELU
          Ch[(size_t)gm * N + gn] = (f16)g;
        } else {
          float wgt = maskw[(size_t)gm * 4 + eidx];
          float val = wgt * v;
          float* pp = Cf + (size_t)gm * N + gn;
          *pp = beta ? (*pp + val) : val;
        }
      }
}

// ---------------- LayerNorm (row=384), optional f32 / pair / f16 outputs ----------------
template <int OUTF32, int OUTPAIR, int OUTH>
__global__ __launch_bounds__(256) void ln_k(
    const float* __restrict__ in, const float* __restrict__ g, const float* __restrict__ bb,
    float* __restrict__ of, f16* __restrict__ ohi, f16* __restrict__ olo, f16* __restrict__ oh) {
  int wave = threadIdx.x >> 6, lane = threadIdx.x & 63;
  size_t row = (size_t)blockIdx.x * 4 + wave;
  const float* xp = in + row * EMB;
  float v[6];
  float s = 0.f, sq = 0.f;
#pragma unroll
  for (int i = 0; i < 6; i++) {
    v[i] = xp[lane + 64 * i];
    s += v[i];
    sq += v[i] * v[i];
  }
#pragma unroll
  for (int off = 32; off; off >>= 1) {
    s += __shfl_xor(s, off);
    sq += __shfl_xor(sq, off);
  }
  float m = s * (1.f / 384.f);
  float var = sq * (1.f / 384.f) - m * m;
  float rs = rsqrtf(var + 1e-5f);
#pragma unroll
  for (int i = 0; i < 6; i++) {
    int c = lane + 64 * i;
    float y = (v[i] - m) * rs * g[c] + bb[c];
    size_t o = row * EMB + c;
    if (OUTF32) of[o] = y;
    if (OUTPAIR) {
      f16 hh = (f16)y;
      ohi[o] = hh;
      olo[o] = (f16)(y - (float)hh);
    }
    if (OUTH) oh[o] = (f16)y;
  }
}

// ---------------- attention (f32 VALU, no-max softmax; scores bounded ~|s|<1) ----------
// grid (6 heads, 64 local-batches); block 256 = 4 waves; wave w covers q rows [w*64, w*64+64)
// lane: r4 = lane>>2 handles rows r4+16*i (i<4); c = lane&3 owns d-columns c*16..c*16+15.
__global__ __launch_bounds__(256, 1) void attn_k(
    const float* __restrict__ qkv,  // chunk base: row = bl*197 + t, stride 1152
    f16* __restrict__ ohi, f16* __restrict__ olo, int batch0) {
  __shared__ float Ks[100 * 64];
  __shared__ float Vs[100 * 64];
  const int h = blockIdx.x;
  const int bl = blockIdx.y;
  const int tid = threadIdx.x;
  const int wave = tid >> 6;
  const int lane = tid & 63;
  const int r4 = lane >> 2;
  const int c = lane & 3;
  const size_t rowbase = (size_t)bl * NTOKC;

  float q[4][16];
  float acc[4][16];
  float lsum[4] = {0.f, 0.f, 0.f, 0.f};
#pragma unroll
  for (int i = 0; i < 4; i++) {
    int row = wave * 64 + 16 * i + r4;
    if (row < NTOKC) {
      const float4* qp = (const float4*)(qkv + (rowbase + row) * QKVD + h * 64 + c * 16);
      float4 a = qp[0], b4 = qp[1], c4 = qp[2], d4 = qp[3];
      q[i][0] = a.x;  q[i][1] = a.y;  q[i][2] = a.z;  q[i][3] = a.w;
      q[i][4] = b4.x; q[i][5] = b4.y; q[i][6] = b4.z; q[i][7] = b4.w;
      q[i][8] = c4.x; q[i][9] = c4.y; q[i][10] = c4.z; q[i][11] = c4.w;
      q[i][12] = d4.x; q[i][13] = d4.y; q[i][14] = d4.z; q[i][15] = d4.w;
    } else {
#pragma unroll
      for (int j = 0; j < 16; j++) q[i][j] = 0.f;
    }
#pragma unroll
    for (int j = 0; j < 16; j++) acc[i][j] = 0.f;
  }

  for (int ch = 0; ch < 2; ch++) {
    const int k0 = ch * 100;
    const int nk = ch ? 97 : 100;
    __syncthreads();
    for (int idx = tid; idx < nk * 16; idx += 256) {
      int kr = idx >> 4, kc = (idx & 15) << 2;
      const float* kp = qkv + (rowbase + k0 + kr) * QKVD + EMB + h * 64 + kc;
      *(float4*)&Ks[kr * 64 + kc] = *(const float4*)kp;
      *(float4*)&Vs[kr * 64 + kc] = *(const float4*)(kp + EMB);
    }
    __syncthreads();
    for (int k = 0; k < nk; k++) {
      const float4* kk = (const float4*)&Ks[k * 64 + c * 16];
      float4 ka = kk[0], kb = kk[1], kc4 = kk[2], kd = kk[3];
      const float4* vv = (const float4*)&Vs[k * 64 + c * 16];
      float4 v0 = vv[0], v1 = vv[1], v2 = vv[2], v3 = vv[3];
#pragma unroll
      for (int i = 0; i < 4; i++) {
        float s = q[i][0] * ka.x + q[i][1] * ka.y + q[i][2] * ka.z + q[i][3] * ka.w +
                  q[i][4] * kb.x + q[i][5] * kb.y + q[i][6] * kb.z + q[i][7] * kb.w +
                  q[i][8] * kc4.x + q[i][9] * kc4.y + q[i][10] * kc4.z + q[i][11] * kc4.w +
                  q[i][12] * kd.x + q[i][13] * kd.y + q[i][14] * kd.z + q[i][15] * kd.w;
        s += __shfl_xor(s, 1);
        s += __shfl_xor(s, 2);
        float p = __expf(s * 0.125f);
        lsum[i] += p;
        acc[i][0] += p * v0.x;  acc[i][1] += p * v0.y;  acc[i][2] += p * v0.z;  acc[i][3] += p * v0.w;
        acc[i][4] += p * v1.x;  acc[i][5] += p * v1.y;  acc[i][6] += p * v1.z;  acc[i][7] += p * v1.w;
        acc[i][8] += p * v2.x;  acc[i][9] += p * v2.y;  acc[i][10] += p * v2.z; acc[i][11] += p * v2.w;
        acc[i][12] += p * v3.x; acc[i][13] += p * v3.y; acc[i][14] += p * v3.z; acc[i][15] += p * v3.w;
      }
    }
  }

#pragma unroll
  for (int i = 0; i < 4; i++) {
    int row = wave * 64 + 16 * i + r4;
    if (row < NTOKC) {
      float rin = 1.f / lsum[i];
      f16 hv[16] __attribute__((aligned(16)));
      f16 lv[16] __attribute__((aligned(16)));
#pragma unroll
      for (int j = 0; j < 16; j++) {
        float vvv = acc[i][j] * rin;
        f16 hh = (f16)vvv;
        hv[j] = hh;
        lv[j] = (f16)(vvv - (float)hh);
      }
      size_t ob = ((size_t)(batch0 + bl) * NTOKC + row) * EMB + h * 64 + c * 16;
      ((uint4*)(ohi + ob))[0] = ((uint4*)hv)[0];
      ((uint4*)(ohi + ob))[1] = ((uint4*)hv)[1];
      ((uint4*)(olo + ob))[0] = ((uint4*)lv)[0];
      ((uint4*)(olo + ob))[1] = ((uint4*)lv)[1];
    }
  }
}

// ---------------- router: top-2 of 4 logits -> {0,0.5} weights ----------------
__global__ __launch_bounds__(256) void router_k(
    const float* __restrict__ hbuf, const float* __restrict__ rw,
    const float* __restrict__ rb, float* __restrict__ maskw) {
  const int tid = threadIdx.x;
  const int tl = tid >> 2, e = tid & 3;
  const int t = blockIdx.x * 64 + tl;
  const float4* h4 = (const float4*)(hbuf + (size_t)t * EMB);
  const float4* w4 = (const float4*)(rw + e * EMB);
  float s = rb[e];
#pragma unroll 8
  for (int i = 0; i < 96; i++) {
    float4 a = h4[i], w = w4[i];
    s += a.x * w.x + a.y * w.y + a.z * w.z + a.w * w.w;
  }
  int lane = tid & 63;
  int base = lane & ~3;
  float l0 = __shfl(s, base + 0);
  float l1 = __shfl(s, base + 1);
  float l2 = __shfl(s, base + 2);
  float l3 = __shfl(s, base + 3);
  // argmax with lowest-index tie-break (matches lax.top_k)
  int i1 = 0; float b1 = l0;
  if (l1 > b1) { b1 = l1; i1 = 1; }
  if (l2 > b1) { b1 = l2; i1 = 2; }
  if (l3 > b1) { b1 = l3; i1 = 3; }
  int i2 = -1; float b2 = 0.f;
  float lv[4] = {l0, l1, l2, l3};
#pragma unroll
  for (int i = 0; i < 4; i++) {
    if (i == i1) continue;
    if (i2 < 0 || lv[i] > b2) { i2 = i; b2 = lv[i]; }
  }
  maskw[(size_t)t * 4 + e] = (e == i1 || e == i2) ? 0.5f : 0.f;
}

// ---------------- fused LN2 + classification head on cls rows ----------------
__global__ __launch_bounds__(256) void head_k(
    const float* __restrict__ moe, const float* __restrict__ g, const float* __restrict__ bb,
    const float* __restrict__ hw, const float* __restrict__ hb, float* __restrict__ outp) {
  __shared__ float sh[EMB];
  __shared__ float red[8];
  int b = blockIdx.x, tid = threadIdx.x;
  const float* xp = moe + (size_t)b * NTOKC * EMB;  // cls row
  float v0 = xp[tid];
  float v1 = (tid < 128) ? xp[256 + tid] : 0.f;
  float s = v0 + v1, sq = v0 * v0 + v1 * v1;
  int lane = tid & 63, wave = tid >> 6;
#pragma unroll
  for (int off = 32; off; off >>= 1) {
    s += __shfl_xor(s, off);
    sq += __shfl_xor(sq, off);
  }
  if (lane == 0) { red[wave] = s; red[4 + wave] = sq; }
  __syncthreads();
  float S = red[0] + red[1] + red[2] + red[3];
  float SQ = red[4] + red[5] + red[6] + red[7];
  float m = S * (1.f / 384.f);
  float var = SQ * (1.f / 384.f) - m * m;
  float rs = rsqrtf(var + 1e-5f);
  sh[tid] = (v0 - m) * rs * g[tid] + bb[tid];
  if (tid < 128) sh[256 + tid] = (v1 - m) * rs * g[256 + tid] + bb[256 + tid];
  __syncthreads();
  for (int n = tid; n < 1000; n += 256) {
    const float4* w4 = (const float4*)(hw + (size_t)n * EMB);
    const float4* s4 = (const float4*)sh;
    float a = hb[n];
#pragma unroll 8
    for (int i = 0; i < 96; i++) {
      float4 x = s4[i], w = w4[i];
      a += x.x * w.x + x.y * w.y + x.z * w.z + x.w * w.w;
    }
    outp[(size_t)b * 1000 + n] = a;
  }
}

// ---------------- host ----------------
extern "C" void kernel_launch(void* const* d_in, const int* in_sizes, int n_in,
                              void* d_out, int out_size, void* d_ws, size_t ws_size,
                              hipStream_t stream) {
  const float* x      = (const float*)d_in[0];
  const float* conv_w = (const float*)d_in[1];
  const float* conv_b = (const float*)d_in[2];
  const float* cls_t  = (const float*)d_in[3];
  const float* pos    = (const float*)d_in[4];
  const float* ln1_g  = (const float*)d_in[5];
  const float* ln1_b  = (const float*)d_in[6];
  const float* inp_w  = (const float*)d_in[7];
  const float* inp_b  = (const float*)d_in[8];
  const float* outp_w = (const float*)d_in[9];
  const float* outp_b = (const float*)d_in[10];
  const float* rt_w   = (const float*)d_in[11];
  const float* rt_b   = (const float*)d_in[12];
  const float* ew1    = (const float*)d_in[13];
  const float* eb1    = (const float*)d_in[14];
  const float* ew2    = (const float*)d_in[15];
  const float* eb2    = (const float*)d_in[16];
  const float* ln2_g  = (const float*)d_in[17];
  const float* ln2_b  = (const float*)d_in[18];
  const float* head_w = (const float*)d_in[19];
  const float* head_b = (const float*)d_in[20];
  float* out = (float*)d_out;
  char* w = (char*)d_ws;
  if (ws_size < WS_NEEDED) return;  // fail visibly via absmax if ws too small

  f16* convw_hi = (f16*)(w + OFF_CONVW_HI);
  f16* convw_lo = (f16*)(w + OFF_CONVW_LO);
  f16* inpw_hi  = (f16*)(w + OFF_INPW_HI);
  f16* inpw_lo  = (f16*)(w + OFF_INPW_LO);
  f16* outpw_hi = (f16*)(w + OFF_OUTPW_HI);
  f16* outpw_lo = (f16*)(w + OFF_OUTPW_LO);
  f16* ew1t     = (f16*)(w + OFF_EW1T);
  f16* ew2t     = (f16*)(w + OFF_EW2T);
  float* maskw  = (float*)(w + OFF_MASKW);
  float* Hbuf   = (float*)(w + OFF_H);      // h0 / o2 / moe_acc
  f16* o_hi     = (f16*)(w + OFF_P);        // attn-out pairs
  f16* o_lo     = (f16*)(w + OFF_P + SZ_TE_F16);
  float* Pf32   = (float*)(w + OFF_P);      // later: h f32 (router input)
  f16* x_hi     = (f16*)(w + OFF_XHI);      // hn pairs, later h f16
  f16* x_lo     = (f16*)(w + OFF_XLO);
  float* qkvbuf = (float*)(w + OFF_Q);
  f16* ehbuf    = (f16*)(w + OFF_Q);

  // ---- weight prep ----
  split_pairs_k<<<dim3((294912 + 255) / 256), dim3(256), 0, stream>>>(conv_w, convw_hi, convw_lo, 294912);
  split_pairs_k<<<dim3((442368 + 255) / 256), dim3(256), 0, stream>>>(inp_w, inpw_hi, inpw_lo, 442368);
  split_pairs_k<<<dim3((147456 + 255) / 256), dim3(256), 0, stream>>>(outp_w, outpw_hi, outpw_lo, 147456);
  transpose_cast_k<<<dim3(48, 12, 4), dim3(256), 0, stream>>>(ew1, ew1t, 384, 1536);
  transpose_cast_k<<<dim3(12, 48, 4), dim3(256), 0, stream>>>(ew2, ew2t, 1536, 384);

  // ---- patch embed (conv-as-GEMM, fused gather + bias + pos) -> h0 (Hbuf) ----
  gemm_x2_k<0><<<dim3(3, 196), dim3(256), 0, stream>>>(
      nullptr, nullptr, x, convw_hi, convw_lo, conv_b, pos, Hbuf,
      768, EMB, 0, 0, 0, 0);
  cls_init_k<<<dim3(128), dim3(384), 0, stream>>>(cls_t, pos, Hbuf);

  // ---- LN1 -> hn pairs ----
  ln_k<0, 1, 0><<<dim3(TTOK / 4), dim3(256), 0, stream>>>(
      Hbuf, ln1_g, ln1_b, nullptr, x_hi, x_lo, nullptr);

  // ---- QKV + attention, two batch-chunks of 64 ----
  for (int ch = 0; ch < 2; ch++) {
    gemm_x2_k<1><<<dim3(9, 99), dim3(256), 0, stream>>>(
        x_hi, x_lo, nullptr, inpw_hi, inpw_lo, inp_b, nullptr, qkvbuf,
        EMB, QKVD, ch * 98, ch * CHROWS, ch * CHROWS + CHROWS, ch * CHROWS);
    attn_k<<<dim3(6, 64), dim3(256), 0, stream>>>(qkvbuf, o_hi, o_lo, ch * 64);
  }

  // ---- out-proj -> o2 (Hbuf) ----
  gemm_x2_k<1><<<dim3(3, 197), dim3(256), 0, stream>>>(
      o_hi, o_lo, nullptr, outpw_hi, outpw_lo, outp_b, nullptr, Hbuf,
      EMB, EMB, 0, 0, TTOK, 0);

  // ---- LN (same params) -> h f32 (Pf32) + h f16 (x_hi) ----
  ln_k<1, 0, 1><<<dim3(TTOK / 4), dim3(256), 0, stream>>>(
      Hbuf, ln1_g, ln1_b, Pf32, nullptr, nullptr, x_hi);

  // ---- router top-2 -> mask weights ----
  router_k<<<dim3(TTOK / 64), dim3(256), 0, stream>>>(Pf32, rt_w, rt_b, maskw);

  // ---- MoE: dense per-expert FFN with masked 0.5x accumulation into Hbuf ----
  for (int e = 0; e < 4; e++) {
    gemm_x1_k<0><<<dim3(12, 197), dim3(256), 0, stream>>>(
        x_hi, ew1t + (size_t)e * HID * EMB, eb1 + e * HID, nullptr,
        nullptr, ehbuf, EMB, HID, e, 0);
    gemm_x1_k<1><<<dim3(3, 197), dim3(256), 0, stream>>>(
        ehbuf, ew2t + (size_t)e * EMB * HID, eb2 + e * EMB, maskw,
        Hbuf, nullptr, HID, EMB, e, e ? 1 : 0);
  }

  // ---- LN2 + head on cls rows ----
  head_k<<<dim3(128), dim3(256), 0, stream>>>(Hbuf, ln2_g, ln2_b, head_w, head_b, out);
  (void)in_sizes; (void)n_in; (void)out_size;
}

// Round 3
// 1318.794 us; speedup vs baseline: 1.0860x; 1.0860x over previous
//
#include <hip/hip_runtime.h>
#include <cstdint>
#include <cstddef>

typedef _Float16 f16;
typedef _Float16 f16x8 __attribute__((ext_vector_type(8)));
typedef float    f32x4 __attribute__((ext_vector_type(4)));

// ---------------- problem constants ----------------
constexpr int BATCH  = 128;
constexpr int NTOKC  = 197;
constexpr int TTOK   = BATCH * NTOKC;     // 25216
constexpr int EMB    = 384;
constexpr int HID    = 1536;
constexpr int QKVD   = 1152;
constexpr int CHROWS = 12608;             // TTOK/2 (qkv batch-chunk rows)

// ---------------- workspace layout (bytes) ----------------
constexpr size_t SZ_CONVW   = (size_t)384 * 768 * 2;
constexpr size_t SZ_INPW    = (size_t)1152 * 384 * 2;
constexpr size_t SZ_OUTPW   = (size_t)384 * 384 * 2;
constexpr size_t SZ_EWT     = (size_t)4 * 1536 * 384 * 2;
constexpr size_t SZ_MASKW   = (size_t)TTOK * 4 * 4;
constexpr size_t SZ_TE_F32  = (size_t)TTOK * EMB * 4;   // 38,731,776
constexpr size_t SZ_TE_F16  = (size_t)TTOK * EMB * 2;   // 19,365,888
constexpr size_t SZ_EH      = (size_t)TTOK * HID * 2;   // 77,463,552
constexpr size_t SZ_QKVCH   = (size_t)CHROWS * QKVD * 4; // 58,097,664

constexpr size_t OFF_CONVW_HI = 0;
constexpr size_t OFF_CONVW_LO = OFF_CONVW_HI + SZ_CONVW;
constexpr size_t OFF_INPW_HI  = OFF_CONVW_LO + SZ_CONVW;
constexpr size_t OFF_INPW_LO  = OFF_INPW_HI + SZ_INPW;
constexpr size_t OFF_OUTPW_HI = OFF_INPW_LO + SZ_INPW;
constexpr size_t OFF_OUTPW_LO = OFF_OUTPW_HI + SZ_OUTPW;
constexpr size_t OFF_EW1T     = OFF_OUTPW_LO + SZ_OUTPW;
constexpr size_t OFF_EW2T     = OFF_EW1T + SZ_EWT;
constexpr size_t OFF_MASKW    = OFF_EW2T + SZ_EWT;
constexpr size_t OFF_H        = OFF_MASKW + SZ_MASKW;   // f32 [T][384]: h0 / attn-partials / o2 / moe_acc
constexpr size_t OFF_P        = OFF_H + SZ_TE_F32;      // attn-out pairs, later h f32
constexpr size_t OFF_XHI      = OFF_P + SZ_TE_F32;
constexpr size_t OFF_XLO      = OFF_XHI + SZ_TE_F16;
constexpr size_t OFF_Q        = OFF_XLO + SZ_TE_F16;    // qkv chunk f32 / eh f16; tail: lsum partials
constexpr size_t WS_NEEDED    = OFF_Q + SZ_EH;          // ~207 MB

// ---------------- global_load_lds helper ----------------
__device__ __forceinline__ void gload16(const void* g, void* l) {
  __builtin_amdgcn_global_load_lds(
      (__attribute__((address_space(1))) void*)(void*)g,
      (__attribute__((address_space(3))) void*)l, 16, 0, 0);
}

// ---------------- prep kernels ----------------
__global__ __launch_bounds__(256) void split_pairs_k(
    const float* __restrict__ in, f16* __restrict__ hi, f16* __restrict__ lo, int n) {
  int i = blockIdx.x * 256 + threadIdx.x;
  if (i < n) {
    float v = in[i];
    f16 h = (f16)v;
    hi[i] = h;
    lo[i] = (f16)(v - (float)h);
  }
}

__global__ __launch_bounds__(256) void transpose_cast_k(
    const float* __restrict__ in, f16* __restrict__ outp, int R, int C) {
  __shared__ float tile[32][33];
  int e = blockIdx.z;
  const float* pin = in + (size_t)e * R * C;
  f16* pout = outp + (size_t)e * R * C;
  int c0 = blockIdx.x * 32, r0 = blockIdx.y * 32;
  int tx = threadIdx.x & 31, ty = threadIdx.x >> 5;
#pragma unroll
  for (int i = 0; i < 4; i++)
    tile[ty + 8 * i][tx] = pin[(size_t)(r0 + ty + 8 * i) * C + c0 + tx];
  __syncthreads();
#pragma unroll
  for (int i = 0; i < 4; i++)
    pout[(size_t)(c0 + ty + 8 * i) * R + r0 + tx] = (f16)tile[tx][ty + 8 * i];
}

__global__ void cls_init_k(const float* __restrict__ cls, const float* __restrict__ posw,
                           float* __restrict__ h0) {
  int b = blockIdx.x, c = threadIdx.x;  // block = 384 threads
  h0[(size_t)b * NTOKC * EMB + c] = cls[c] + posw[c];
}

// ---------------- patch-embed GEMM (fp16x2 split, fused gather+bias+pos) ----------------
__global__ __launch_bounds__(256) void embed_k(
    const float* __restrict__ Ximg,
    const f16* __restrict__ Bhi, const f16* __restrict__ Blo,
    const float* __restrict__ bias, const float* __restrict__ posw,
    float* __restrict__ Cout) {
  __shared__ f16 As[2][128 * 40];
  __shared__ f16 Bs[2][128 * 40];
  const int K = 768;
  const int tid = threadIdx.x;
  const int m0 = (int)blockIdx.y * 128;
  const int n0 = (int)blockIdx.x * 128;
  const int lr = tid >> 1;
  const int lc = (tid & 1) * 16;
  const int lane = tid & 63;
  const int wave = tid >> 6;
  const int wm = (wave >> 1) * 64;
  const int wn = (wave & 1) * 64;
  const int fr = lane & 15;
  const int fq = lane >> 4;

  f32x4 acc[4][4];
#pragma unroll
  for (int i = 0; i < 4; i++)
#pragma unroll
    for (int j = 0; j < 4; j++) acc[i][j] = f32x4{0.f, 0.f, 0.f, 0.f};

  int rp = m0 + lr;
  int bimg = rp / 196;
  int p = rp - bimg * 196;
  int py = p / 14, px = p - py * 14;
  const float* srcbase = Ximg + (size_t)(bimg * 3) * 50176 + (py * 16) * 224 + px * 16;
  const f16* bhi_row = Bhi + (size_t)(n0 + lr) * K + lc;
  const f16* blo_row = Blo + (size_t)(n0 + lr) * K + lc;
  f16* asd_h = &As[0][lr * 40 + lc];
  f16* asd_l = &As[1][lr * 40 + lc];
  f16* bsd_h = &Bs[0][lr * 40 + lc];
  f16* bsd_l = &Bs[1][lr * 40 + lc];

  for (int k0 = 0; k0 < K; k0 += 32) {
    {
      uint4 h0v = *(const uint4*)(bhi_row + k0);
      uint4 h1v = *(const uint4*)(bhi_row + k0 + 8);
      uint4 l0v = *(const uint4*)(blo_row + k0);
      uint4 l1v = *(const uint4*)(blo_row + k0 + 8);
      ((uint4*)bsd_h)[0] = h0v; ((uint4*)bsd_h)[1] = h1v;
      ((uint4*)bsd_l)[0] = l0v; ((uint4*)bsd_l)[1] = l1v;
    }
    {
      int kg = k0 + lc;
      int cch = kg >> 8;
      int ky = (kg & 255) >> 4;
      const float* src = srcbase + (size_t)cch * 50176 + ky * 224;
      float vals[16] __attribute__((aligned(16)));
      ((float4*)vals)[0] = ((const float4*)src)[0];
      ((float4*)vals)[1] = ((const float4*)src)[1];
      ((float4*)vals)[2] = ((const float4*)src)[2];
      ((float4*)vals)[3] = ((const float4*)src)[3];
      f16 hv[16] __attribute__((aligned(16)));
      f16 lv[16] __attribute__((aligned(16)));
#pragma unroll
      for (int t = 0; t < 16; t++) {
        f16 hh = (f16)vals[t];
        hv[t] = hh;
        lv[t] = (f16)(vals[t] - (float)hh);
      }
      ((uint4*)asd_h)[0] = ((uint4*)hv)[0]; ((uint4*)asd_h)[1] = ((uint4*)hv)[1];
      ((uint4*)asd_l)[0] = ((uint4*)lv)[0]; ((uint4*)asd_l)[1] = ((uint4*)lv)[1];
    }
    __syncthreads();

    f16x8 ah[4], al[4], bh[4], bl[4];
#pragma unroll
    for (int i = 0; i < 4; i++) {
      int ra = (wm + i * 16 + fr) * 40 + fq * 8;
      ah[i] = *(const f16x8*)&As[0][ra];
      al[i] = *(const f16x8*)&As[1][ra];
      int rb = (wn + i * 16 + fr) * 40 + fq * 8;
      bh[i] = *(const f16x8*)&Bs[0][rb];
      bl[i] = *(const f16x8*)&Bs[1][rb];
    }
#pragma unroll
    for (int i = 0; i < 4; i++)
#pragma unroll
      for (int j = 0; j < 4; j++) {
        acc[i][j] = __builtin_amdgcn_mfma_f32_16x16x32_f16(ah[i], bh[j], acc[i][j], 0, 0, 0);
        acc[i][j] = __builtin_amdgcn_mfma_f32_16x16x32_f16(ah[i], bl[j], acc[i][j], 0, 0, 0);
        acc[i][j] = __builtin_amdgcn_mfma_f32_16x16x32_f16(al[i], bh[j], acc[i][j], 0, 0, 0);
      }
    __syncthreads();
  }

#pragma unroll
  for (int i = 0; i < 4; i++)
#pragma unroll
    for (int j = 0; j < 4; j++)
#pragma unroll
      for (int rg = 0; rg < 4; rg++) {
        int gm = m0 + wm + i * 16 + fq * 4 + rg;
        int gn = n0 + wn + j * 16 + fr;
        float v = acc[i][j][rg];
        int bb = gm / 196;
        int pp = gm - bb * 196;
        Cout[((size_t)bb * NTOKC + pp + 1) * EMB + gn] =
            v + bias[gn] + posw[(size_t)(pp + 1) * EMB + gn];
      }
}

// ---------------- fp16x2 split GEMM, global_load_lds staging: C = A*B^T ----------------
__global__ __launch_bounds__(256) void gemm_x2_k(
    const f16* __restrict__ Ahi, const f16* __restrict__ Alo,
    const f16* __restrict__ Bhi, const f16* __restrict__ Blo,
    const float* __restrict__ bias, float* __restrict__ Cout,
    int K, int N, int mTile0, int rowLo, int rowHi, int rowOff) {
  __shared__ f16 Ash[128 * 32];
  __shared__ f16 Asl[128 * 32];
  __shared__ f16 Bsh[128 * 32];
  __shared__ f16 Bsl[128 * 32];
  const int tid = threadIdx.x;
  const int lane = tid & 63;
  const int wave = tid >> 6;
  const int m0 = (mTile0 + (int)blockIdx.y) * 128;
  const int n0 = (int)blockIdx.x * 128;
  const int wm = (wave >> 1) * 64;
  const int wn = (wave & 1) * 64;
  const int fr = lane & 15;
  const int fq = lane >> 4;

  f32x4 acc[4][4];
#pragma unroll
  for (int i = 0; i < 4; i++)
#pragma unroll
    for (int j = 0; j < 4; j++) acc[i][j] = f32x4{0.f, 0.f, 0.f, 0.f};

  // staging: wave w covers rows [w*32, w*32+32) via two 16-row dwordx4 DMAs per plane
  const int srow = wave * 32 + (lane >> 2);
  const int scol = (lane & 3) * 8;
  const f16* agh = Ahi + (size_t)(m0 + srow) * K + scol;
  const f16* agl = Alo + (size_t)(m0 + srow) * K + scol;
  const f16* bgh = Bhi + (size_t)(n0 + srow) * K + scol;
  const f16* bgl = Blo + (size_t)(n0 + srow) * K + scol;
  const size_t rstep = (size_t)16 * K;
  f16* lah = Ash + wave * 32 * 32;
  f16* lal = Asl + wave * 32 * 32;
  f16* lbh = Bsh + wave * 32 * 32;
  f16* lbl = Bsl + wave * 32 * 32;

  for (int k0 = 0; k0 < K; k0 += 32) {
    gload16(agh, lah);          gload16(agh + rstep, lah + 16 * 32);
    gload16(agl, lal);          gload16(agl + rstep, lal + 16 * 32);
    gload16(bgh, lbh);          gload16(bgh + rstep, lbh + 16 * 32);
    gload16(bgl, lbl);          gload16(bgl + rstep, lbl + 16 * 32);
    agh += 32; agl += 32; bgh += 32; bgl += 32;
    __syncthreads();

    f16x8 ah[4], al[4], bh[4], bl[4];
#pragma unroll
    for (int i = 0; i < 4; i++) {
      int ra = (wm + i * 16 + fr) * 32 + fq * 8;
      ah[i] = *(const f16x8*)&Ash[ra];
      al[i] = *(const f16x8*)&Asl[ra];
      int rb = (wn + i * 16 + fr) * 32 + fq * 8;
      bh[i] = *(const f16x8*)&Bsh[rb];
      bl[i] = *(const f16x8*)&Bsl[rb];
    }
#pragma unroll
    for (int i = 0; i < 4; i++)
#pragma unroll
      for (int j = 0; j < 4; j++) {
        acc[i][j] = __builtin_amdgcn_mfma_f32_16x16x32_f16(ah[i], bh[j], acc[i][j], 0, 0, 0);
        acc[i][j] = __builtin_amdgcn_mfma_f32_16x16x32_f16(ah[i], bl[j], acc[i][j], 0, 0, 0);
        acc[i][j] = __builtin_amdgcn_mfma_f32_16x16x32_f16(al[i], bh[j], acc[i][j], 0, 0, 0);
      }
    __syncthreads();
  }

#pragma unroll
  for (int i = 0; i < 4; i++)
#pragma unroll
    for (int j = 0; j < 4; j++)
#pragma unroll
      for (int rg = 0; rg < 4; rg++) {
        int gm = m0 + wm + i * 16 + fq * 4 + rg;
        int gn = n0 + wn + j * 16 + fr;
        if (gm >= rowLo && gm < rowHi)
          Cout[(size_t)(gm - rowOff) * N + gn] = acc[i][j][rg] + bias[gn];
      }
}

// ---------------- plain fp16 GEMM (MoE), global_load_lds staging ----------------
template <int MODE>  // 0 = GELU -> f16 out, 1 = MoE2 masked f32 accumulate
__global__ __launch_bounds__(256) void gemm_x1_k(
    const f16* __restrict__ A, const f16* __restrict__ Bm,
    const float* __restrict__ bias, const float* __restrict__ maskw,
    float* __restrict__ Cf, f16* __restrict__ Ch,
    int K, int N, int eidx, int beta) {
  __shared__ f16 As[128 * 32];
  __shared__ f16 Bs[128 * 32];
  const int tid = threadIdx.x;
  const int lane = tid & 63;
  const int wave = tid >> 6;
  const int m0 = (int)blockIdx.y * 128;
  const int n0 = (int)blockIdx.x * 128;
  const int wm = (wave >> 1) * 64;
  const int wn = (wave & 1) * 64;
  const int fr = lane & 15;
  const int fq = lane >> 4;

  f32x4 acc[4][4];
#pragma unroll
  for (int i = 0; i < 4; i++)
#pragma unroll
    for (int j = 0; j < 4; j++) acc[i][j] = f32x4{0.f, 0.f, 0.f, 0.f};

  const int srow = wave * 32 + (lane >> 2);
  const int scol = (lane & 3) * 8;
  const f16* ag = A + (size_t)(m0 + srow) * K + scol;
  const f16* bg = Bm + (size_t)(n0 + srow) * K + scol;
  const size_t rstep = (size_t)16 * K;
  f16* la = As + wave * 32 * 32;
  f16* lb = Bs + wave * 32 * 32;

  for (int k0 = 0; k0 < K; k0 += 32) {
    gload16(ag, la);          gload16(ag + rstep, la + 16 * 32);
    gload16(bg, lb);          gload16(bg + rstep, lb + 16 * 32);
    ag += 32; bg += 32;
    __syncthreads();
    f16x8 af[4], bf[4];
#pragma unroll
    for (int i = 0; i < 4; i++) {
      af[i] = *(const f16x8*)&As[(wm + i * 16 + fr) * 32 + fq * 8];
      bf[i] = *(const f16x8*)&Bs[(wn + i * 16 + fr) * 32 + fq * 8];
    }
#pragma unroll
    for (int i = 0; i < 4; i++)
#pragma unroll
      for (int j = 0; j < 4; j++)
        acc[i][j] = __builtin_amdgcn_mfma_f32_16x16x32_f16(af[i], bf[j], acc[i][j], 0, 0, 0);
    __syncthreads();
  }

#pragma unroll
  for (int i = 0; i < 4; i++)
#pragma unroll
    for (int j = 0; j < 4; j++)
#pragma unroll
      for (int rg = 0; rg < 4; rg++) {
        int gm = m0 + wm + i * 16 + fq * 4 + rg;
        int gn = n0 + wn + j * 16 + fr;
        float v = acc[i][j][rg] + bias[gn];
        if (MODE == 0) {
          float g = 0.5f * v * (1.0f + erff(v * 0.70710678118654752f));  // exact GELU
          Ch[(size_t)gm * N + gn] = (f16)g;
        } else {
          float wgt = maskw[(size_t)gm * 4 + eidx];
          float val = wgt * v;
          float* pp = Cf + (size_t)gm * N + gn;
          *pp = beta ? (*pp + val) : val;
        }
      }
}

// ---------------- LayerNorm (row=384) ----------------
template <int OUTF32, int OUTPAIR, int OUTH>
__global__ __launch_bounds__(256) void ln_k(
    const float* __restrict__ in, const float* __restrict__ g, const float* __restrict__ bb,
    float* __restrict__ of, f16* __restrict__ ohi, f16* __restrict__ olo, f16* __restrict__ oh) {
  int wave = threadIdx.x >> 6, lane = threadIdx.x & 63;
  size_t row = (size_t)blockIdx.x * 4 + wave;
  const float* xp = in + row * EMB;
  float v[6];
  float s = 0.f, sq = 0.f;
#pragma unroll
  for (int i = 0; i < 6; i++) {
    v[i] = xp[lane + 64 * i];
    s += v[i];
    sq += v[i] * v[i];
  }
#pragma unroll
  for (int off = 32; off; off >>= 1) {
    s += __shfl_xor(s, off);
    sq += __shfl_xor(sq, off);
  }
  float m = s * (1.f / 384.f);
  float var = sq * (1.f / 384.f) - m * m;
  float rs = rsqrtf(var + 1e-5f);
#pragma unroll
  for (int i = 0; i < 6; i++) {
    int c = lane + 64 * i;
    float y = (v[i] - m) * rs * g[c] + bb[c];
    size_t o = row * EMB + c;
    if (OUTF32) of[o] = y;
    if (OUTPAIR) {
      f16 hh = (f16)y;
      ohi[o] = hh;
      olo[o] = (f16)(y - (float)hh);
    }
    if (OUTH) oh[o] = (f16)y;
  }
}

// ---------------- attention partial (f32 VALU, no-max softmax, k-chunk split) ----------
// grid (6 heads, 64 local-batches, 2 k-chunks); block 256 = 4 waves.
// Each block processes all 197 q rows against its k-chunk; writes additive partials.
// NOTE: lsum[i] already holds the FULL quad sum (score was quad-reduced before exp,
// so p is identical across the 4 lanes of a quad). Store it directly — do NOT
// re-reduce across the quad (R2 bug: 4x-scaled denominators).
__global__ __launch_bounds__(256, 3) void attn_k(
    const float* __restrict__ qkv,  // chunk base: row = bl*197 + t, stride 1152
    float* __restrict__ Pacc,       // [2][64][197][384] partial p*v
    float* __restrict__ Plsum) {    // [2][64][197][6]   partial sum(p)
  __shared__ float Ks[100 * 64];
  __shared__ float Vs[100 * 64];
  const int h = blockIdx.x;
  const int bl = blockIdx.y;
  const int kc = blockIdx.z;
  const int tid = threadIdx.x;
  const int wave = tid >> 6;
  const int lane = tid & 63;
  const int r4 = lane >> 2;
  const int c = lane & 3;
  const size_t rowbase = (size_t)bl * NTOKC;
  const int k0 = kc * 100;
  const int nk = kc ? 97 : 100;

  float q[4][16];
  float acc[4][16];
  float lsum[4] = {0.f, 0.f, 0.f, 0.f};
#pragma unroll
  for (int i = 0; i < 4; i++) {
    int row = wave * 64 + 16 * i + r4;
    if (row < NTOKC) {
      const float4* qp = (const float4*)(qkv + (rowbase + row) * QKVD + h * 64 + c * 16);
      float4 a = qp[0], b4 = qp[1], c4 = qp[2], d4 = qp[3];
      q[i][0] = a.x;  q[i][1] = a.y;  q[i][2] = a.z;  q[i][3] = a.w;
      q[i][4] = b4.x; q[i][5] = b4.y; q[i][6] = b4.z; q[i][7] = b4.w;
      q[i][8] = c4.x; q[i][9] = c4.y; q[i][10] = c4.z; q[i][11] = c4.w;
      q[i][12] = d4.x; q[i][13] = d4.y; q[i][14] = d4.z; q[i][15] = d4.w;
    } else {
#pragma unroll
      for (int j = 0; j < 16; j++) q[i][j] = 0.f;
    }
#pragma unroll
    for (int j = 0; j < 16; j++) acc[i][j] = 0.f;
  }

  for (int idx = tid; idx < nk * 16; idx += 256) {
    int kr = idx >> 4, kcq = (idx & 15) << 2;
    const float* kp = qkv + (rowbase + k0 + kr) * QKVD + EMB + h * 64 + kcq;
    *(float4*)&Ks[kr * 64 + kcq] = *(const float4*)kp;
    *(float4*)&Vs[kr * 64 + kcq] = *(const float4*)(kp + EMB);
  }
  __syncthreads();

  for (int k = 0; k < nk; k++) {
    const float4* kk = (const float4*)&Ks[k * 64 + c * 16];
    float4 ka = kk[0], kb = kk[1], kc4 = kk[2], kd = kk[3];
    const float4* vv = (const float4*)&Vs[k * 64 + c * 16];
    float4 v0 = vv[0], v1 = vv[1], v2 = vv[2], v3 = vv[3];
#pragma unroll
    for (int i = 0; i < 4; i++) {
      float s = q[i][0] * ka.x + q[i][1] * ka.y + q[i][2] * ka.z + q[i][3] * ka.w +
                q[i][4] * kb.x + q[i][5] * kb.y + q[i][6] * kb.z + q[i][7] * kb.w +
                q[i][8] * kc4.x + q[i][9] * kc4.y + q[i][10] * kc4.z + q[i][11] * kc4.w +
                q[i][12] * kd.x + q[i][13] * kd.y + q[i][14] * kd.z + q[i][15] * kd.w;
      s += __shfl_xor(s, 1);
      s += __shfl_xor(s, 2);
      float p = __expf(s * 0.125f);
      lsum[i] += p;
      acc[i][0] += p * v0.x;  acc[i][1] += p * v0.y;  acc[i][2] += p * v0.z;  acc[i][3] += p * v0.w;
      acc[i][4] += p * v1.x;  acc[i][5] += p * v1.y;  acc[i][6] += p * v1.z;  acc[i][7] += p * v1.w;
      acc[i][8] += p * v2.x;  acc[i][9] += p * v2.y;  acc[i][10] += p * v2.z; acc[i][11] += p * v2.w;
      acc[i][12] += p * v3.x; acc[i][13] += p * v3.y; acc[i][14] += p * v3.z; acc[i][15] += p * v3.w;
    }
  }

#pragma unroll
  for (int i = 0; i < 4; i++) {
    int row = wave * 64 + 16 * i + r4;
    if (row < NTOKC) {
      size_t pb = (((size_t)(kc * 64 + bl) * NTOKC + row) * EMB) + h * 64 + c * 16;
      float4* po = (float4*)(Pacc + pb);
      po[0] = make_float4(acc[i][0], acc[i][1], acc[i][2], acc[i][3]);
      po[1] = make_float4(acc[i][4], acc[i][5], acc[i][6], acc[i][7]);
      po[2] = make_float4(acc[i][8], acc[i][9], acc[i][10], acc[i][11]);
      po[3] = make_float4(acc[i][12], acc[i][13], acc[i][14], acc[i][15]);
      if (c == 0)
        Plsum[((size_t)(kc * 64 + bl) * NTOKC + row) * 6 + h] = lsum[i];
    }
  }
}

// combine the two k-chunk partials, normalize, emit o hi/lo pairs
__global__ __launch_bounds__(256) void attn_norm_k(
    const float* __restrict__ Pacc, const float* __restrict__ Plsum,
    f16* __restrict__ ohi, f16* __restrict__ olo, int batch0) {
  int wave = threadIdx.x >> 6, lane = threadIdx.x & 63;
  int lrow = blockIdx.x * 4 + wave;          // 0..12607
  int bl = lrow / NTOKC, row = lrow - bl * NTOKC;
  size_t b0 = ((size_t)bl * NTOKC + row) * EMB;
  size_t b1 = ((size_t)(64 + bl) * NTOKC + row) * EMB;
  size_t l0 = ((size_t)bl * NTOKC + row) * 6;
  size_t l1 = ((size_t)(64 + bl) * NTOKC + row) * 6;
  size_t ob = ((size_t)(batch0 + bl) * NTOKC + row) * EMB;
#pragma unroll
  for (int i = 0; i < 6; i++) {
    int cc = i * 64 + lane;
    float rin = 1.f / (Plsum[l0 + i] + Plsum[l1 + i]);
    float v = (Pacc[b0 + cc] + Pacc[b1 + cc]) * rin;
    f16 hh = (f16)v;
    ohi[ob + cc] = hh;
    olo[ob + cc] = (f16)(v - (float)hh);
  }
}

// ---------------- router: top-2 of 4 logits -> {0,0.5} weights ----------------
__global__ __launch_bounds__(256) void router_k(
    const float* __restrict__ hbuf, const float* __restrict__ rw,
    const float* __restrict__ rb, float* __restrict__ maskw) {
  const int tid = threadIdx.x;
  const int tl = tid >> 2, e = tid & 3;
  const int t = blockIdx.x * 64 + tl;
  const float4* h4 = (const float4*)(hbuf + (size_t)t * EMB);
  const float4* w4 = (const float4*)(rw + e * EMB);
  float s = rb[e];
#pragma unroll 8
  for (int i = 0; i < 96; i++) {
    float4 a = h4[i], w = w4[i];
    s += a.x * w.x + a.y * w.y + a.z * w.z + a.w * w.w;
  }
  int lane = tid & 63;
  int base = lane & ~3;
  float l0 = __shfl(s, base + 0);
  float l1 = __shfl(s, base + 1);
  float l2 = __shfl(s, base + 2);
  float l3 = __shfl(s, base + 3);
  int i1 = 0; float b1 = l0;
  if (l1 > b1) { b1 = l1; i1 = 1; }
  if (l2 > b1) { b1 = l2; i1 = 2; }
  if (l3 > b1) { b1 = l3; i1 = 3; }
  int i2 = -1; float b2 = 0.f;
  float lv[4] = {l0, l1, l2, l3};
#pragma unroll
  for (int i = 0; i < 4; i++) {
    if (i == i1) continue;
    if (i2 < 0 || lv[i] > b2) { i2 = i; b2 = lv[i]; }
  }
  maskw[(size_t)t * 4 + e] = (e == i1 || e == i2) ? 0.5f : 0.f;
}

// ---------------- fused LN2 + classification head on cls rows ----------------
__global__ __launch_bounds__(256) void head_k(
    const float* __restrict__ moe, const float* __restrict__ g, const float* __restrict__ bb,
    const float* __restrict__ hw, const float* __restrict__ hb, float* __restrict__ outp) {
  __shared__ float sh[EMB];
  __shared__ float red[8];
  int b = blockIdx.x, tid = threadIdx.x;
  const float* xp = moe + (size_t)b * NTOKC * EMB;  // cls row
  float v0 = xp[tid];
  float v1 = (tid < 128) ? xp[256 + tid] : 0.f;
  float s = v0 + v1, sq = v0 * v0 + v1 * v1;
  int lane = tid & 63, wave = tid >> 6;
#pragma unroll
  for (int off = 32; off; off >>= 1) {
    s += __shfl_xor(s, off);
    sq += __shfl_xor(sq, off);
  }
  if (lane == 0) { red[wave] = s; red[4 + wave] = sq; }
  __syncthreads();
  float S = red[0] + red[1] + red[2] + red[3];
  float SQ = red[4] + red[5] + red[6] + red[7];
  float m = S * (1.f / 384.f);
  float var = SQ * (1.f / 384.f) - m * m;
  float rs = rsqrtf(var + 1e-5f);
  sh[tid] = (v0 - m) * rs * g[tid] + bb[tid];
  if (tid < 128) sh[256 + tid] = (v1 - m) * rs * g[256 + tid] + bb[256 + tid];
  __syncthreads();
  for (int n = tid; n < 1000; n += 256) {
    const float4* w4 = (const float4*)(hw + (size_t)n * EMB);
    const float4* s4 = (const float4*)sh;
    float a = hb[n];
#pragma unroll 8
    for (int i = 0; i < 96; i++) {
      float4 x = s4[i], w = w4[i];
      a += x.x * w.x + x.y * w.y + x.z * w.z + x.w * w.w;
    }
    outp[(size_t)b * 1000 + n] = a;
  }
}

// ---------------- host ----------------
extern "C" void kernel_launch(void* const* d_in, const int* in_sizes, int n_in,
                              void* d_out, int out_size, void* d_ws, size_t ws_size,
                              hipStream_t stream) {
  const float* x      = (const float*)d_in[0];
  const float* conv_w = (const float*)d_in[1];
  const float* conv_b = (const float*)d_in[2];
  const float* cls_t  = (const float*)d_in[3];
  const float* pos    = (const float*)d_in[4];
  const float* ln1_g  = (const float*)d_in[5];
  const float* ln1_b  = (const float*)d_in[6];
  const float* inp_w  = (const float*)d_in[7];
  const float* inp_b  = (const float*)d_in[8];
  const float* outp_w = (const float*)d_in[9];
  const float* outp_b = (const float*)d_in[10];
  const float* rt_w   = (const float*)d_in[11];
  const float* rt_b   = (const float*)d_in[12];
  const float* ew1    = (const float*)d_in[13];
  const float* eb1    = (const float*)d_in[14];
  const float* ew2    = (const float*)d_in[15];
  const float* eb2    = (const float*)d_in[16];
  const float* ln2_g  = (const float*)d_in[17];
  const float* ln2_b  = (const float*)d_in[18];
  const float* head_w = (const float*)d_in[19];
  const float* head_b = (const float*)d_in[20];
  float* out = (float*)d_out;
  char* w = (char*)d_ws;
  if (ws_size < WS_NEEDED) return;

  f16* convw_hi = (f16*)(w + OFF_CONVW_HI);
  f16* convw_lo = (f16*)(w + OFF_CONVW_LO);
  f16* inpw_hi  = (f16*)(w + OFF_INPW_HI);
  f16* inpw_lo  = (f16*)(w + OFF_INPW_LO);
  f16* outpw_hi = (f16*)(w + OFF_OUTPW_HI);
  f16* outpw_lo = (f16*)(w + OFF_OUTPW_LO);
  f16* ew1t     = (f16*)(w + OFF_EW1T);
  f16* ew2t     = (f16*)(w + OFF_EW2T);
  float* maskw  = (float*)(w + OFF_MASKW);
  float* Hbuf   = (float*)(w + OFF_H);      // h0 / attn-partials / o2 / moe_acc
  f16* o_hi     = (f16*)(w + OFF_P);        // attn-out pairs
  f16* o_lo     = (f16*)(w + OFF_P + SZ_TE_F16);
  float* Pf32   = (float*)(w + OFF_P);      // later: h f32 (router input)
  f16* x_hi     = (f16*)(w + OFF_XHI);      // hn pairs, later h f16
  f16* x_lo     = (f16*)(w + OFF_XLO);
  float* qkvbuf = (float*)(w + OFF_Q);
  f16* ehbuf    = (f16*)(w + OFF_Q);
  float* Plsum  = (float*)(w + OFF_Q + SZ_QKVCH);  // tail of qkv region

  // ---- weight prep ----
  split_pairs_k<<<dim3((294912 + 255) / 256), dim3(256), 0, stream>>>(conv_w, convw_hi, convw_lo, 294912);
  split_pairs_k<<<dim3((442368 + 255) / 256), dim3(256), 0, stream>>>(inp_w, inpw_hi, inpw_lo, 442368);
  split_pairs_k<<<dim3((147456 + 255) / 256), dim3(256), 0, stream>>>(outp_w, outpw_hi, outpw_lo, 147456);
  transpose_cast_k<<<dim3(48, 12, 4), dim3(256), 0, stream>>>(ew1, ew1t, 384, 1536);
  transpose_cast_k<<<dim3(12, 48, 4), dim3(256), 0, stream>>>(ew2, ew2t, 1536, 384);

  // ---- patch embed -> h0 (Hbuf) ----
  embed_k<<<dim3(3, 196), dim3(256), 0, stream>>>(x, convw_hi, convw_lo, conv_b, pos, Hbuf);
  cls_init_k<<<dim3(128), dim3(384), 0, stream>>>(cls_t, pos, Hbuf);

  // ---- LN1 -> hn pairs ----
  ln_k<0, 1, 0><<<dim3(TTOK / 4), dim3(256), 0, stream>>>(
      Hbuf, ln1_g, ln1_b, nullptr, x_hi, x_lo, nullptr);

  // ---- QKV + attention, two batch-chunks of 64 ----
  for (int ch = 0; ch < 2; ch++) {
    gemm_x2_k<<<dim3(9, 99), dim3(256), 0, stream>>>(
        x_hi, x_lo, inpw_hi, inpw_lo, inp_b, qkvbuf,
        EMB, QKVD, ch * 98, ch * CHROWS, ch * CHROWS + CHROWS, ch * CHROWS);
    attn_k<<<dim3(6, 64, 2), dim3(256), 0, stream>>>(qkvbuf, Hbuf, Plsum);
    attn_norm_k<<<dim3(CHROWS / 4), dim3(256), 0, stream>>>(Hbuf, Plsum, o_hi, o_lo, ch * 64);
  }

  // ---- out-proj -> o2 (Hbuf) ----
  gemm_x2_k<<<dim3(3, 197), dim3(256), 0, stream>>>(
      o_hi, o_lo, outpw_hi, outpw_lo, outp_b, Hbuf,
      EMB, EMB, 0, 0, TTOK, 0);

  // ---- LN (same params) -> h f32 (Pf32) + h f16 (x_hi) ----
  ln_k<1, 0, 1><<<dim3(TTOK / 4), dim3(256), 0, stream>>>(
      Hbuf, ln1_g, ln1_b, Pf32, nullptr, nullptr, x_hi);

  // ---- router top-2 -> mask weights ----
  router_k<<<dim3(TTOK / 64), dim3(256), 0, stream>>>(Pf32, rt_w, rt_b, maskw);

  // ---- MoE: dense per-expert FFN with masked 0.5x accumulation into Hbuf ----
  for (int e = 0; e < 4; e++) {
    gemm_x1_k<0><<<dim3(12, 197), dim3(256), 0, stream>>>(
        x_hi, ew1t + (size_t)e * HID * EMB, eb1 + e * HID, nullptr,
        nullptr, ehbuf, EMB, HID, e, 0);
    gemm_x1_k<1><<<dim3(3, 197), dim3(256), 0, stream>>>(
        ehbuf, ew2t + (size_t)e * EMB * HID, eb2 + e * EMB, maskw,
        Hbuf, nullptr, HID, EMB, e, e ? 1 : 0);
  }

  // ---- LN2 + head on cls rows ----
  head_k<<<dim3(128), dim3(256), 0, stream>>>(Hbuf, ln2_g, ln2_b, head_w, head_b, out);
  (void)in_sizes; (void)n_in; (void)out_size;
}

// Round 4
// 522.709 us; speedup vs baseline: 2.7400x; 2.5230x over previous
//
#include <hip/hip_runtime.h>
#include <cstdint>
#include <cstddef>

typedef _Float16 f16;
typedef _Float16 f16x8 __attribute__((ext_vector_type(8)));
typedef float    f32x4 __attribute__((ext_vector_type(4)));

// ---------------- problem constants ----------------
constexpr int NTOKC  = 197;
constexpr int TTOK   = 128 * 197;         // 25216
constexpr int MROWS  = 128 * 196;         // 25088 (patch rows)
constexpr int EMB    = 384;
constexpr int HID    = 1536;

// ---------------- workspace layout (bytes) ----------------
constexpr size_t OFF_CONVW_HI = 0;                      // 384*768*2
constexpr size_t OFF_CONVW_LO = 589824;
constexpr size_t OFF_KVW_HI   = 1179648;                // 768*384*2 (in_proj rows 384..1151)
constexpr size_t OFF_KVW_LO   = 1769472;
constexpr size_t OFF_EW1T     = 2359296;                // 4*1536*384*2
constexpr size_t OFF_EW2T     = 7077888;
constexpr size_t OFF_QCLS     = 11796480;               // 128*384 f32
constexpr size_t OFF_OCLS     = 11993088;
constexpr size_t OFF_O2CLS    = 12189696;
constexpr size_t OFF_HCLS32   = 12386304;
constexpr size_t OFF_HCLS16   = 12582912;               // 128*384 f16
constexpr size_t OFF_MASKW    = 12681216;               // 128*4 f32
constexpr size_t OFF_EH       = 12683264;               // 4*128*1536 f16
constexpr size_t OFF_EO       = 14256128;               // 4*128*384 f32
constexpr size_t OFF_H        = 15042560;               // TTOK*384 f32 (embed out)
constexpr size_t OFF_XHI      = 53774336;               // TTOK*384 f16 (ln1 hi)
constexpr size_t OFF_XLO      = 73140224;               // TTOK*384 f16 (ln1 lo)
constexpr size_t OFF_KV       = 92506112;               // TTOK*768 f32 (K|V); earlier: im2col planes
constexpr size_t OFF_AIM_HI   = OFF_KV;                 // MROWS*768 f16 = 38,535,168
constexpr size_t OFF_AIM_LO   = OFF_KV + 38535168;
constexpr size_t WS_NEEDED    = OFF_KV + 77463552;      // ~170 MB

// ---------------- global_load_lds helper ----------------
__device__ __forceinline__ void gload16(const void* g, void* l) {
  __builtin_amdgcn_global_load_lds(
      (__attribute__((address_space(1))) void*)(void*)g,
      (__attribute__((address_space(3))) void*)l, 16, 0, 0);
}

// ---------------- prep kernels ----------------
__global__ __launch_bounds__(256) void split_pairs_k(
    const float* __restrict__ in, f16* __restrict__ hi, f16* __restrict__ lo, int n) {
  int i = blockIdx.x * 256 + threadIdx.x;
  if (i < n) {
    float v = in[i];
    f16 h = (f16)v;
    hi[i] = h;
    lo[i] = (f16)(v - (float)h);
  }
}

// in f32 [R][C] -> out f16 [C][R] per expert slice
__global__ __launch_bounds__(256) void transpose_cast_k(
    const float* __restrict__ in, f16* __restrict__ outp, int R, int C) {
  __shared__ float tile[32][33];
  int e = blockIdx.z;
  const float* pin = in + (size_t)e * R * C;
  f16* pout = outp + (size_t)e * R * C;
  int c0 = blockIdx.x * 32, r0 = blockIdx.y * 32;
  int tx = threadIdx.x & 31, ty = threadIdx.x >> 5;
#pragma unroll
  for (int i = 0; i < 4; i++)
    tile[ty + 8 * i][tx] = pin[(size_t)(r0 + ty + 8 * i) * C + c0 + tx];
  __syncthreads();
#pragma unroll
  for (int i = 0; i < 4; i++)
    pout[(size_t)(c0 + ty + 8 * i) * R + r0 + tx] = (f16)tile[tx][ty + 8 * i];
}

__global__ void cls_init_k(const float* __restrict__ cls, const float* __restrict__ posw,
                           float* __restrict__ h0) {
  int b = blockIdx.x, c = threadIdx.x;  // block = 384 threads
  h0[(size_t)b * NTOKC * EMB + c] = cls[c] + posw[c];
}

// ---------------- im2col + fp16 split of the image ----------------
// grid (14=py, 3=cch, 128=b), block 256. A[row=b*196+py*14+px][k=cch*256+ky*16+kx]
__global__ __launch_bounds__(256) void im2col_k(
    const float* __restrict__ img, f16* __restrict__ Ahi, f16* __restrict__ Alo) {
  __shared__ float tile[16 * 224];
  int py = blockIdx.x, cch = blockIdx.y, b = blockIdx.z;
  const float* src = img + ((size_t)(b * 3 + cch) * 224 + py * 16) * 224;
  for (int i = threadIdx.x; i < 16 * 224; i += 256) tile[i] = src[i];
  __syncthreads();
  if (threadIdx.x < 224) {
    int px = threadIdx.x >> 4, ky = threadIdx.x & 15;
    size_t outb = ((size_t)(b * 196 + py * 14 + px)) * 768 + cch * 256 + ky * 16;
    f16 hv[16] __attribute__((aligned(16)));
    f16 lv[16] __attribute__((aligned(16)));
#pragma unroll
    for (int t = 0; t < 16; t++) {
      float v = tile[ky * 224 + px * 16 + t];
      f16 hh = (f16)v;
      hv[t] = hh;
      lv[t] = (f16)(v - (float)hh);
    }
    ((uint4*)(Ahi + outb))[0] = ((uint4*)hv)[0];
    ((uint4*)(Ahi + outb))[1] = ((uint4*)hv)[1];
    ((uint4*)(Alo + outb))[0] = ((uint4*)lv)[0];
    ((uint4*)(Alo + outb))[1] = ((uint4*)lv)[1];
  }
}

// ---------------- fp16x2 split GEMM, global_load_lds staging: C = A*B^T ----------------
// EMBED=1: remap output rows (skip cls) and add pos_embed.
template <int EMBED>
__global__ __launch_bounds__(256) void gemm_x2_k(
    const f16* __restrict__ Ahi, const f16* __restrict__ Alo,
    const f16* __restrict__ Bhi, const f16* __restrict__ Blo,
    const float* __restrict__ bias, const float* __restrict__ posw,
    float* __restrict__ Cout, int K, int N) {
  __shared__ f16 Ash[128 * 32];
  __shared__ f16 Asl[128 * 32];
  __shared__ f16 Bsh[128 * 32];
  __shared__ f16 Bsl[128 * 32];
  const int tid = threadIdx.x;
  const int lane = tid & 63;
  const int wave = tid >> 6;
  const int m0 = (int)blockIdx.y * 128;
  const int n0 = (int)blockIdx.x * 128;
  const int wm = (wave >> 1) * 64;
  const int wn = (wave & 1) * 64;
  const int fr = lane & 15;
  const int fq = lane >> 4;

  f32x4 acc[4][4];
#pragma unroll
  for (int i = 0; i < 4; i++)
#pragma unroll
    for (int j = 0; j < 4; j++) acc[i][j] = f32x4{0.f, 0.f, 0.f, 0.f};

  const int srow = wave * 32 + (lane >> 2);
  const int scol = (lane & 3) * 8;
  const f16* agh = Ahi + (size_t)(m0 + srow) * K + scol;
  const f16* agl = Alo + (size_t)(m0 + srow) * K + scol;
  const f16* bgh = Bhi + (size_t)(n0 + srow) * K + scol;
  const f16* bgl = Blo + (size_t)(n0 + srow) * K + scol;
  const size_t rstep = (size_t)16 * K;
  f16* lah = Ash + wave * 32 * 32;
  f16* lal = Asl + wave * 32 * 32;
  f16* lbh = Bsh + wave * 32 * 32;
  f16* lbl = Bsl + wave * 32 * 32;

  for (int k0 = 0; k0 < K; k0 += 32) {
    gload16(agh, lah);          gload16(agh + rstep, lah + 16 * 32);
    gload16(agl, lal);          gload16(agl + rstep, lal + 16 * 32);
    gload16(bgh, lbh);          gload16(bgh + rstep, lbh + 16 * 32);
    gload16(bgl, lbl);          gload16(bgl + rstep, lbl + 16 * 32);
    agh += 32; agl += 32; bgh += 32; bgl += 32;
    __syncthreads();

    f16x8 ah[4], al[4], bh[4], bl[4];
#pragma unroll
    for (int i = 0; i < 4; i++) {
      int ra = (wm + i * 16 + fr) * 32 + fq * 8;
      ah[i] = *(const f16x8*)&Ash[ra];
      al[i] = *(const f16x8*)&Asl[ra];
      int rb = (wn + i * 16 + fr) * 32 + fq * 8;
      bh[i] = *(const f16x8*)&Bsh[rb];
      bl[i] = *(const f16x8*)&Bsl[rb];
    }
#pragma unroll
    for (int i = 0; i < 4; i++)
#pragma unroll
      for (int j = 0; j < 4; j++) {
        acc[i][j] = __builtin_amdgcn_mfma_f32_16x16x32_f16(ah[i], bh[j], acc[i][j], 0, 0, 0);
        acc[i][j] = __builtin_amdgcn_mfma_f32_16x16x32_f16(ah[i], bl[j], acc[i][j], 0, 0, 0);
        acc[i][j] = __builtin_amdgcn_mfma_f32_16x16x32_f16(al[i], bh[j], acc[i][j], 0, 0, 0);
      }
    __syncthreads();
  }

#pragma unroll
  for (int i = 0; i < 4; i++)
#pragma unroll
    for (int j = 0; j < 4; j++)
#pragma unroll
      for (int rg = 0; rg < 4; rg++) {
        int gm = m0 + wm + i * 16 + fq * 4 + rg;
        int gn = n0 + wn + j * 16 + fr;
        float v = acc[i][j][rg] + bias[gn];
        if (EMBED) {
          int bb = gm / 196;
          int pp = gm - bb * 196;
          Cout[((size_t)bb * NTOKC + pp + 1) * EMB + gn] =
              v + posw[(size_t)(pp + 1) * EMB + gn];
        } else {
          Cout[(size_t)gm * N + gn] = v;
        }
      }
}

// ---------------- MoE fp16 GEMM over 128 cls tokens, all experts fused ----------------
// grid (n_tiles, 4 experts). GELU=1: f16 GELU out; else f32 + bias out.
template <int GELU>
__global__ __launch_bounds__(256) void moe_gemm_k(
    const f16* __restrict__ A, size_t aestride,
    const f16* __restrict__ Bm, size_t bestride,
    const float* __restrict__ bias, int biasstride,
    f16* __restrict__ outh, float* __restrict__ outf, size_t ostride,
    int K, int N) {
  __shared__ f16 As[128 * 32];
  __shared__ f16 Bs[128 * 32];
  const int tid = threadIdx.x;
  const int lane = tid & 63;
  const int wave = tid >> 6;
  const int e = (int)blockIdx.y;
  const int n0 = (int)blockIdx.x * 128;
  const int wm = (wave >> 1) * 64;
  const int wn = (wave & 1) * 64;
  const int fr = lane & 15;
  const int fq = lane >> 4;
  A += (size_t)e * aestride;
  Bm += (size_t)e * bestride;
  bias += (size_t)e * biasstride;

  f32x4 acc[4][4];
#pragma unroll
  for (int i = 0; i < 4; i++)
#pragma unroll
    for (int j = 0; j < 4; j++) acc[i][j] = f32x4{0.f, 0.f, 0.f, 0.f};

  const int srow = wave * 32 + (lane >> 2);
  const int scol = (lane & 3) * 8;
  const f16* ag = A + (size_t)srow * K + scol;
  const f16* bg = Bm + (size_t)(n0 + srow) * K + scol;
  const size_t rstep = (size_t)16 * K;
  f16* la = As + wave * 32 * 32;
  f16* lb = Bs + wave * 32 * 32;

  for (int k0 = 0; k0 < K; k0 += 32) {
    gload16(ag, la);          gload16(ag + rstep, la + 16 * 32);
    gload16(bg, lb);          gload16(bg + rstep, lb + 16 * 32);
    ag += 32; bg += 32;
    __syncthreads();
    f16x8 af[4], bf[4];
#pragma unroll
    for (int i = 0; i < 4; i++) {
      af[i] = *(const f16x8*)&As[(wm + i * 16 + fr) * 32 + fq * 8];
      bf[i] = *(const f16x8*)&Bs[(wn + i * 16 + fr) * 32 + fq * 8];
    }
#pragma unroll
    for (int i = 0; i < 4; i++)
#pragma unroll
      for (int j = 0; j < 4; j++)
        acc[i][j] = __builtin_amdgcn_mfma_f32_16x16x32_f16(af[i], bf[j], acc[i][j], 0, 0, 0);
    __syncthreads();
  }

#pragma unroll
  for (int i = 0; i < 4; i++)
#pragma unroll
    for (int j = 0; j < 4; j++)
#pragma unroll
      for (int rg = 0; rg < 4; rg++) {
        int gm = wm + i * 16 + fq * 4 + rg;
        int gn = n0 + wn + j * 16 + fr;
        float v = acc[i][j][rg] + bias[gn];
        if (GELU) {
          float g = 0.5f * v * (1.0f + erff(v * 0.70710678118654752f));  // exact GELU
          outh[(size_t)e * ostride + (size_t)gm * N + gn] = (f16)g;
        } else {
          outf[(size_t)e * ostride + (size_t)gm * N + gn] = v;
        }
      }
}

// ---------------- LayerNorm (row=384) ----------------
template <int OUTF32, int OUTPAIR, int OUTH>
__global__ __launch_bounds__(256) void ln_k(
    const float* __restrict__ in, const float* __restrict__ g, const float* __restrict__ bb,
    float* __restrict__ of, f16* __restrict__ ohi, f16* __restrict__ olo, f16* __restrict__ oh) {
  int wave = threadIdx.x >> 6, lane = threadIdx.x & 63;
  size_t row = (size_t)blockIdx.x * 4 + wave;
  const float* xp = in + row * EMB;
  float v[6];
  float s = 0.f, sq = 0.f;
#pragma unroll
  for (int i = 0; i < 6; i++) {
    v[i] = xp[lane + 64 * i];
    s += v[i];
    sq += v[i] * v[i];
  }
#pragma unroll
  for (int off = 32; off; off >>= 1) {
    s += __shfl_xor(s, off);
    sq += __shfl_xor(sq, off);
  }
  float m = s * (1.f / 384.f);
  float var = sq * (1.f / 384.f) - m * m;
  float rs = rsqrtf(var + 1e-5f);
#pragma unroll
  for (int i = 0; i < 6; i++) {
    int c = lane + 64 * i;
    float y = (v[i] - m) * rs * g[c] + bb[c];
    size_t o = row * EMB + c;
    if (OUTF32) of[o] = y;
    if (OUTPAIR) {
      f16 hh = (f16)y;
      ohi[o] = hh;
      olo[o] = (f16)(y - (float)hh);
    }
    if (OUTH) oh[o] = (f16)y;
  }
}

// ---------------- cls-row projection (exact f32): out[col] = b[col] + x . W[col,:] ------
// grid (128), block 384. x from hi+lo pairs at row b*197 (ROWSEL=0) or dense row b (ROWSEL=1).
template <int PAIRIN>
__global__ __launch_bounds__(384) void rowproj_k(
    const f16* __restrict__ xhi, const f16* __restrict__ xlo, const float* __restrict__ xf,
    const float* __restrict__ W, const float* __restrict__ bias,
    float* __restrict__ outp, int rowstride) {
  __shared__ float hx[EMB];
  int b = blockIdx.x, t = threadIdx.x;
  size_t rb = (size_t)b * rowstride * EMB;
  if (PAIRIN)
    hx[t] = (float)xhi[rb + t] + (float)xlo[rb + t];
  else
    hx[t] = xf[rb + t];
  __syncthreads();
  const float4* w4 = (const float4*)(W + (size_t)t * EMB);
  const float4* s4 = (const float4*)hx;
  float a = bias[t];
#pragma unroll 8
  for (int i = 0; i < 96; i++) {
    float4 x = s4[i], w = w4[i];
    a += x.x * w.x + x.y * w.y + x.z * w.z + x.w * w.w;
  }
  outp[(size_t)b * EMB + t] = a;
}

// ---------------- cls attention (exact f32), one wave per (head, batch) ----------------
// kv row layout: [t][768] = K(384) | V(384). q from qcls[128][384].
__global__ __launch_bounds__(64) void attn_cls_k(
    const float* __restrict__ kv, const float* __restrict__ qcls,
    float* __restrict__ ocls) {
  __shared__ float qs[64];
  __shared__ float red[64][65];
  const int h = blockIdx.x, b = blockIdx.y;
  const int lane = threadIdx.x;
  qs[lane] = qcls[(size_t)b * EMB + h * 64 + lane];
  __syncthreads();

  float accv[64];
#pragma unroll
  for (int d = 0; d < 64; d++) accv[d] = 0.f;
  float lsum = 0.f;

  for (int r = 0; r < 4; r++) {
    int row = lane + r * 64;
    if (row < NTOKC) {
      const float4* kp = (const float4*)(kv + ((size_t)b * NTOKC + row) * 768 + h * 64);
      float s0 = 0.f, s1 = 0.f, s2 = 0.f, s3 = 0.f;
#pragma unroll
      for (int i = 0; i < 16; i++) {
        float4 kk = kp[i];
        s0 += qs[i * 4 + 0] * kk.x;
        s1 += qs[i * 4 + 1] * kk.y;
        s2 += qs[i * 4 + 2] * kk.z;
        s3 += qs[i * 4 + 3] * kk.w;
      }
      float p = __expf((s0 + s1 + s2 + s3) * 0.125f);
      lsum += p;
      const float4* vp = (const float4*)(kv + ((size_t)b * NTOKC + row) * 768 + 384 + h * 64);
#pragma unroll
      for (int i = 0; i < 16; i++) {
        float4 vv = vp[i];
        accv[i * 4 + 0] += p * vv.x;
        accv[i * 4 + 1] += p * vv.y;
        accv[i * 4 + 2] += p * vv.z;
        accv[i * 4 + 3] += p * vv.w;
      }
    }
  }
#pragma unroll
  for (int d = 0; d < 64; d++) red[lane][d] = accv[d];
#pragma unroll
  for (int off = 32; off; off >>= 1) lsum += __shfl_xor(lsum, off);
  __syncthreads();
  float o = 0.f;
#pragma unroll
  for (int r = 0; r < 64; r++) o += red[r][lane];
  ocls[(size_t)b * EMB + h * 64 + lane] = o / lsum;
}

// ---------------- router on 128 cls rows: top-2 of 4 -> {0,0.5} ----------------
__global__ __launch_bounds__(256) void router_k(
    const float* __restrict__ hbuf, const float* __restrict__ rw,
    const float* __restrict__ rb, float* __restrict__ maskw) {
  const int tid = threadIdx.x;
  const int tl = tid >> 2, e = tid & 3;
  const int t = blockIdx.x * 64 + tl;
  const float4* h4 = (const float4*)(hbuf + (size_t)t * EMB);
  const float4* w4 = (const float4*)(rw + e * EMB);
  float s = rb[e];
#pragma unroll 8
  for (int i = 0; i < 96; i++) {
    float4 a = h4[i], w = w4[i];
    s += a.x * w.x + a.y * w.y + a.z * w.z + a.w * w.w;
  }
  int lane = tid & 63;
  int base = lane & ~3;
  float l0 = __shfl(s, base + 0);
  float l1 = __shfl(s, base + 1);
  float l2 = __shfl(s, base + 2);
  float l3 = __shfl(s, base + 3);
  int i1 = 0; float b1 = l0;
  if (l1 > b1) { b1 = l1; i1 = 1; }
  if (l2 > b1) { b1 = l2; i1 = 2; }
  if (l3 > b1) { b1 = l3; i1 = 3; }
  int i2 = -1; float b2 = 0.f;
  float lv[4] = {l0, l1, l2, l3};
#pragma unroll
  for (int i = 0; i < 4; i++) {
    if (i == i1) continue;
    if (i2 < 0 || lv[i] > b2) { i2 = i; b2 = lv[i]; }
  }
  maskw[(size_t)t * 4 + e] = (e == i1 || e == i2) ? 0.5f : 0.f;
}

// ---------------- expert combine + LN2 + classification head ----------------
__global__ __launch_bounds__(256) void head_k(
    const float* __restrict__ eo, const float* __restrict__ maskw,
    const float* __restrict__ g, const float* __restrict__ bb,
    const float* __restrict__ hw, const float* __restrict__ hb, float* __restrict__ outp) {
  __shared__ float sh[EMB];
  __shared__ float red[8];
  int b = blockIdx.x, tid = threadIdx.x;
  float mw0 = maskw[b * 4 + 0], mw1 = maskw[b * 4 + 1];
  float mw2 = maskw[b * 4 + 2], mw3 = maskw[b * 4 + 3];
  const size_t eb = (size_t)b * EMB;
  const size_t es = (size_t)128 * EMB;
  float v0 = mw0 * eo[eb + tid] + mw1 * eo[es + eb + tid] +
             mw2 * eo[2 * es + eb + tid] + mw3 * eo[3 * es + eb + tid];
  float v1 = 0.f;
  if (tid < 128) {
    int c = 256 + tid;
    v1 = mw0 * eo[eb + c] + mw1 * eo[es + eb + c] +
         mw2 * eo[2 * es + eb + c] + mw3 * eo[3 * es + eb + c];
  }
  float s = v0 + v1, sq = v0 * v0 + v1 * v1;
  int lane = tid & 63, wave = tid >> 6;
#pragma unroll
  for (int off = 32; off; off >>= 1) {
    s += __shfl_xor(s, off);
    sq += __shfl_xor(sq, off);
  }
  if (lane == 0) { red[wave] = s; red[4 + wave] = sq; }
  __syncthreads();
  float S = red[0] + red[1] + red[2] + red[3];
  float SQ = red[4] + red[5] + red[6] + red[7];
  float m = S * (1.f / 384.f);
  float var = SQ * (1.f / 384.f) - m * m;
  float rs = rsqrtf(var + 1e-5f);
  sh[tid] = (v0 - m) * rs * g[tid] + bb[tid];
  if (tid < 128) sh[256 + tid] = (v1 - m) * rs * g[256 + tid] + bb[256 + tid];
  __syncthreads();
  for (int n = tid; n < 1000; n += 256) {
    const float4* w4 = (const float4*)(hw + (size_t)n * EMB);
    const float4* s4 = (const float4*)sh;
    float a = hb[n];
#pragma unroll 8
    for (int i = 0; i < 96; i++) {
      float4 x = s4[i], w = w4[i];
      a += x.x * w.x + x.y * w.y + x.z * w.z + x.w * w.w;
    }
    outp[(size_t)b * 1000 + n] = a;
  }
}

// ---------------- host ----------------
extern "C" void kernel_launch(void* const* d_in, const int* in_sizes, int n_in,
                              void* d_out, int out_size, void* d_ws, size_t ws_size,
                              hipStream_t stream) {
  const float* x      = (const float*)d_in[0];
  const float* conv_w = (const float*)d_in[1];
  const float* conv_b = (const float*)d_in[2];
  const float* cls_t  = (const float*)d_in[3];
  const float* pos    = (const float*)d_in[4];
  const float* ln1_g  = (const float*)d_in[5];
  const float* ln1_b  = (const float*)d_in[6];
  const float* inp_w  = (const float*)d_in[7];
  const float* inp_b  = (const float*)d_in[8];
  const float* outp_w = (const float*)d_in[9];
  const float* outp_b = (const float*)d_in[10];
  const float* rt_w   = (const float*)d_in[11];
  const float* rt_b   = (const float*)d_in[12];
  const float* ew1    = (const float*)d_in[13];
  const float* eb1    = (const float*)d_in[14];
  const float* ew2    = (const float*)d_in[15];
  const float* eb2    = (const float*)d_in[16];
  const float* ln2_g  = (const float*)d_in[17];
  const float* ln2_b  = (const float*)d_in[18];
  const float* head_w = (const float*)d_in[19];
  const float* head_b = (const float*)d_in[20];
  float* out = (float*)d_out;
  char* w = (char*)d_ws;
  if (ws_size < WS_NEEDED) return;

  f16* convw_hi = (f16*)(w + OFF_CONVW_HI);
  f16* convw_lo = (f16*)(w + OFF_CONVW_LO);
  f16* kvw_hi   = (f16*)(w + OFF_KVW_HI);
  f16* kvw_lo   = (f16*)(w + OFF_KVW_LO);
  f16* ew1t     = (f16*)(w + OFF_EW1T);
  f16* ew2t     = (f16*)(w + OFF_EW2T);
  float* qcls   = (float*)(w + OFF_QCLS);
  float* ocls   = (float*)(w + OFF_OCLS);
  float* o2cls  = (float*)(w + OFF_O2CLS);
  float* hcls32 = (float*)(w + OFF_HCLS32);
  f16* hcls16   = (f16*)(w + OFF_HCLS16);
  float* maskw  = (float*)(w + OFF_MASKW);
  f16* ehbuf    = (f16*)(w + OFF_EH);
  float* eobuf  = (float*)(w + OFF_EO);
  float* Hbuf   = (float*)(w + OFF_H);
  f16* x_hi     = (f16*)(w + OFF_XHI);
  f16* x_lo     = (f16*)(w + OFF_XLO);
  float* kvbuf  = (float*)(w + OFF_KV);
  f16* aim_hi   = (f16*)(w + OFF_AIM_HI);
  f16* aim_lo   = (f16*)(w + OFF_AIM_LO);

  // ---- weight prep ----
  split_pairs_k<<<dim3((294912 + 255) / 256), 256, 0, stream>>>(conv_w, convw_hi, convw_lo, 294912);
  split_pairs_k<<<dim3((294912 + 255) / 256), 256, 0, stream>>>(inp_w + 384 * 384, kvw_hi, kvw_lo, 294912);
  transpose_cast_k<<<dim3(48, 12, 4), 256, 0, stream>>>(ew1, ew1t, 384, 1536);
  transpose_cast_k<<<dim3(12, 48, 4), 256, 0, stream>>>(ew2, ew2t, 1536, 384);

  // ---- im2col split + patch-embed GEMM -> Hbuf ----
  im2col_k<<<dim3(14, 3, 128), 256, 0, stream>>>(x, aim_hi, aim_lo);
  gemm_x2_k<1><<<dim3(3, 196), 256, 0, stream>>>(
      aim_hi, aim_lo, convw_hi, convw_lo, conv_b, pos, Hbuf, 768, EMB);
  cls_init_k<<<dim3(128), dim3(384), 0, stream>>>(cls_t, pos, Hbuf);

  // ---- LN1 -> hn pairs (all tokens) ----
  ln_k<0, 1, 0><<<dim3(TTOK / 4), 256, 0, stream>>>(
      Hbuf, ln1_g, ln1_b, nullptr, x_hi, x_lo, nullptr);

  // ---- K,V projection for all tokens (2/3 of in_proj) ----
  gemm_x2_k<0><<<dim3(6, 197), 256, 0, stream>>>(
      x_hi, x_lo, kvw_hi, kvw_lo, inp_b + 384, nullptr, kvbuf, EMB, 768);

  // ---- Q projection for cls rows only (exact f32) ----
  rowproj_k<1><<<dim3(128), 384, 0, stream>>>(
      x_hi, x_lo, nullptr, inp_w, inp_b, qcls, NTOKC);

  // ---- cls attention (exact f32) ----
  attn_cls_k<<<dim3(6, 128), 64, 0, stream>>>(kvbuf, qcls, ocls);

  // ---- out-proj on cls rows (exact f32) ----
  rowproj_k<0><<<dim3(128), 384, 0, stream>>>(
      nullptr, nullptr, ocls, outp_w, outp_b, o2cls, 1);

  // ---- LN (same ln1 params) on cls rows -> f32 + f16 ----
  ln_k<1, 0, 1><<<dim3(32), 256, 0, stream>>>(
      o2cls, ln1_g, ln1_b, hcls32, nullptr, nullptr, hcls16);

  // ---- router top-2 on cls rows ----
  router_k<<<dim3(2), 256, 0, stream>>>(hcls32, rt_w, rt_b, maskw);

  // ---- MoE on 128 cls tokens, all 4 experts fused per launch ----
  moe_gemm_k<1><<<dim3(12, 4), 256, 0, stream>>>(
      hcls16, 0, ew1t, (size_t)HID * EMB, eb1, HID,
      ehbuf, nullptr, (size_t)128 * HID, EMB, HID);
  moe_gemm_k<0><<<dim3(3, 4), 256, 0, stream>>>(
      ehbuf, (size_t)128 * HID, ew2t, (size_t)EMB * HID, eb2, EMB,
      nullptr, eobuf, (size_t)128 * EMB, HID, EMB);

  // ---- combine + LN2 + head ----
  head_k<<<dim3(128), 256, 0, stream>>>(eobuf, maskw, ln2_g, ln2_b, head_w, head_b, out);
  (void)in_sizes; (void)n_in; (void)out_size;
}

// Round 5
// 428.606 us; speedup vs baseline: 3.3415x; 1.2196x over previous
//
#include <hip/hip_runtime.h>
#include <cstdint>
#include <cstddef>

typedef _Float16 f16;
typedef _Float16 f16x8 __attribute__((ext_vector_type(8)));
typedef float    f32x4 __attribute__((ext_vector_type(4)));

// ---------------- problem constants ----------------
constexpr int NTOKC  = 197;
constexpr int TTOK   = 128 * 197;         // 25216
constexpr int EMB    = 384;
constexpr int HID    = 1536;

// ---------------- workspace layout (bytes) ----------------
constexpr size_t OFF_CONVW  = 0;                       // 384*768 f16
constexpr size_t OFF_KVW    = 589824;                  // 768*384 f16 (in_proj rows 384..1151)
constexpr size_t OFF_EW1T   = 1179648;                 // 4*1536*384 f16
constexpr size_t OFF_EW2T   = 5898240;                 // 4*384*1536 f16
constexpr size_t OFF_OCLS   = 10616832;                // 128*384 f32
constexpr size_t OFF_O2CLS  = 10813440;                // 128*384 f32
constexpr size_t OFF_HCLS16 = 11010048;                // 128*384 f16
constexpr size_t OFF_MASKW  = 11108352;                // 128*4 f32
constexpr size_t OFF_EH     = 11110400;                // 4*128*1536 f16
constexpr size_t OFF_EO     = 12683264;                // 4*128*384 f32
constexpr size_t OFF_H      = 13500416;                // TTOK*384 f32 (embed out)
constexpr size_t OFF_XH     = 52232192;                // TTOK*384 f16 (ln1 out)
constexpr size_t OFF_KV     = 71598080;                // TTOK*768 f32; earlier reused as im2col plane
constexpr size_t OFF_AIM    = OFF_KV;                  // 25088*768 f16 = 38,535,168 (< kv region)
constexpr size_t WS_NEEDED  = OFF_KV + (size_t)TTOK * 768 * 4;  // ~142 MB

// ---------------- global_load_lds helper ----------------
__device__ __forceinline__ void gload16(const void* g, void* l) {
  __builtin_amdgcn_global_load_lds(
      (__attribute__((address_space(1))) void*)(void*)g,
      (__attribute__((address_space(3))) void*)l, 16, 0, 0);
}

// ---------------- prep kernels ----------------
__global__ __launch_bounds__(256) void cast_f16_k(
    const float* __restrict__ in, f16* __restrict__ o, int n) {
  int i = blockIdx.x * 256 + threadIdx.x;
  if (i < n) o[i] = (f16)in[i];
}

// in f32 [R][C] -> out f16 [C][R] per expert slice
__global__ __launch_bounds__(256) void transpose_cast_k(
    const float* __restrict__ in, f16* __restrict__ outp, int R, int C) {
  __shared__ float tile[32][33];
  int e = blockIdx.z;
  const float* pin = in + (size_t)e * R * C;
  f16* pout = outp + (size_t)e * R * C;
  int c0 = blockIdx.x * 32, r0 = blockIdx.y * 32;
  int tx = threadIdx.x & 31, ty = threadIdx.x >> 5;
#pragma unroll
  for (int i = 0; i < 4; i++)
    tile[ty + 8 * i][tx] = pin[(size_t)(r0 + ty + 8 * i) * C + c0 + tx];
  __syncthreads();
#pragma unroll
  for (int i = 0; i < 4; i++)
    pout[(size_t)(c0 + ty + 8 * i) * R + r0 + tx] = (f16)tile[tx][ty + 8 * i];
}

__global__ void cls_init_k(const float* __restrict__ cls, const float* __restrict__ posw,
                           float* __restrict__ h0) {
  int b = blockIdx.x, c = threadIdx.x;  // block = 384 threads
  h0[(size_t)b * NTOKC * EMB + c] = cls[c] + posw[c];
}

// ---------------- im2col (f16, single plane) ----------------
// grid (14=py, 3=cch, 128=b). A[row=b*196+py*14+px][k=cch*256+ky*16+kx]
__global__ __launch_bounds__(256) void im2col_k(
    const float* __restrict__ img, f16* __restrict__ A) {
  __shared__ float tile[16 * 224];
  int py = blockIdx.x, cch = blockIdx.y, b = blockIdx.z;
  const float* src = img + ((size_t)(b * 3 + cch) * 224 + py * 16) * 224;
  for (int i = threadIdx.x; i < 16 * 224; i += 256) tile[i] = src[i];
  __syncthreads();
  if (threadIdx.x < 224) {
    int px = threadIdx.x >> 4, ky = threadIdx.x & 15;
    size_t outb = ((size_t)(b * 196 + py * 14 + px)) * 768 + cch * 256 + ky * 16;
    f16 hv[16] __attribute__((aligned(16)));
#pragma unroll
    for (int t = 0; t < 16; t++) hv[t] = (f16)tile[ky * 224 + px * 16 + t];
    ((uint4*)(A + outb))[0] = ((uint4*)hv)[0];
    ((uint4*)(A + outb))[1] = ((uint4*)hv)[1];
  }
}

// ---------------- plain f16 GEMM, global_load_lds staging: C = A*B^T ----------------
// EMBED=1: remap output rows (skip cls) and add pos_embed.
template <int EMBED>
__global__ __launch_bounds__(256) void gemm16_k(
    const f16* __restrict__ A, const f16* __restrict__ B,
    const float* __restrict__ bias, const float* __restrict__ posw,
    float* __restrict__ Cout, int K, int N) {
  __shared__ f16 As[128 * 32];
  __shared__ f16 Bs[128 * 32];
  const int tid = threadIdx.x;
  const int lane = tid & 63;
  const int wave = tid >> 6;
  const int m0 = (int)blockIdx.y * 128;
  const int n0 = (int)blockIdx.x * 128;
  const int wm = (wave >> 1) * 64;
  const int wn = (wave & 1) * 64;
  const int fr = lane & 15;
  const int fq = lane >> 4;

  f32x4 acc[4][4];
#pragma unroll
  for (int i = 0; i < 4; i++)
#pragma unroll
    for (int j = 0; j < 4; j++) acc[i][j] = f32x4{0.f, 0.f, 0.f, 0.f};

  const int srow = wave * 32 + (lane >> 2);
  const int scol = (lane & 3) * 8;
  const f16* ag = A + (size_t)(m0 + srow) * K + scol;
  const f16* bg = B + (size_t)(n0 + srow) * K + scol;
  const size_t rstep = (size_t)16 * K;
  f16* la = As + wave * 32 * 32;
  f16* lb = Bs + wave * 32 * 32;

  for (int k0 = 0; k0 < K; k0 += 32) {
    gload16(ag, la);          gload16(ag + rstep, la + 16 * 32);
    gload16(bg, lb);          gload16(bg + rstep, lb + 16 * 32);
    ag += 32; bg += 32;
    __syncthreads();
    f16x8 af[4], bf[4];
#pragma unroll
    for (int i = 0; i < 4; i++) {
      af[i] = *(const f16x8*)&As[(wm + i * 16 + fr) * 32 + fq * 8];
      bf[i] = *(const f16x8*)&Bs[(wn + i * 16 + fr) * 32 + fq * 8];
    }
#pragma unroll
    for (int i = 0; i < 4; i++)
#pragma unroll
      for (int j = 0; j < 4; j++)
        acc[i][j] = __builtin_amdgcn_mfma_f32_16x16x32_f16(af[i], bf[j], acc[i][j], 0, 0, 0);
    __syncthreads();
  }

#pragma unroll
  for (int i = 0; i < 4; i++)
#pragma unroll
    for (int j = 0; j < 4; j++)
#pragma unroll
      for (int rg = 0; rg < 4; rg++) {
        int gm = m0 + wm + i * 16 + fq * 4 + rg;
        int gn = n0 + wn + j * 16 + fr;
        float v = acc[i][j][rg] + bias[gn];
        if (EMBED) {
          int bb = gm / 196;
          int pp = gm - bb * 196;
          Cout[((size_t)bb * NTOKC + pp + 1) * EMB + gn] =
              v + posw[(size_t)(pp + 1) * EMB + gn];
        } else {
          Cout[(size_t)gm * N + gn] = v;
        }
      }
}

// ---------------- MoE fp16 GEMM over 128 cls tokens, all experts fused ----------------
template <int GELU>
__global__ __launch_bounds__(256) void moe_gemm_k(
    const f16* __restrict__ A, size_t aestride,
    const f16* __restrict__ Bm, size_t bestride,
    const float* __restrict__ bias, int biasstride,
    f16* __restrict__ outh, float* __restrict__ outf, size_t ostride,
    int K, int N) {
  __shared__ f16 As[128 * 32];
  __shared__ f16 Bs[128 * 32];
  const int tid = threadIdx.x;
  const int lane = tid & 63;
  const int wave = tid >> 6;
  const int e = (int)blockIdx.y;
  const int n0 = (int)blockIdx.x * 128;
  const int wm = (wave >> 1) * 64;
  const int wn = (wave & 1) * 64;
  const int fr = lane & 15;
  const int fq = lane >> 4;
  A += (size_t)e * aestride;
  Bm += (size_t)e * bestride;
  bias += (size_t)e * biasstride;

  f32x4 acc[4][4];
#pragma unroll
  for (int i = 0; i < 4; i++)
#pragma unroll
    for (int j = 0; j < 4; j++) acc[i][j] = f32x4{0.f, 0.f, 0.f, 0.f};

  const int srow = wave * 32 + (lane >> 2);
  const int scol = (lane & 3) * 8;
  const f16* ag = A + (size_t)srow * K + scol;
  const f16* bg = Bm + (size_t)(n0 + srow) * K + scol;
  const size_t rstep = (size_t)16 * K;
  f16* la = As + wave * 32 * 32;
  f16* lb = Bs + wave * 32 * 32;

  for (int k0 = 0; k0 < K; k0 += 32) {
    gload16(ag, la);          gload16(ag + rstep, la + 16 * 32);
    gload16(bg, lb);          gload16(bg + rstep, lb + 16 * 32);
    ag += 32; bg += 32;
    __syncthreads();
    f16x8 af[4], bf[4];
#pragma unroll
    for (int i = 0; i < 4; i++) {
      af[i] = *(const f16x8*)&As[(wm + i * 16 + fr) * 32 + fq * 8];
      bf[i] = *(const f16x8*)&Bs[(wn + i * 16 + fr) * 32 + fq * 8];
    }
#pragma unroll
    for (int i = 0; i < 4; i++)
#pragma unroll
      for (int j = 0; j < 4; j++)
        acc[i][j] = __builtin_amdgcn_mfma_f32_16x16x32_f16(af[i], bf[j], acc[i][j], 0, 0, 0);
    __syncthreads();
  }

#pragma unroll
  for (int i = 0; i < 4; i++)
#pragma unroll
    for (int j = 0; j < 4; j++)
#pragma unroll
      for (int rg = 0; rg < 4; rg++) {
        int gm = wm + i * 16 + fq * 4 + rg;
        int gn = n0 + wn + j * 16 + fr;
        float v = acc[i][j][rg] + bias[gn];
        if (GELU) {
          float g = 0.5f * v * (1.0f + erff(v * 0.70710678118654752f));  // exact GELU
          outh[(size_t)e * ostride + (size_t)gm * N + gn] = (f16)g;
        } else {
          outf[(size_t)e * ostride + (size_t)gm * N + gn] = v;
        }
      }
}

// ---------------- LayerNorm over all tokens -> f16 ----------------
__global__ __launch_bounds__(256) void ln_k(
    const float* __restrict__ in, const float* __restrict__ g, const float* __restrict__ bb,
    f16* __restrict__ oh) {
  int wave = threadIdx.x >> 6, lane = threadIdx.x & 63;
  size_t row = (size_t)blockIdx.x * 4 + wave;
  const float* xp = in + row * EMB;
  float v[6];
  float s = 0.f, sq = 0.f;
#pragma unroll
  for (int i = 0; i < 6; i++) {
    v[i] = xp[lane + 64 * i];
    s += v[i];
    sq += v[i] * v[i];
  }
#pragma unroll
  for (int off = 32; off; off >>= 1) {
    s += __shfl_xor(s, off);
    sq += __shfl_xor(sq, off);
  }
  float m = s * (1.f / 384.f);
  float var = sq * (1.f / 384.f) - m * m;
  float rs = rsqrtf(var + 1e-5f);
#pragma unroll
  for (int i = 0; i < 6; i++) {
    int c = lane + 64 * i;
    oh[row * EMB + c] = (f16)((v[i] - m) * rs * g[c] + bb[c]);
  }
}

// ---------------- fused cls-LN + Q-proj + attention (exact f32) ----------------
// grid (6 heads, 128 batch), block 64 (one wave).
__global__ __launch_bounds__(64) void attn_cls_k(
    const float* __restrict__ Hbuf, const float* __restrict__ g, const float* __restrict__ bb,
    const float* __restrict__ Wq, const float* __restrict__ bq,
    const float* __restrict__ kv, float* __restrict__ ocls) {
  __shared__ float xs[EMB];
  __shared__ float qs[64];
  __shared__ float red[64][65];
  const int h = blockIdx.x, b = blockIdx.y;
  const int lane = threadIdx.x;

  // LN of cls row (exact f32, recomputed per head — cheap)
  const float* xp = Hbuf + (size_t)b * NTOKC * EMB;
  float v[6];
  float s = 0.f, sq = 0.f;
#pragma unroll
  for (int i = 0; i < 6; i++) {
    v[i] = xp[lane + 64 * i];
    s += v[i];
    sq += v[i] * v[i];
  }
#pragma unroll
  for (int off = 32; off; off >>= 1) {
    s += __shfl_xor(s, off);
    sq += __shfl_xor(sq, off);
  }
  float m = s * (1.f / 384.f);
  float rs = rsqrtf(sq * (1.f / 384.f) - m * m + 1e-5f);
#pragma unroll
  for (int i = 0; i < 6; i++) {
    int c = lane + 64 * i;
    xs[c] = (v[i] - m) * rs * g[c] + bb[c];
  }
  __syncthreads();

  // q[lane] = bq + xs . Wq[h*64+lane]
  {
    const float4* w4 = (const float4*)(Wq + (size_t)(h * 64 + lane) * EMB);
    const float4* s4 = (const float4*)xs;
    float a = bq[h * 64 + lane];
#pragma unroll 8
    for (int i = 0; i < 96; i++) {
      float4 xx = s4[i], ww = w4[i];
      a += xx.x * ww.x + xx.y * ww.y + xx.z * ww.z + xx.w * ww.w;
    }
    qs[lane] = a;
  }
  __syncthreads();

  float accv[64];
#pragma unroll
  for (int d = 0; d < 64; d++) accv[d] = 0.f;
  float lsum = 0.f;

  for (int r = 0; r < 4; r++) {
    int row = lane + r * 64;
    if (row < NTOKC) {
      const float4* kp = (const float4*)(kv + ((size_t)b * NTOKC + row) * 768 + h * 64);
      float s0 = 0.f, s1 = 0.f, s2 = 0.f, s3 = 0.f;
#pragma unroll
      for (int i = 0; i < 16; i++) {
        float4 kk = kp[i];
        s0 += qs[i * 4 + 0] * kk.x;
        s1 += qs[i * 4 + 1] * kk.y;
        s2 += qs[i * 4 + 2] * kk.z;
        s3 += qs[i * 4 + 3] * kk.w;
      }
      float p = __expf((s0 + s1 + s2 + s3) * 0.125f);
      lsum += p;
      const float4* vp = (const float4*)(kv + ((size_t)b * NTOKC + row) * 768 + 384 + h * 64);
#pragma unroll
      for (int i = 0; i < 16; i++) {
        float4 vv = vp[i];
        accv[i * 4 + 0] += p * vv.x;
        accv[i * 4 + 1] += p * vv.y;
        accv[i * 4 + 2] += p * vv.z;
        accv[i * 4 + 3] += p * vv.w;
      }
    }
  }
#pragma unroll
  for (int d = 0; d < 64; d++) red[lane][d] = accv[d];
#pragma unroll
  for (int off = 32; off; off >>= 1) lsum += __shfl_xor(lsum, off);
  __syncthreads();
  float o = 0.f;
#pragma unroll
  for (int r = 0; r < 64; r++) o += red[r][lane];
  ocls[(size_t)b * EMB + h * 64 + lane] = o / lsum;
}

// ---------------- cls-row projection (exact f32, f32 input) ----------------
__global__ __launch_bounds__(384) void rowproj_k(
    const float* __restrict__ xf, const float* __restrict__ W,
    const float* __restrict__ bias, float* __restrict__ outp) {
  __shared__ float hx[EMB];
  int b = blockIdx.x, t = threadIdx.x;
  hx[t] = xf[(size_t)b * EMB + t];
  __syncthreads();
  const float4* w4 = (const float4*)(W + (size_t)t * EMB);
  const float4* s4 = (const float4*)hx;
  float a = bias[t];
#pragma unroll 8
  for (int i = 0; i < 96; i++) {
    float4 x = s4[i], w = w4[i];
    a += x.x * w.x + x.y * w.y + x.z * w.z + x.w * w.w;
  }
  outp[(size_t)b * EMB + t] = a;
}

// ---------------- fused LN (ln1 params again) + router top-2 ----------------
// grid 128, block 384 (6 waves).
__global__ __launch_bounds__(384) void ln_router_k(
    const float* __restrict__ o2cls, const float* __restrict__ g, const float* __restrict__ bb,
    const float* __restrict__ rw, const float* __restrict__ rb,
    f16* __restrict__ hcls16, float* __restrict__ maskw) {
  __shared__ float sh[EMB];
  __shared__ float red[16];
  __shared__ float part[6][4];
  __shared__ float logits[4];
  int b = blockIdx.x, t = threadIdx.x;
  int lane = t & 63, wave = t >> 6;
  float v = o2cls[(size_t)b * EMB + t];
  float s = v, sq = v * v;
#pragma unroll
  for (int off = 32; off; off >>= 1) {
    s += __shfl_xor(s, off);
    sq += __shfl_xor(sq, off);
  }
  if (lane == 0) { red[wave] = s; red[8 + wave] = sq; }
  __syncthreads();
  float S = 0.f, SQ = 0.f;
#pragma unroll
  for (int i = 0; i < 6; i++) { S += red[i]; SQ += red[8 + i]; }
  float m = S * (1.f / 384.f);
  float rs = rsqrtf(SQ * (1.f / 384.f) - m * m + 1e-5f);
  float y = (v - m) * rs * g[t] + bb[t];
  sh[t] = y;
  hcls16[(size_t)b * EMB + t] = (f16)y;
  // router partials
  float p0 = y * rw[t];
  float p1 = y * rw[EMB + t];
  float p2 = y * rw[2 * EMB + t];
  float p3 = y * rw[3 * EMB + t];
#pragma unroll
  for (int off = 32; off; off >>= 1) {
    p0 += __shfl_xor(p0, off);
    p1 += __shfl_xor(p1, off);
    p2 += __shfl_xor(p2, off);
    p3 += __shfl_xor(p3, off);
  }
  if (lane == 0) { part[wave][0] = p0; part[wave][1] = p1; part[wave][2] = p2; part[wave][3] = p3; }
  __syncthreads();
  if (t < 4) {
    float a = rb[t];
#pragma unroll
    for (int i = 0; i < 6; i++) a += part[i][t];
    logits[t] = a;
  }
  __syncthreads();
  if (t == 0) {
    float l0 = logits[0], l1 = logits[1], l2 = logits[2], l3 = logits[3];
    int i1 = 0; float b1 = l0;
    if (l1 > b1) { b1 = l1; i1 = 1; }
    if (l2 > b1) { b1 = l2; i1 = 2; }
    if (l3 > b1) { b1 = l3; i1 = 3; }
    int i2 = -1; float b2 = 0.f;
    float lv[4] = {l0, l1, l2, l3};
#pragma unroll
    for (int i = 0; i < 4; i++) {
      if (i == i1) continue;
      if (i2 < 0 || lv[i] > b2) { i2 = i; b2 = lv[i]; }
    }
#pragma unroll
    for (int e = 0; e < 4; e++)
      maskw[(size_t)b * 4 + e] = (e == i1 || e == i2) ? 0.5f : 0.f;
  }
}

// ---------------- expert combine + LN2 + classification head ----------------
__global__ __launch_bounds__(256) void head_k(
    const float* __restrict__ eo, const float* __restrict__ maskw,
    const float* __restrict__ g, const float* __restrict__ bb,
    const float* __restrict__ hw, const float* __restrict__ hb, float* __restrict__ outp) {
  __shared__ float sh[EMB];
  __shared__ float red[8];
  int b = blockIdx.x, tid = threadIdx.x;
  float mw0 = maskw[b * 4 + 0], mw1 = maskw[b * 4 + 1];
  float mw2 = maskw[b * 4 + 2], mw3 = maskw[b * 4 + 3];
  const size_t eb = (size_t)b * EMB;
  const size_t es = (size_t)128 * EMB;
  float v0 = mw0 * eo[eb + tid] + mw1 * eo[es + eb + tid] +
             mw2 * eo[2 * es + eb + tid] + mw3 * eo[3 * es + eb + tid];
  float v1 = 0.f;
  if (tid < 128) {
    int c = 256 + tid;
    v1 = mw0 * eo[eb + c] + mw1 * eo[es + eb + c] +
         mw2 * eo[2 * es + eb + c] + mw3 * eo[3 * es + eb + c];
  }
  float s = v0 + v1, sq = v0 * v0 + v1 * v1;
  int lane = tid & 63, wave = tid >> 6;
#pragma unroll
  for (int off = 32; off; off >>= 1) {
    s += __shfl_xor(s, off);
    sq += __shfl_xor(sq, off);
  }
  if (lane == 0) { red[wave] = s; red[4 + wave] = sq; }
  __syncthreads();
  float S = red[0] + red[1] + red[2] + red[3];
  float SQ = red[4] + red[5] + red[6] + red[7];
  float m = S * (1.f / 384.f);
  float var = SQ * (1.f / 384.f) - m * m;
  float rs = rsqrtf(var + 1e-5f);
  sh[tid] = (v0 - m) * rs * g[tid] + bb[tid];
  if (tid < 128) sh[256 + tid] = (v1 - m) * rs * g[256 + tid] + bb[256 + tid];
  __syncthreads();
  for (int n = tid; n < 1000; n += 256) {
    const float4* w4 = (const float4*)(hw + (size_t)n * EMB);
    const float4* s4 = (const float4*)sh;
    float a = hb[n];
#pragma unroll 8
    for (int i = 0; i < 96; i++) {
      float4 x = s4[i], w = w4[i];
      a += x.x * w.x + x.y * w.y + x.z * w.z + x.w * w.w;
    }
    outp[(size_t)b * 1000 + n] = a;
  }
}

// ---------------- host ----------------
extern "C" void kernel_launch(void* const* d_in, const int* in_sizes, int n_in,
                              void* d_out, int out_size, void* d_ws, size_t ws_size,
                              hipStream_t stream) {
  const float* x      = (const float*)d_in[0];
  const float* conv_w = (const float*)d_in[1];
  const float* conv_b = (const float*)d_in[2];
  const float* cls_t  = (const float*)d_in[3];
  const float* pos    = (const float*)d_in[4];
  const float* ln1_g  = (const float*)d_in[5];
  const float* ln1_b  = (const float*)d_in[6];
  const float* inp_w  = (const float*)d_in[7];
  const float* inp_b  = (const float*)d_in[8];
  const float* outp_w = (const float*)d_in[9];
  const float* outp_b = (const float*)d_in[10];
  const float* rt_w   = (const float*)d_in[11];
  const float* rt_b   = (const float*)d_in[12];
  const float* ew1    = (const float*)d_in[13];
  const float* eb1    = (const float*)d_in[14];
  const float* ew2    = (const float*)d_in[15];
  const float* eb2    = (const float*)d_in[16];
  const float* ln2_g  = (const float*)d_in[17];
  const float* ln2_b  = (const float*)d_in[18];
  const float* head_w = (const float*)d_in[19];
  const float* head_b = (const float*)d_in[20];
  float* out = (float*)d_out;
  char* w = (char*)d_ws;
  if (ws_size < WS_NEEDED) return;

  f16* convw    = (f16*)(w + OFF_CONVW);
  f16* kvw      = (f16*)(w + OFF_KVW);
  f16* ew1t     = (f16*)(w + OFF_EW1T);
  f16* ew2t     = (f16*)(w + OFF_EW2T);
  float* ocls   = (float*)(w + OFF_OCLS);
  float* o2cls  = (float*)(w + OFF_O2CLS);
  f16* hcls16   = (f16*)(w + OFF_HCLS16);
  float* maskw  = (float*)(w + OFF_MASKW);
  f16* ehbuf    = (f16*)(w + OFF_EH);
  float* eobuf  = (float*)(w + OFF_EO);
  float* Hbuf   = (float*)(w + OFF_H);
  f16* xh       = (f16*)(w + OFF_XH);
  float* kvbuf  = (float*)(w + OFF_KV);
  f16* aim      = (f16*)(w + OFF_AIM);   // overlaps kvbuf; dead before kv gemm writes

  // ---- weight prep ----
  cast_f16_k<<<dim3((294912 + 255) / 256), 256, 0, stream>>>(conv_w, convw, 294912);
  cast_f16_k<<<dim3((294912 + 255) / 256), 256, 0, stream>>>(inp_w + 384 * 384, kvw, 294912);
  transpose_cast_k<<<dim3(48, 12, 4), 256, 0, stream>>>(ew1, ew1t, 384, 1536);
  transpose_cast_k<<<dim3(12, 48, 4), 256, 0, stream>>>(ew2, ew2t, 1536, 384);

  // ---- im2col + patch-embed GEMM -> Hbuf ----
  im2col_k<<<dim3(14, 3, 128), 256, 0, stream>>>(x, aim);
  gemm16_k<1><<<dim3(3, 196), 256, 0, stream>>>(aim, convw, conv_b, pos, Hbuf, 768, EMB);
  cls_init_k<<<dim3(128), dim3(384), 0, stream>>>(cls_t, pos, Hbuf);

  // ---- LN1 -> f16 (all tokens) ----
  ln_k<<<dim3(TTOK / 4), 256, 0, stream>>>(Hbuf, ln1_g, ln1_b, xh);

  // ---- K,V projection for all tokens (plain f16 MFMA) ----
  gemm16_k<0><<<dim3(6, 197), 256, 0, stream>>>(xh, kvw, inp_b + 384, nullptr, kvbuf, EMB, 768);

  // ---- fused cls-LN + Q-proj + attention (exact f32) ----
  attn_cls_k<<<dim3(6, 128), 64, 0, stream>>>(
      Hbuf, ln1_g, ln1_b, inp_w, inp_b, kvbuf, ocls);

  // ---- out-proj on cls rows (exact f32) ----
  rowproj_k<<<dim3(128), 384, 0, stream>>>(ocls, outp_w, outp_b, o2cls);

  // ---- fused LN (ln1 params) + router top-2 ----
  ln_router_k<<<dim3(128), 384, 0, stream>>>(
      o2cls, ln1_g, ln1_b, rt_w, rt_b, hcls16, maskw);

  // ---- MoE on 128 cls tokens, all 4 experts fused per launch ----
  moe_gemm_k<1><<<dim3(12, 4), 256, 0, stream>>>(
      hcls16, 0, ew1t, (size_t)HID * EMB, eb1, HID,
      ehbuf, nullptr, (size_t)128 * HID, EMB, HID);
  moe_gemm_k<0><<<dim3(3, 4), 256, 0, stream>>>(
      ehbuf, (size_t)128 * HID, ew2t, (size_t)EMB * HID, eb2, EMB,
      nullptr, eobuf, (size_t)128 * EMB, HID, EMB);

  // ---- combine + LN2 + head ----
  head_k<<<dim3(128), 256, 0, stream>>>(eobuf, maskw, ln2_g, ln2_b, head_w, head_b, out);
  (void)in_sizes; (void)n_in; (void)out_size;
}

// Round 6
// 394.492 us; speedup vs baseline: 3.6305x; 1.0865x over previous
//
#include <hip/hip_runtime.h>
#include <cstdint>
#include <cstddef>

typedef _Float16 f16;
typedef _Float16 f16x8 __attribute__((ext_vector_type(8)));
typedef float    f32x4 __attribute__((ext_vector_type(4)));

// ---------------- problem constants ----------------
constexpr int NTOKC  = 197;
constexpr int TTOK   = 128 * 197;         // 25216
constexpr int EMB    = 384;
constexpr int HID    = 1536;

// ---------------- workspace layout (bytes) ----------------
constexpr size_t OFF_CONVW  = 0;                       // 384*768 f16
constexpr size_t OFF_KVW    = 589824;                  // 768*384 f16 (in_proj rows 384..1151)
constexpr size_t OFF_EW1T   = 1179648;                 // 4*1536*384 f16
constexpr size_t OFF_EW2T   = 5898240;                 // 4*384*1536 f16
constexpr size_t OFF_OCLS   = 10616832;                // 128*384 f32
constexpr size_t OFF_O2CLS  = 10813440;                // 128*384 f32
constexpr size_t OFF_HCLS16 = 11010048;                // 128*384 f16
constexpr size_t OFF_MASKW  = 11108352;                // 128*4 f32
constexpr size_t OFF_EH     = 11110400;                // 4*128*1536 f16
constexpr size_t OFF_EO     = 12683264;                // 4*128*384 f32
constexpr size_t OFF_H      = 13500416;                // TTOK*384 f32 (embed out)
constexpr size_t OFF_XH     = 52232192;                // TTOK*384 f16 (ln1 out)
constexpr size_t OFF_KV     = 71598080;                // TTOK*768 f32; earlier reused as im2col plane
constexpr size_t OFF_AIM    = OFF_KV;                  // 25088*768 f16 (< kv region, dead before kv write)
constexpr size_t OFF_HEADW16 = OFF_KV + (size_t)TTOK * 768 * 4;  // 1024*384 f16 (row-padded)
constexpr size_t OFF_HFIN   = OFF_HEADW16 + 786432;    // 128*384 f16
constexpr size_t WS_NEEDED  = OFF_HFIN + 98304;        // ~150 MB

// ---------------- global_load_lds helper ----------------
__device__ __forceinline__ void gload16(const void* g, void* l) {
  __builtin_amdgcn_global_load_lds(
      (__attribute__((address_space(1))) void*)(void*)g,
      (__attribute__((address_space(3))) void*)l, 16, 0, 0);
}

// ---------------- prep kernels ----------------
__global__ __launch_bounds__(256) void cast_f16_k(
    const float* __restrict__ in, f16* __restrict__ o, int n) {
  int i = blockIdx.x * 256 + threadIdx.x;
  if (i < n) o[i] = (f16)in[i];
}

// head_w [1000][384] f32 -> [1024][384] f16, rows >=1000 zero
__global__ __launch_bounds__(256) void cast_pad_k(
    const float* __restrict__ in, f16* __restrict__ o) {
  int i = blockIdx.x * 256 + threadIdx.x;
  if (i < 1024 * 384) {
    int row = i / 384;
    o[i] = (row < 1000) ? (f16)in[i] : (f16)0.f;
  }
}

// in f32 [R][C] -> out f16 [C][R] per expert slice
__global__ __launch_bounds__(256) void transpose_cast_k(
    const float* __restrict__ in, f16* __restrict__ outp, int R, int C) {
  __shared__ float tile[32][33];
  int e = blockIdx.z;
  const float* pin = in + (size_t)e * R * C;
  f16* pout = outp + (size_t)e * R * C;
  int c0 = blockIdx.x * 32, r0 = blockIdx.y * 32;
  int tx = threadIdx.x & 31, ty = threadIdx.x >> 5;
#pragma unroll
  for (int i = 0; i < 4; i++)
    tile[ty + 8 * i][tx] = pin[(size_t)(r0 + ty + 8 * i) * C + c0 + tx];
  __syncthreads();
#pragma unroll
  for (int i = 0; i < 4; i++)
    pout[(size_t)(c0 + ty + 8 * i) * R + r0 + tx] = (f16)tile[tx][ty + 8 * i];
}

__global__ void cls_init_k(const float* __restrict__ cls, const float* __restrict__ posw,
                           float* __restrict__ h0) {
  int b = blockIdx.x, c = threadIdx.x;  // block = 384 threads
  h0[(size_t)b * NTOKC * EMB + c] = cls[c] + posw[c];
}

// ---------------- im2col (f16, single plane) ----------------
__global__ __launch_bounds__(256) void im2col_k(
    const float* __restrict__ img, f16* __restrict__ A) {
  __shared__ float tile[16 * 224];
  int py = blockIdx.x, cch = blockIdx.y, b = blockIdx.z;
  const float* src = img + ((size_t)(b * 3 + cch) * 224 + py * 16) * 224;
  for (int i = threadIdx.x; i < 16 * 224; i += 256) tile[i] = src[i];
  __syncthreads();
  if (threadIdx.x < 224) {
    int px = threadIdx.x >> 4, ky = threadIdx.x & 15;
    size_t outb = ((size_t)(b * 196 + py * 14 + px)) * 768 + cch * 256 + ky * 16;
    f16 hv[16] __attribute__((aligned(16)));
#pragma unroll
    for (int t = 0; t < 16; t++) hv[t] = (f16)tile[ky * 224 + px * 16 + t];
    ((uint4*)(A + outb))[0] = ((uint4*)hv)[0];
    ((uint4*)(A + outb))[1] = ((uint4*)hv)[1];
  }
}

// ---------------- plain f16 GEMM, global_load_lds staging: C = A*B^T ----------------
// EMBED=1: remap output rows (skip cls) and add pos_embed.
template <int EMBED>
__global__ __launch_bounds__(256) void gemm16_k(
    const f16* __restrict__ A, const f16* __restrict__ B,
    const float* __restrict__ bias, const float* __restrict__ posw,
    float* __restrict__ Cout, int K, int N) {
  __shared__ f16 As[128 * 32];
  __shared__ f16 Bs[128 * 32];
  const int tid = threadIdx.x;
  const int lane = tid & 63;
  const int wave = tid >> 6;
  const int m0 = (int)blockIdx.y * 128;
  const int n0 = (int)blockIdx.x * 128;
  const int wm = (wave >> 1) * 64;
  const int wn = (wave & 1) * 64;
  const int fr = lane & 15;
  const int fq = lane >> 4;

  f32x4 acc[4][4];
#pragma unroll
  for (int i = 0; i < 4; i++)
#pragma unroll
    for (int j = 0; j < 4; j++) acc[i][j] = f32x4{0.f, 0.f, 0.f, 0.f};

  const int srow = wave * 32 + (lane >> 2);
  const int scol = (lane & 3) * 8;
  const f16* ag = A + (size_t)(m0 + srow) * K + scol;
  const f16* bg = B + (size_t)(n0 + srow) * K + scol;
  const size_t rstep = (size_t)16 * K;
  f16* la = As + wave * 32 * 32;
  f16* lb = Bs + wave * 32 * 32;

  for (int k0 = 0; k0 < K; k0 += 32) {
    gload16(ag, la);          gload16(ag + rstep, la + 16 * 32);
    gload16(bg, lb);          gload16(bg + rstep, lb + 16 * 32);
    ag += 32; bg += 32;
    __syncthreads();
    f16x8 af[4], bf[4];
#pragma unroll
    for (int i = 0; i < 4; i++) {
      af[i] = *(const f16x8*)&As[(wm + i * 16 + fr) * 32 + fq * 8];
      bf[i] = *(const f16x8*)&Bs[(wn + i * 16 + fr) * 32 + fq * 8];
    }
#pragma unroll
    for (int i = 0; i < 4; i++)
#pragma unroll
      for (int j = 0; j < 4; j++)
        acc[i][j] = __builtin_amdgcn_mfma_f32_16x16x32_f16(af[i], bf[j], acc[i][j], 0, 0, 0);
    __syncthreads();
  }

#pragma unroll
  for (int i = 0; i < 4; i++)
#pragma unroll
    for (int j = 0; j < 4; j++)
#pragma unroll
      for (int rg = 0; rg < 4; rg++) {
        int gm = m0 + wm + i * 16 + fq * 4 + rg;
        int gn = n0 + wn + j * 16 + fr;
        float v = acc[i][j][rg] + bias[gn];
        if (EMBED) {
          int bb = gm / 196;
          int pp = gm - bb * 196;
          Cout[((size_t)bb * NTOKC + pp + 1) * EMB + gn] =
              v + posw[(size_t)(pp + 1) * EMB + gn];
        } else {
          Cout[(size_t)gm * N + gn] = v;
        }
      }
}

// ---------------- MoE fp16 GEMM over 128 cls tokens, all experts fused ----------------
template <int GELU>
__global__ __launch_bounds__(256) void moe_gemm_k(
    const f16* __restrict__ A, size_t aestride,
    const f16* __restrict__ Bm, size_t bestride,
    const float* __restrict__ bias, int biasstride,
    f16* __restrict__ outh, float* __restrict__ outf, size_t ostride,
    int K, int N) {
  __shared__ f16 As[128 * 32];
  __shared__ f16 Bs[128 * 32];
  const int tid = threadIdx.x;
  const int lane = tid & 63;
  const int wave = tid >> 6;
  const int e = (int)blockIdx.y;
  const int n0 = (int)blockIdx.x * 128;
  const int wm = (wave >> 1) * 64;
  const int wn = (wave & 1) * 64;
  const int fr = lane & 15;
  const int fq = lane >> 4;
  A += (size_t)e * aestride;
  Bm += (size_t)e * bestride;
  bias += (size_t)e * biasstride;

  f32x4 acc[4][4];
#pragma unroll
  for (int i = 0; i < 4; i++)
#pragma unroll
    for (int j = 0; j < 4; j++) acc[i][j] = f32x4{0.f, 0.f, 0.f, 0.f};

  const int srow = wave * 32 + (lane >> 2);
  const int scol = (lane & 3) * 8;
  const f16* ag = A + (size_t)srow * K + scol;
  const f16* bg = Bm + (size_t)(n0 + srow) * K + scol;
  const size_t rstep = (size_t)16 * K;
  f16* la = As + wave * 32 * 32;
  f16* lb = Bs + wave * 32 * 32;

  for (int k0 = 0; k0 < K; k0 += 32) {
    gload16(ag, la);          gload16(ag + rstep, la + 16 * 32);
    gload16(bg, lb);          gload16(bg + rstep, lb + 16 * 32);
    ag += 32; bg += 32;
    __syncthreads();
    f16x8 af[4], bf[4];
#pragma unroll
    for (int i = 0; i < 4; i++) {
      af[i] = *(const f16x8*)&As[(wm + i * 16 + fr) * 32 + fq * 8];
      bf[i] = *(const f16x8*)&Bs[(wn + i * 16 + fr) * 32 + fq * 8];
    }
#pragma unroll
    for (int i = 0; i < 4; i++)
#pragma unroll
      for (int j = 0; j < 4; j++)
        acc[i][j] = __builtin_amdgcn_mfma_f32_16x16x32_f16(af[i], bf[j], acc[i][j], 0, 0, 0);
    __syncthreads();
  }

#pragma unroll
  for (int i = 0; i < 4; i++)
#pragma unroll
    for (int j = 0; j < 4; j++)
#pragma unroll
      for (int rg = 0; rg < 4; rg++) {
        int gm = wm + i * 16 + fq * 4 + rg;
        int gn = n0 + wn + j * 16 + fr;
        float v = acc[i][j][rg] + bias[gn];
        if (GELU) {
          float g = 0.5f * v * (1.0f + erff(v * 0.70710678118654752f));  // exact GELU
          outh[(size_t)e * ostride + (size_t)gm * N + gn] = (f16)g;
        } else {
          outf[(size_t)e * ostride + (size_t)gm * N + gn] = v;
        }
      }
}

// ---------------- head GEMM: [128 x 384] @ headw16^T [1024 x 384] -> out f32 ---------
__global__ __launch_bounds__(256) void head_gemm_k(
    const f16* __restrict__ A, const f16* __restrict__ B,
    const float* __restrict__ hb, float* __restrict__ outp) {
  __shared__ f16 As[128 * 32];
  __shared__ f16 Bs[128 * 32];
  const int K = 384;
  const int tid = threadIdx.x;
  const int lane = tid & 63;
  const int wave = tid >> 6;
  const int n0 = (int)blockIdx.x * 128;
  const int wm = (wave >> 1) * 64;
  const int wn = (wave & 1) * 64;
  const int fr = lane & 15;
  const int fq = lane >> 4;

  f32x4 acc[4][4];
#pragma unroll
  for (int i = 0; i < 4; i++)
#pragma unroll
    for (int j = 0; j < 4; j++) acc[i][j] = f32x4{0.f, 0.f, 0.f, 0.f};

  const int srow = wave * 32 + (lane >> 2);
  const int scol = (lane & 3) * 8;
  const f16* ag = A + (size_t)srow * K + scol;
  const f16* bg = B + (size_t)(n0 + srow) * K + scol;
  const size_t rstep = (size_t)16 * K;
  f16* la = As + wave * 32 * 32;
  f16* lb = Bs + wave * 32 * 32;

  for (int k0 = 0; k0 < K; k0 += 32) {
    gload16(ag, la);          gload16(ag + rstep, la + 16 * 32);
    gload16(bg, lb);          gload16(bg + rstep, lb + 16 * 32);
    ag += 32; bg += 32;
    __syncthreads();
    f16x8 af[4], bf[4];
#pragma unroll
    for (int i = 0; i < 4; i++) {
      af[i] = *(const f16x8*)&As[(wm + i * 16 + fr) * 32 + fq * 8];
      bf[i] = *(const f16x8*)&Bs[(wn + i * 16 + fr) * 32 + fq * 8];
    }
#pragma unroll
    for (int i = 0; i < 4; i++)
#pragma unroll
      for (int j = 0; j < 4; j++)
        acc[i][j] = __builtin_amdgcn_mfma_f32_16x16x32_f16(af[i], bf[j], acc[i][j], 0, 0, 0);
    __syncthreads();
  }

#pragma unroll
  for (int i = 0; i < 4; i++)
#pragma unroll
    for (int j = 0; j < 4; j++)
#pragma unroll
      for (int rg = 0; rg < 4; rg++) {
        int gm = wm + i * 16 + fq * 4 + rg;
        int gn = n0 + wn + j * 16 + fr;
        if (gn < 1000)
          outp[(size_t)gm * 1000 + gn] = acc[i][j][rg] + hb[gn];
      }
}

// ---------------- LayerNorm over all tokens -> f16 ----------------
__global__ __launch_bounds__(256) void ln_k(
    const float* __restrict__ in, const float* __restrict__ g, const float* __restrict__ bb,
    f16* __restrict__ oh) {
  int wave = threadIdx.x >> 6, lane = threadIdx.x & 63;
  size_t row = (size_t)blockIdx.x * 4 + wave;
  const float* xp = in + row * EMB;
  float v[6];
  float s = 0.f, sq = 0.f;
#pragma unroll
  for (int i = 0; i < 6; i++) {
    v[i] = xp[lane + 64 * i];
    s += v[i];
    sq += v[i] * v[i];
  }
#pragma unroll
  for (int off = 32; off; off >>= 1) {
    s += __shfl_xor(s, off);
    sq += __shfl_xor(sq, off);
  }
  float m = s * (1.f / 384.f);
  float var = sq * (1.f / 384.f) - m * m;
  float rs = rsqrtf(var + 1e-5f);
#pragma unroll
  for (int i = 0; i < 6; i++) {
    int c = lane + 64 * i;
    oh[row * EMB + c] = (f16)((v[i] - m) * rs * g[c] + bb[c]);
  }
}

// ---------------- fused cls-LN + Q-proj + attention (exact f32), 4 waves -----------
// grid (6 heads, 128 batch), block 256.
// lane = r4*4 + c: quad (r4) owns a K-row slot; c owns V-dims [c*16, c*16+16).
// row = wave*16 + r4 + 64*i  (i<4) covers 0..255 -> guard <197.
__global__ __launch_bounds__(256) void attn_cls_k(
    const float* __restrict__ Hbuf, const float* __restrict__ g, const float* __restrict__ bb,
    const float* __restrict__ Wq, const float* __restrict__ bq,
    const float* __restrict__ kv, float* __restrict__ ocls) {
  __shared__ float xs[EMB];
  __shared__ float qs[64];
  __shared__ float red[8];
  __shared__ float qpart[4][64];
  __shared__ float racc[64 * 64];   // [rowslot][dim] 16 KB
  __shared__ float rsum[64];
  const int h = blockIdx.x, b = blockIdx.y;
  const int tid = threadIdx.x;
  const int wave = tid >> 6, lane = tid & 63;

  // ---- LN of cls row (256 threads over 384 elems) ----
  const float* xp = Hbuf + (size_t)b * NTOKC * EMB;
  float v0 = xp[tid];
  float v1 = (tid < 128) ? xp[256 + tid] : 0.f;
  float s = v0 + v1, sq = v0 * v0 + v1 * v1;
#pragma unroll
  for (int off = 32; off; off >>= 1) {
    s += __shfl_xor(s, off);
    sq += __shfl_xor(sq, off);
  }
  if (lane == 0) { red[wave] = s; red[4 + wave] = sq; }
  __syncthreads();
  float S = red[0] + red[1] + red[2] + red[3];
  float SQ = red[4] + red[5] + red[6] + red[7];
  float m = S * (1.f / 384.f);
  float rs = rsqrtf(SQ * (1.f / 384.f) - m * m + 1e-5f);
  xs[tid] = (v0 - m) * rs * g[tid] + bb[tid];
  if (tid < 128) xs[256 + tid] = (v1 - m) * rs * g[256 + tid] + bb[256 + tid];
  __syncthreads();

  // ---- Q-proj: q[d] = bq + xs . Wq[h*64+d], 4-way k-split ----
  {
    int d = tid & 63, part = tid >> 6;
    const float4* w4 = (const float4*)(Wq + (size_t)(h * 64 + d) * EMB + part * 96);
    const float4* s4 = (const float4*)(xs + part * 96);
    float a = 0.f;
#pragma unroll
    for (int i = 0; i < 24; i++) {
      float4 xx = s4[i], ww = w4[i];
      a += xx.x * ww.x + xx.y * ww.y + xx.z * ww.z + xx.w * ww.w;
    }
    qpart[part][d] = a;
  }
  __syncthreads();
  if (tid < 64)
    qs[tid] = bq[h * 64 + tid] + qpart[0][tid] + qpart[1][tid] + qpart[2][tid] + qpart[3][tid];
  __syncthreads();

  // ---- attention over K-rows ----
  const int r4 = lane >> 2, c = lane & 3;
  const int rowslot = wave * 16 + r4;       // 0..63
  float qv[16];
#pragma unroll
  for (int j = 0; j < 16; j++) qv[j] = qs[c * 16 + j];
  float acc[16];
#pragma unroll
  for (int j = 0; j < 16; j++) acc[j] = 0.f;
  float lsum = 0.f;

#pragma unroll
  for (int i = 0; i < 4; i++) {
    int row = rowslot + 64 * i;
    if (row < NTOKC) {
      const float4* kp = (const float4*)(kv + ((size_t)b * NTOKC + row) * 768 + h * 64 + c * 16);
      float4 k0 = kp[0], k1 = kp[1], k2 = kp[2], k3 = kp[3];
      float sc = qv[0] * k0.x + qv[1] * k0.y + qv[2] * k0.z + qv[3] * k0.w +
                 qv[4] * k1.x + qv[5] * k1.y + qv[6] * k1.z + qv[7] * k1.w +
                 qv[8] * k2.x + qv[9] * k2.y + qv[10] * k2.z + qv[11] * k2.w +
                 qv[12] * k3.x + qv[13] * k3.y + qv[14] * k3.z + qv[15] * k3.w;
      sc += __shfl_xor(sc, 1);
      sc += __shfl_xor(sc, 2);
      float p = __expf(sc * 0.125f);
      lsum += p;
      const float4* vp = (const float4*)(kv + ((size_t)b * NTOKC + row) * 768 + 384 + h * 64 + c * 16);
      float4 w0 = vp[0], w1 = vp[1], w2 = vp[2], w3 = vp[3];
      acc[0] += p * w0.x;  acc[1] += p * w0.y;  acc[2] += p * w0.z;  acc[3] += p * w0.w;
      acc[4] += p * w1.x;  acc[5] += p * w1.y;  acc[6] += p * w1.z;  acc[7] += p * w1.w;
      acc[8] += p * w2.x;  acc[9] += p * w2.y;  acc[10] += p * w2.z; acc[11] += p * w2.w;
      acc[12] += p * w3.x; acc[13] += p * w3.y; acc[14] += p * w3.z; acc[15] += p * w3.w;
    }
  }
#pragma unroll
  for (int j = 0; j < 16; j++) racc[rowslot * 64 + c * 16 + j] = acc[j];
  if (c == 0) rsum[rowslot] = lsum;
  __syncthreads();

  if (tid < 64) {
    float o = 0.f, ls = 0.f;
#pragma unroll 8
    for (int r = 0; r < 64; r++) {
      o += racc[r * 64 + tid];
      ls += rsum[r];
    }
    ocls[(size_t)b * EMB + h * 64 + tid] = o / ls;
  }
}

// ---------------- cls-row projection (exact f32, f32 input) ----------------
__global__ __launch_bounds__(384) void rowproj_k(
    const float* __restrict__ xf, const float* __restrict__ W,
    const float* __restrict__ bias, float* __restrict__ outp) {
  __shared__ float hx[EMB];
  int b = blockIdx.x, t = threadIdx.x;
  hx[t] = xf[(size_t)b * EMB + t];
  __syncthreads();
  const float4* w4 = (const float4*)(W + (size_t)t * EMB);
  const float4* s4 = (const float4*)hx;
  float a = bias[t];
#pragma unroll 8
  for (int i = 0; i < 96; i++) {
    float4 x = s4[i], w = w4[i];
    a += x.x * w.x + x.y * w.y + x.z * w.z + x.w * w.w;
  }
  outp[(size_t)b * EMB + t] = a;
}

// ---------------- fused LN (ln1 params again) + router top-2 ----------------
__global__ __launch_bounds__(384) void ln_router_k(
    const float* __restrict__ o2cls, const float* __restrict__ g, const float* __restrict__ bb,
    const float* __restrict__ rw, const float* __restrict__ rb,
    f16* __restrict__ hcls16, float* __restrict__ maskw) {
  __shared__ float red[16];
  __shared__ float part[6][4];
  __shared__ float logits[4];
  int b = blockIdx.x, t = threadIdx.x;
  int lane = t & 63, wave = t >> 6;
  float v = o2cls[(size_t)b * EMB + t];
  float s = v, sq = v * v;
#pragma unroll
  for (int off = 32; off; off >>= 1) {
    s += __shfl_xor(s, off);
    sq += __shfl_xor(sq, off);
  }
  if (lane == 0) { red[wave] = s; red[8 + wave] = sq; }
  __syncthreads();
  float S = 0.f, SQ = 0.f;
#pragma unroll
  for (int i = 0; i < 6; i++) { S += red[i]; SQ += red[8 + i]; }
  float m = S * (1.f / 384.f);
  float rs = rsqrtf(SQ * (1.f / 384.f) - m * m + 1e-5f);
  float y = (v - m) * rs * g[t] + bb[t];
  hcls16[(size_t)b * EMB + t] = (f16)y;
  float p0 = y * rw[t];
  float p1 = y * rw[EMB + t];
  float p2 = y * rw[2 * EMB + t];
  float p3 = y * rw[3 * EMB + t];
#pragma unroll
  for (int off = 32; off; off >>= 1) {
    p0 += __shfl_xor(p0, off);
    p1 += __shfl_xor(p1, off);
    p2 += __shfl_xor(p2, off);
    p3 += __shfl_xor(p3, off);
  }
  if (lane == 0) { part[wave][0] = p0; part[wave][1] = p1; part[wave][2] = p2; part[wave][3] = p3; }
  __syncthreads();
  if (t < 4) {
    float a = rb[t];
#pragma unroll
    for (int i = 0; i < 6; i++) a += part[i][t];
    logits[t] = a;
  }
  __syncthreads();
  if (t == 0) {
    float l0 = logits[0], l1 = logits[1], l2 = logits[2], l3 = logits[3];
    int i1 = 0; float b1 = l0;
    if (l1 > b1) { b1 = l1; i1 = 1; }
    if (l2 > b1) { b1 = l2; i1 = 2; }
    if (l3 > b1) { b1 = l3; i1 = 3; }
    int i2 = -1; float b2 = 0.f;
    float lv[4] = {l0, l1, l2, l3};
#pragma unroll
    for (int i = 0; i < 4; i++) {
      if (i == i1) continue;
      if (i2 < 0 || lv[i] > b2) { i2 = i; b2 = lv[i]; }
    }
#pragma unroll
    for (int e = 0; e < 4; e++)
      maskw[(size_t)b * 4 + e] = (e == i1 || e == i2) ? 0.5f : 0.f;
  }
}

// ---------------- expert combine + LN2 -> f16 ----------------
__global__ __launch_bounds__(384) void combine_ln2_k(
    const float* __restrict__ eo, const float* __restrict__ maskw,
    const float* __restrict__ g, const float* __restrict__ bb,
    f16* __restrict__ hfin) {
  __shared__ float red[16];
  int b = blockIdx.x, t = threadIdx.x;
  int lane = t & 63, wave = t >> 6;
  float mw0 = maskw[b * 4 + 0], mw1 = maskw[b * 4 + 1];
  float mw2 = maskw[b * 4 + 2], mw3 = maskw[b * 4 + 3];
  const size_t eb = (size_t)b * EMB;
  const size_t es = (size_t)128 * EMB;
  float v = mw0 * eo[eb + t] + mw1 * eo[es + eb + t] +
            mw2 * eo[2 * es + eb + t] + mw3 * eo[3 * es + eb + t];
  float s = v, sq = v * v;
#pragma unroll
  for (int off = 32; off; off >>= 1) {
    s += __shfl_xor(s, off);
    sq += __shfl_xor(sq, off);
  }
  if (lane == 0) { red[wave] = s; red[8 + wave] = sq; }
  __syncthreads();
  float S = 0.f, SQ = 0.f;
#pragma unroll
  for (int i = 0; i < 6; i++) { S += red[i]; SQ += red[8 + i]; }
  float m = S * (1.f / 384.f);
  float rs = rsqrtf(SQ * (1.f / 384.f) - m * m + 1e-5f);
  hfin[(size_t)b * EMB + t] = (f16)((v - m) * rs * g[t] + bb[t]);
}

// ---------------- host ----------------
extern "C" void kernel_launch(void* const* d_in, const int* in_sizes, int n_in,
                              void* d_out, int out_size, void* d_ws, size_t ws_size,
                              hipStream_t stream) {
  const float* x      = (const float*)d_in[0];
  const float* conv_w = (const float*)d_in[1];
  const float* conv_b = (const float*)d_in[2];
  const float* cls_t  = (const float*)d_in[3];
  const float* pos    = (const float*)d_in[4];
  const float* ln1_g  = (const float*)d_in[5];
  const float* ln1_b  = (const float*)d_in[6];
  const float* inp_w  = (const float*)d_in[7];
  const float* inp_b  = (const float*)d_in[8];
  const float* outp_w = (const float*)d_in[9];
  const float* outp_b = (const float*)d_in[10];
  const float* rt_w   = (const float*)d_in[11];
  const float* rt_b   = (const float*)d_in[12];
  const float* ew1    = (const float*)d_in[13];
  const float* eb1    = (const float*)d_in[14];
  const float* ew2    = (const float*)d_in[15];
  const float* eb2    = (const float*)d_in[16];
  const float* ln2_g  = (const float*)d_in[17];
  const float* ln2_b  = (const float*)d_in[18];
  const float* head_w = (const float*)d_in[19];
  const float* head_b = (const float*)d_in[20];
  float* out = (float*)d_out;
  char* w = (char*)d_ws;
  if (ws_size < WS_NEEDED) return;

  f16* convw    = (f16*)(w + OFF_CONVW);
  f16* kvw      = (f16*)(w + OFF_KVW);
  f16* ew1t     = (f16*)(w + OFF_EW1T);
  f16* ew2t     = (f16*)(w + OFF_EW2T);
  float* ocls   = (float*)(w + OFF_OCLS);
  float* o2cls  = (float*)(w + OFF_O2CLS);
  f16* hcls16   = (f16*)(w + OFF_HCLS16);
  float* maskw  = (float*)(w + OFF_MASKW);
  f16* ehbuf    = (f16*)(w + OFF_EH);
  float* eobuf  = (float*)(w + OFF_EO);
  float* Hbuf   = (float*)(w + OFF_H);
  f16* xh       = (f16*)(w + OFF_XH);
  float* kvbuf  = (float*)(w + OFF_KV);
  f16* aim      = (f16*)(w + OFF_AIM);
  f16* headw16  = (f16*)(w + OFF_HEADW16);
  f16* hfin     = (f16*)(w + OFF_HFIN);

  // ---- weight prep ----
  cast_f16_k<<<dim3((294912 + 255) / 256), 256, 0, stream>>>(conv_w, convw, 294912);
  cast_f16_k<<<dim3((294912 + 255) / 256), 256, 0, stream>>>(inp_w + 384 * 384, kvw, 294912);
  cast_pad_k<<<dim3((1024 * 384 + 255) / 256), 256, 0, stream>>>(head_w, headw16);
  transpose_cast_k<<<dim3(48, 12, 4), 256, 0, stream>>>(ew1, ew1t, 384, 1536);
  transpose_cast_k<<<dim3(12, 48, 4), 256, 0, stream>>>(ew2, ew2t, 1536, 384);

  // ---- im2col + patch-embed GEMM -> Hbuf ----
  im2col_k<<<dim3(14, 3, 128), 256, 0, stream>>>(x, aim);
  gemm16_k<1><<<dim3(3, 196), 256, 0, stream>>>(aim, convw, conv_b, pos, Hbuf, 768, EMB);
  cls_init_k<<<dim3(128), dim3(384), 0, stream>>>(cls_t, pos, Hbuf);

  // ---- LN1 -> f16 (all tokens) ----
  ln_k<<<dim3(TTOK / 4), 256, 0, stream>>>(Hbuf, ln1_g, ln1_b, xh);

  // ---- K,V projection for all tokens ----
  gemm16_k<0><<<dim3(6, 197), 256, 0, stream>>>(xh, kvw, inp_b + 384, nullptr, kvbuf, EMB, 768);

  // ---- fused cls-LN + Q-proj + attention (exact f32) ----
  attn_cls_k<<<dim3(6, 128), 256, 0, stream>>>(
      Hbuf, ln1_g, ln1_b, inp_w, inp_b, kvbuf, ocls);

  // ---- out-proj on cls rows (exact f32) ----
  rowproj_k<<<dim3(128), 384, 0, stream>>>(ocls, outp_w, outp_b, o2cls);

  // ---- fused LN (ln1 params) + router top-2 ----
  ln_router_k<<<dim3(128), 384, 0, stream>>>(
      o2cls, ln1_g, ln1_b, rt_w, rt_b, hcls16, maskw);

  // ---- MoE on 128 cls tokens, all 4 experts fused per launch ----
  moe_gemm_k<1><<<dim3(12, 4), 256, 0, stream>>>(
      hcls16, 0, ew1t, (size_t)HID * EMB, eb1, HID,
      ehbuf, nullptr, (size_t)128 * HID, EMB, HID);
  moe_gemm_k<0><<<dim3(3, 4), 256, 0, stream>>>(
      ehbuf, (size_t)128 * HID, ew2t, (size_t)EMB * HID, eb2, EMB,
      nullptr, eobuf, (size_t)128 * EMB, HID, EMB);

  // ---- combine + LN2 -> f16, then MFMA head ----
  combine_ln2_k<<<dim3(128), 384, 0, stream>>>(eobuf, maskw, ln2_g, ln2_b, hfin);
  head_gemm_k<<<dim3(8), 256, 0, stream>>>(hfin, headw16, head_b, out);
  (void)in_sizes; (void)n_in; (void)out_size;
}

// Round 7
// 377.089 us; speedup vs baseline: 3.7981x; 1.0462x over previous
//
#include <hip/hip_runtime.h>
#include <cstdint>
#include <cstddef>

typedef _Float16 f16;
typedef _Float16 f16x8 __attribute__((ext_vector_type(8)));
typedef float    f32x4 __attribute__((ext_vector_type(4)));

// ---------------- problem constants ----------------
constexpr int NTOKC  = 197;
constexpr int TTOK   = 128 * 197;         // 25216
constexpr int EMB    = 384;
constexpr int HID    = 1536;

// ---------------- workspace layout (bytes) ----------------
constexpr size_t OFF_CONVW   = 0;                        // 384*768 f16
constexpr size_t OFF_KVW     = 589824;                   // 768*384 f16
constexpr size_t OFF_EW1T    = 1179648;                  // 4*1536*384 f16
constexpr size_t OFF_EW2T    = 5898240;                  // 4*384*1536 f16
constexpr size_t OFF_HEADW16 = 10616832;                 // 1024*384 f16
constexpr size_t OFF_XCLS16  = 11403264;                 // 384 f16
constexpr size_t OFF_Q       = 11404800;                 // 384 f32
constexpr size_t OFF_OCLS    = 11406336;                 // 128*384 f32
constexpr size_t OFF_O2CLS   = 11602944;                 // 128*384 f32
constexpr size_t OFF_HCLS16  = 11799552;                 // 128*384 f16
constexpr size_t OFF_MASKW   = 11897856;                 // 128*4 f32
constexpr size_t OFF_EH      = 11899904;                 // 4*128*1536 f16
constexpr size_t OFF_EPART   = 13472768;                 // 4kc*4e*128*384 f32 = 3 MB
constexpr size_t OFF_HFIN    = 16618496;                 // 128*384 f16
constexpr size_t OFF_XH      = 16716800;                 // TTOK*384 f16
constexpr size_t OFF_KV      = 36082688;                 // TTOK*768 f16
constexpr size_t OFF_AIM     = 74814464;                 // 25088*768 f16
constexpr size_t WS_NEEDED   = 113349632;                // ~113 MB

// ---------------- global_load_lds helper ----------------
__device__ __forceinline__ void gload16(const void* g, void* l) {
  __builtin_amdgcn_global_load_lds(
      (__attribute__((address_space(1))) void*)(void*)g,
      (__attribute__((address_space(3))) void*)l, 16, 0, 0);
}

// ---------------- prep kernels ----------------
__global__ __launch_bounds__(256) void cast_f16_k(
    const float* __restrict__ in, f16* __restrict__ o, int n) {
  int i = blockIdx.x * 256 + threadIdx.x;
  if (i < n) o[i] = (f16)in[i];
}

// head_w [1000][384] f32 -> [1024][384] f16, rows >=1000 zero
__global__ __launch_bounds__(256) void cast_pad_k(
    const float* __restrict__ in, f16* __restrict__ o) {
  int i = blockIdx.x * 256 + threadIdx.x;
  if (i < 1024 * 384) {
    int row = i / 384;
    o[i] = (row < 1000) ? (f16)in[i] : (f16)0.f;
  }
}

// in f32 [R][C] -> out f16 [C][R] per expert slice
__global__ __launch_bounds__(256) void transpose_cast_k(
    const float* __restrict__ in, f16* __restrict__ outp, int R, int C) {
  __shared__ float tile[32][33];
  int e = blockIdx.z;
  const float* pin = in + (size_t)e * R * C;
  f16* pout = outp + (size_t)e * R * C;
  int c0 = blockIdx.x * 32, r0 = blockIdx.y * 32;
  int tx = threadIdx.x & 31, ty = threadIdx.x >> 5;
#pragma unroll
  for (int i = 0; i < 4; i++)
    tile[ty + 8 * i][tx] = pin[(size_t)(r0 + ty + 8 * i) * C + c0 + tx];
  __syncthreads();
#pragma unroll
  for (int i = 0; i < 4; i++)
    pout[(size_t)(c0 + ty + 8 * i) * R + r0 + tx] = (f16)tile[tx][ty + 8 * i];
}

// ---------------- cls precompute: xcls = LN(cls+pos[0]); q = Wq.xcls + bq ----------
__global__ __launch_bounds__(384) void clsprep_k(
    const float* __restrict__ cls, const float* __restrict__ posw,
    const float* __restrict__ g, const float* __restrict__ bb,
    const float* __restrict__ Wq, const float* __restrict__ bq,
    f16* __restrict__ xcls16, float* __restrict__ qout) {
  __shared__ float xs[EMB];
  __shared__ float red[16];
  int t = threadIdx.x, lane = t & 63, wave = t >> 6;
  float v = cls[t] + posw[t];
  float s = v, sq = v * v;
#pragma unroll
  for (int off = 32; off; off >>= 1) {
    s += __shfl_xor(s, off);
    sq += __shfl_xor(sq, off);
  }
  if (lane == 0) { red[wave] = s; red[8 + wave] = sq; }
  __syncthreads();
  float S = 0.f, SQ = 0.f;
#pragma unroll
  for (int i = 0; i < 6; i++) { S += red[i]; SQ += red[8 + i]; }
  float m = S * (1.f / 384.f);
  float rs = rsqrtf(SQ * (1.f / 384.f) - m * m + 1e-5f);
  float y = (v - m) * rs * g[t] + bb[t];
  xs[t] = y;
  xcls16[t] = (f16)y;
  __syncthreads();
  const float4* w4 = (const float4*)(Wq + (size_t)t * EMB);
  const float4* s4 = (const float4*)xs;
  float a = bq[t];
#pragma unroll 8
  for (int i = 0; i < 96; i++) {
    float4 xx = s4[i], ww = w4[i];
    a += xx.x * ww.x + xx.y * ww.y + xx.z * ww.z + xx.w * ww.w;
  }
  qout[t] = a;
}

// broadcast xcls16 into xh cls rows
__global__ __launch_bounds__(384) void bcast_cls_k(
    const f16* __restrict__ xcls16, f16* __restrict__ xh) {
  int b = blockIdx.x, t = threadIdx.x;
  xh[(size_t)b * NTOKC * EMB + t] = xcls16[t];
}

// ---------------- im2col (f16) ----------------
__global__ __launch_bounds__(256) void im2col_k(
    const float* __restrict__ img, f16* __restrict__ A) {
  __shared__ float tile[16 * 224];
  int py = blockIdx.x, cch = blockIdx.y, b = blockIdx.z;
  const float* src = img + ((size_t)(b * 3 + cch) * 224 + py * 16) * 224;
  for (int i = threadIdx.x; i < 16 * 224; i += 256) tile[i] = src[i];
  __syncthreads();
  if (threadIdx.x < 224) {
    int px = threadIdx.x >> 4, ky = threadIdx.x & 15;
    size_t outb = ((size_t)(b * 196 + py * 14 + px)) * 768 + cch * 256 + ky * 16;
    f16 hv[16] __attribute__((aligned(16)));
#pragma unroll
    for (int t = 0; t < 16; t++) hv[t] = (f16)tile[ky * 224 + px * 16 + t];
    ((uint4*)(A + outb))[0] = ((uint4*)hv)[0];
    ((uint4*)(A + outb))[1] = ((uint4*)hv)[1];
  }
}

// ---------------- fused patch-embed GEMM + bias + pos + LN1 -> xh f16 -------------
// grid 392 blocks of 64 rows x 384 cols. Wave w owns rows [w*16, w*16+16).
__global__ __launch_bounds__(256) void embed_ln_k(
    const f16* __restrict__ A, const f16* __restrict__ B,
    const float* __restrict__ bias, const float* __restrict__ posw,
    const float* __restrict__ g, const float* __restrict__ bb,
    f16* __restrict__ xh) {
  __shared__ f16 As[64 * 32];     // 4 KB
  __shared__ f16 Bs[384 * 32];    // 24 KB
  const int K = 768;
  const int tid = threadIdx.x;
  const int lane = tid & 63;
  const int wave = tid >> 6;
  const int m0 = (int)blockIdx.x * 64;
  const int fr = lane & 15;
  const int fq = lane >> 4;

  f32x4 acc[24];
#pragma unroll
  for (int j = 0; j < 24; j++) acc[j] = f32x4{0.f, 0.f, 0.f, 0.f};

  const int sr = lane >> 2;
  const int sc = (lane & 3) * 8;
  const f16* ag = A + (size_t)(m0 + wave * 16 + sr) * K + sc;
  f16* la = As + wave * 16 * 32;
  const f16* bg = B + (size_t)(wave * 96 + sr) * K + sc;
  f16* lb = Bs + wave * 96 * 32;

  for (int k0 = 0; k0 < K; k0 += 32) {
    gload16(ag + k0, la);
#pragma unroll
    for (int t = 0; t < 6; t++)
      gload16(bg + (size_t)(t * 16) * K + k0, lb + t * 16 * 32);
    __syncthreads();
    f16x8 af = *(const f16x8*)&As[(wave * 16 + fr) * 32 + fq * 8];
#pragma unroll
    for (int j = 0; j < 24; j++) {
      f16x8 bf = *(const f16x8*)&Bs[(j * 16 + fr) * 32 + fq * 8];
      acc[j] = __builtin_amdgcn_mfma_f32_16x16x32_f16(af, bf, acc[j], 0, 0, 0);
    }
    __syncthreads();
  }

  // stage bias/gamma/beta into LDS (Bs is free now)
  float* sCB = (float*)Bs;
  float* sG  = sCB + 384;
  float* sB2 = sG + 384;
  for (int i = tid; i < 384; i += 256) {
    sCB[i] = bias[i]; sG[i] = g[i]; sB2[i] = bb[i];
  }
  __syncthreads();

#pragma unroll
  for (int rg = 0; rg < 4; rg++) {
    int row = m0 + wave * 16 + fq * 4 + rg;
    int bimg = row / 196;
    int pp = row - bimg * 196;
    const float* prow = posw + (size_t)(pp + 1) * EMB;
    float v[24];
    float s = 0.f, sq = 0.f;
#pragma unroll
    for (int j = 0; j < 24; j++) {
      int col = j * 16 + fr;
      float t = acc[j][rg] + sCB[col] + prow[col];
      v[j] = t;
      s += t; sq += t * t;
    }
    // reduce across the 16-lane fr-group (lane bits 0..3)
#pragma unroll
    for (int off = 1; off < 16; off <<= 1) {
      s += __shfl_xor(s, off);
      sq += __shfl_xor(sq, off);
    }
    float m = s * (1.f / 384.f);
    float rs = rsqrtf(sq * (1.f / 384.f) - m * m + 1e-5f);
    f16* orow = xh + ((size_t)bimg * NTOKC + pp + 1) * EMB;
#pragma unroll
    for (int j = 0; j < 24; j++) {
      int col = j * 16 + fr;
      orow[col] = (f16)((v[j] - m) * rs * sG[col] + sB2[col]);
    }
  }
}

// ---------------- KV GEMM (f16 out): kv = xh @ kvw^T + bias ----------------
__global__ __launch_bounds__(256) void gemm_kv_k(
    const f16* __restrict__ A, const f16* __restrict__ B,
    const float* __restrict__ bias, f16* __restrict__ Cout) {
  __shared__ f16 As[128 * 32];
  __shared__ f16 Bs[128 * 32];
  const int K = EMB, N = 768;
  const int tid = threadIdx.x;
  const int lane = tid & 63;
  const int wave = tid >> 6;
  const int m0 = (int)blockIdx.y * 128;
  const int n0 = (int)blockIdx.x * 128;
  const int wm = (wave >> 1) * 64;
  const int wn = (wave & 1) * 64;
  const int fr = lane & 15;
  const int fq = lane >> 4;

  f32x4 acc[4][4];
#pragma unroll
  for (int i = 0; i < 4; i++)
#pragma unroll
    for (int j = 0; j < 4; j++) acc[i][j] = f32x4{0.f, 0.f, 0.f, 0.f};

  const int srow = wave * 32 + (lane >> 2);
  const int scol = (lane & 3) * 8;
  const f16* ag = A + (size_t)(m0 + srow) * K + scol;
  const f16* bg = B + (size_t)(n0 + srow) * K + scol;
  const size_t rstep = (size_t)16 * K;
  f16* la = As + wave * 32 * 32;
  f16* lb = Bs + wave * 32 * 32;

  for (int k0 = 0; k0 < K; k0 += 32) {
    gload16(ag, la);          gload16(ag + rstep, la + 16 * 32);
    gload16(bg, lb);          gload16(bg + rstep, lb + 16 * 32);
    ag += 32; bg += 32;
    __syncthreads();
    f16x8 af[4], bf[4];
#pragma unroll
    for (int i = 0; i < 4; i++) {
      af[i] = *(const f16x8*)&As[(wm + i * 16 + fr) * 32 + fq * 8];
      bf[i] = *(const f16x8*)&Bs[(wn + i * 16 + fr) * 32 + fq * 8];
    }
#pragma unroll
    for (int i = 0; i < 4; i++)
#pragma unroll
      for (int j = 0; j < 4; j++)
        acc[i][j] = __builtin_amdgcn_mfma_f32_16x16x32_f16(af[i], bf[j], acc[i][j], 0, 0, 0);
    __syncthreads();
  }

#pragma unroll
  for (int i = 0; i < 4; i++)
#pragma unroll
    for (int j = 0; j < 4; j++)
#pragma unroll
      for (int rg = 0; rg < 4; rg++) {
        int gm = m0 + wm + i * 16 + fq * 4 + rg;
        int gn = n0 + wn + j * 16 + fr;
        Cout[(size_t)gm * N + gn] = (f16)(acc[i][j][rg] + bias[gn]);
      }
}

// ---------------- attention on cls token (f32 accumulate, f16 KV, precomputed q) ----
__global__ __launch_bounds__(256) void attn_cls_k(
    const float* __restrict__ qg, const f16* __restrict__ kv,
    float* __restrict__ ocls) {
  __shared__ float racc[64 * 64];
  __shared__ float rsum[64];
  const int h = blockIdx.x, b = blockIdx.y;
  const int tid = threadIdx.x;
  const int wave = tid >> 6, lane = tid & 63;
  const int r4 = lane >> 2, c = lane & 3;
  const int rowslot = wave * 16 + r4;

  float qv[16];
#pragma unroll
  for (int j = 0; j < 16; j++) qv[j] = qg[h * 64 + c * 16 + j];
  float acc[16];
#pragma unroll
  for (int j = 0; j < 16; j++) acc[j] = 0.f;
  float lsum = 0.f;

#pragma unroll
  for (int i = 0; i < 4; i++) {
    int row = rowslot + 64 * i;
    if (row < NTOKC) {
      const f16* kp = kv + ((size_t)b * NTOKC + row) * 768 + h * 64 + c * 16;
      f16x8 k0 = *(const f16x8*)kp;
      f16x8 k1 = *(const f16x8*)(kp + 8);
      float sc = 0.f;
#pragma unroll
      for (int j = 0; j < 8; j++) sc += qv[j] * (float)k0[j];
#pragma unroll
      for (int j = 0; j < 8; j++) sc += qv[8 + j] * (float)k1[j];
      sc += __shfl_xor(sc, 1);
      sc += __shfl_xor(sc, 2);
      float p = __expf(sc * 0.125f);
      lsum += p;
      const f16* vp = kp + 384;
      f16x8 v0 = *(const f16x8*)vp;
      f16x8 v1 = *(const f16x8*)(vp + 8);
#pragma unroll
      for (int j = 0; j < 8; j++) acc[j] += p * (float)v0[j];
#pragma unroll
      for (int j = 0; j < 8; j++) acc[8 + j] += p * (float)v1[j];
    }
  }
#pragma unroll
  for (int j = 0; j < 16; j++) racc[rowslot * 64 + c * 16 + j] = acc[j];
  if (c == 0) rsum[rowslot] = lsum;
  __syncthreads();

  if (tid < 64) {
    float o = 0.f, ls = 0.f;
#pragma unroll 8
    for (int r = 0; r < 64; r++) {
      o += racc[r * 64 + tid];
      ls += rsum[r];
    }
    ocls[(size_t)b * EMB + h * 64 + tid] = o / ls;
  }
}

// ---------------- cls-row out-proj (exact f32) ----------------
__global__ __launch_bounds__(384) void rowproj_k(
    const float* __restrict__ xf, const float* __restrict__ W,
    const float* __restrict__ bias, float* __restrict__ outp) {
  __shared__ float hx[EMB];
  int b = blockIdx.x, t = threadIdx.x;
  hx[t] = xf[(size_t)b * EMB + t];
  __syncthreads();
  const float4* w4 = (const float4*)(W + (size_t)t * EMB);
  const float4* s4 = (const float4*)hx;
  float a = bias[t];
#pragma unroll 8
  for (int i = 0; i < 96; i++) {
    float4 x = s4[i], w = w4[i];
    a += x.x * w.x + x.y * w.y + x.z * w.z + x.w * w.w;
  }
  outp[(size_t)b * EMB + t] = a;
}

// ---------------- fused LN (ln1 params) + router top-2 ----------------
__global__ __launch_bounds__(384) void ln_router_k(
    const float* __restrict__ o2cls, const float* __restrict__ g, const float* __restrict__ bb,
    const float* __restrict__ rw, const float* __restrict__ rb,
    f16* __restrict__ hcls16, float* __restrict__ maskw) {
  __shared__ float red[16];
  __shared__ float part[6][4];
  __shared__ float logits[4];
  int b = blockIdx.x, t = threadIdx.x;
  int lane = t & 63, wave = t >> 6;
  float v = o2cls[(size_t)b * EMB + t];
  float s = v, sq = v * v;
#pragma unroll
  for (int off = 32; off; off >>= 1) {
    s += __shfl_xor(s, off);
    sq += __shfl_xor(sq, off);
  }
  if (lane == 0) { red[wave] = s; red[8 + wave] = sq; }
  __syncthreads();
  float S = 0.f, SQ = 0.f;
#pragma unroll
  for (int i = 0; i < 6; i++) { S += red[i]; SQ += red[8 + i]; }
  float m = S * (1.f / 384.f);
  float rs = rsqrtf(SQ * (1.f / 384.f) - m * m + 1e-5f);
  float y = (v - m) * rs * g[t] + bb[t];
  hcls16[(size_t)b * EMB + t] = (f16)y;
  float p0 = y * rw[t];
  float p1 = y * rw[EMB + t];
  float p2 = y * rw[2 * EMB + t];
  float p3 = y * rw[3 * EMB + t];
#pragma unroll
  for (int off = 32; off; off >>= 1) {
    p0 += __shfl_xor(p0, off);
    p1 += __shfl_xor(p1, off);
    p2 += __shfl_xor(p2, off);
    p3 += __shfl_xor(p3, off);
  }
  if (lane == 0) { part[wave][0] = p0; part[wave][1] = p1; part[wave][2] = p2; part[wave][3] = p3; }
  __syncthreads();
  if (t < 4) {
    float a = rb[t];
#pragma unroll
    for (int i = 0; i < 6; i++) a += part[i][t];
    logits[t] = a;
  }
  __syncthreads();
  if (t == 0) {
    float l0 = logits[0], l1 = logits[1], l2 = logits[2], l3 = logits[3];
    int i1 = 0; float b1 = l0;
    if (l1 > b1) { b1 = l1; i1 = 1; }
    if (l2 > b1) { b1 = l2; i1 = 2; }
    if (l3 > b1) { b1 = l3; i1 = 3; }
    int i2 = -1; float b2 = 0.f;
    float lv[4] = {l0, l1, l2, l3};
#pragma unroll
    for (int i = 0; i < 4; i++) {
      if (i == i1) continue;
      if (i2 < 0 || lv[i] > b2) { i2 = i; b2 = lv[i]; }
    }
#pragma unroll
    for (int e = 0; e < 4; e++)
      maskw[(size_t)b * 4 + e] = (e == i1 || e == i2) ? 0.5f : 0.f;
  }
}

// ---------------- MoE GEMM1: hcls16[128x384] @ ew1t^T + GELU -> ehbuf f16 ---------
// grid (24 n-tiles of 64, 4 experts), 128x64 tile.
__global__ __launch_bounds__(256) void moe1_k(
    const f16* __restrict__ A, const f16* __restrict__ Bm,
    const float* __restrict__ bias, f16* __restrict__ outh) {
  __shared__ f16 As[128 * 32];   // 8 KB
  __shared__ f16 Bs[64 * 32];    // 4 KB
  const int K = EMB;
  const int tid = threadIdx.x;
  const int lane = tid & 63;
  const int wave = tid >> 6;
  const int e = (int)blockIdx.y;
  const int n0 = (int)blockIdx.x * 64;
  const int wm = (wave >> 1) * 64;
  const int wn = (wave & 1) * 32;
  const int fr = lane & 15;
  const int fq = lane >> 4;
  Bm += (size_t)e * HID * EMB;
  bias += (size_t)e * HID;

  f32x4 acc[4][2];
#pragma unroll
  for (int i = 0; i < 4; i++)
#pragma unroll
    for (int j = 0; j < 2; j++) acc[i][j] = f32x4{0.f, 0.f, 0.f, 0.f};

  const int sr = lane >> 2;
  const int sc = (lane & 3) * 8;
  const f16* ag = A + (size_t)(wave * 32 + sr) * K + sc;
  const f16* bg = Bm + (size_t)(n0 + wave * 16 + sr) * K + sc;
  const size_t rstep = (size_t)16 * K;
  f16* la = As + wave * 32 * 32;
  f16* lb = Bs + wave * 16 * 32;

  for (int k0 = 0; k0 < K; k0 += 32) {
    gload16(ag, la);  gload16(ag + rstep, la + 16 * 32);
    gload16(bg, lb);
    ag += 32; bg += 32;
    __syncthreads();
    f16x8 af[4], bf[2];
#pragma unroll
    for (int i = 0; i < 4; i++)
      af[i] = *(const f16x8*)&As[(wm + i * 16 + fr) * 32 + fq * 8];
#pragma unroll
    for (int j = 0; j < 2; j++)
      bf[j] = *(const f16x8*)&Bs[(wn + j * 16 + fr) * 32 + fq * 8];
#pragma unroll
    for (int i = 0; i < 4; i++)
#pragma unroll
      for (int j = 0; j < 2; j++)
        acc[i][j] = __builtin_amdgcn_mfma_f32_16x16x32_f16(af[i], bf[j], acc[i][j], 0, 0, 0);
    __syncthreads();
  }

#pragma unroll
  for (int i = 0; i < 4; i++)
#pragma unroll
    for (int j = 0; j < 2; j++)
#pragma unroll
      for (int rg = 0; rg < 4; rg++) {
        int gm = wm + i * 16 + fq * 4 + rg;
        int gn = n0 + wn + j * 16 + fr;
        float v = acc[i][j][rg] + bias[gn];
        float gl = 0.5f * v * (1.0f + erff(v * 0.70710678118654752f));
        outh[(size_t)e * 128 * HID + (size_t)gm * HID + gn] = (f16)gl;
      }
}

// ---------------- MoE GEMM2 split-K: ehbuf @ ew2t^T -> partial f32 ----------------
// grid (6 n-tiles of 64, 4 experts, 4 k-chunks of 384).
__global__ __launch_bounds__(256) void moe2_k(
    const f16* __restrict__ EH, const f16* __restrict__ W2,
    float* __restrict__ part) {
  __shared__ f16 As[128 * 32];
  __shared__ f16 Bs[64 * 32];
  const int tid = threadIdx.x;
  const int lane = tid & 63;
  const int wave = tid >> 6;
  const int n0 = (int)blockIdx.x * 64;
  const int e = (int)blockIdx.y;
  const int kc = (int)blockIdx.z;
  const int wm = (wave >> 1) * 64;
  const int wn = (wave & 1) * 32;
  const int fr = lane & 15;
  const int fq = lane >> 4;
  const f16* A = EH + (size_t)e * 128 * HID + kc * 384;
  const f16* B = W2 + (size_t)e * EMB * HID + kc * 384;

  f32x4 acc[4][2];
#pragma unroll
  for (int i = 0; i < 4; i++)
#pragma unroll
    for (int j = 0; j < 2; j++) acc[i][j] = f32x4{0.f, 0.f, 0.f, 0.f};

  const int sr = lane >> 2;
  const int sc = (lane & 3) * 8;
  const f16* ag = A + (size_t)(wave * 32 + sr) * HID + sc;
  const f16* bg = B + (size_t)(n0 + wave * 16 + sr) * HID + sc;
  const size_t rstep = (size_t)16 * HID;
  f16* la = As + wave * 32 * 32;
  f16* lb = Bs + wave * 16 * 32;

  for (int k0 = 0; k0 < 384; k0 += 32) {
    gload16(ag, la);  gload16(ag + rstep, la + 16 * 32);
    gload16(bg, lb);
    ag += 32; bg += 32;
    __syncthreads();
    f16x8 af[4], bf[2];
#pragma unroll
    for (int i = 0; i < 4; i++)
      af[i] = *(const f16x8*)&As[(wm + i * 16 + fr) * 32 + fq * 8];
#pragma unroll
    for (int j = 0; j < 2; j++)
      bf[j] = *(const f16x8*)&Bs[(wn + j * 16 + fr) * 32 + fq * 8];
#pragma unroll
    for (int i = 0; i < 4; i++)
#pragma unroll
      for (int j = 0; j < 2; j++)
        acc[i][j] = __builtin_amdgcn_mfma_f32_16x16x32_f16(af[i], bf[j], acc[i][j], 0, 0, 0);
    __syncthreads();
  }

#pragma unroll
  for (int i = 0; i < 4; i++)
#pragma unroll
    for (int j = 0; j < 2; j++)
#pragma unroll
      for (int rg = 0; rg < 4; rg++) {
        int gm = wm + i * 16 + fq * 4 + rg;
        int gn = n0 + wn + j * 16 + fr;
        part[(((size_t)kc * 4 + e) * 128 + gm) * EMB + gn] = acc[i][j][rg];
      }
}

// ---------------- combine split-K + experts + LN2 -> f16 ----------------
__global__ __launch_bounds__(384) void combine_ln2_k(
    const float* __restrict__ part, const float* __restrict__ eb2,
    const float* __restrict__ maskw,
    const float* __restrict__ g, const float* __restrict__ bb,
    f16* __restrict__ hfin) {
  __shared__ float red[16];
  int b = blockIdx.x, t = threadIdx.x;
  int lane = t & 63, wave = t >> 6;
  float v = 0.f;
#pragma unroll
  for (int e = 0; e < 4; e++) {
    float s = eb2[e * EMB + t];
#pragma unroll
    for (int kc = 0; kc < 4; kc++)
      s += part[(((size_t)kc * 4 + e) * 128 + b) * EMB + t];
    v += maskw[b * 4 + e] * s;
  }
  float s = v, sq = v * v;
#pragma unroll
  for (int off = 32; off; off >>= 1) {
    s += __shfl_xor(s, off);
    sq += __shfl_xor(sq, off);
  }
  if (lane == 0) { red[wave] = s; red[8 + wave] = sq; }
  __syncthreads();
  float S = 0.f, SQ = 0.f;
#pragma unroll
  for (int i = 0; i < 6; i++) { S += red[i]; SQ += red[8 + i]; }
  float m = S * (1.f / 384.f);
  float rs = rsqrtf(SQ * (1.f / 384.f) - m * m + 1e-5f);
  hfin[(size_t)b * EMB + t] = (f16)((v - m) * rs * g[t] + bb[t]);
}

// ---------------- head GEMM: hfin[128x384] @ headw16^T[1024x384] -> out ------------
__global__ __launch_bounds__(256) void head_gemm_k(
    const f16* __restrict__ A, const f16* __restrict__ B,
    const float* __restrict__ hb, float* __restrict__ outp) {
  __shared__ f16 As[128 * 32];
  __shared__ f16 Bs[128 * 32];
  const int K = 384;
  const int tid = threadIdx.x;
  const int lane = tid & 63;
  const int wave = tid >> 6;
  const int n0 = (int)blockIdx.x * 128;
  const int wm = (wave >> 1) * 64;
  const int wn = (wave & 1) * 64;
  const int fr = lane & 15;
  const int fq = lane >> 4;

  f32x4 acc[4][4];
#pragma unroll
  for (int i = 0; i < 4; i++)
#pragma unroll
    for (int j = 0; j < 4; j++) acc[i][j] = f32x4{0.f, 0.f, 0.f, 0.f};

  const int srow = wave * 32 + (lane >> 2);
  const int scol = (lane & 3) * 8;
  const f16* ag = A + (size_t)srow * K + scol;
  const f16* bg = B + (size_t)(n0 + srow) * K + scol;
  const size_t rstep = (size_t)16 * K;
  f16* la = As + wave * 32 * 32;
  f16* lb = Bs + wave * 32 * 32;

  for (int k0 = 0; k0 < K; k0 += 32) {
    gload16(ag, la);          gload16(ag + rstep, la + 16 * 32);
    gload16(bg, lb);          gload16(bg + rstep, lb + 16 * 32);
    ag += 32; bg += 32;
    __syncthreads();
    f16x8 af[4], bf[4];
#pragma unroll
    for (int i = 0; i < 4; i++) {
      af[i] = *(const f16x8*)&As[(wm + i * 16 + fr) * 32 + fq * 8];
      bf[i] = *(const f16x8*)&Bs[(wn + i * 16 + fr) * 32 + fq * 8];
    }
#pragma unroll
    for (int i = 0; i < 4; i++)
#pragma unroll
      for (int j = 0; j < 4; j++)
        acc[i][j] = __builtin_amdgcn_mfma_f32_16x16x32_f16(af[i], bf[j], acc[i][j], 0, 0, 0);
    __syncthreads();
  }

#pragma unroll
  for (int i = 0; i < 4; i++)
#pragma unroll
    for (int j = 0; j < 4; j++)
#pragma unroll
      for (int rg = 0; rg < 4; rg++) {
        int gm = wm + i * 16 + fq * 4 + rg;
        int gn = n0 + wn + j * 16 + fr;
        if (gn < 1000)
          outp[(size_t)gm * 1000 + gn] = acc[i][j][rg] + hb[gn];
      }
}

// ---------------- host ----------------
extern "C" void kernel_launch(void* const* d_in, const int* in_sizes, int n_in,
                              void* d_out, int out_size, void* d_ws, size_t ws_size,
                              hipStream_t stream) {
  const float* x      = (const float*)d_in[0];
  const float* conv_w = (const float*)d_in[1];
  const float* conv_b = (const float*)d_in[2];
  const float* cls_t  = (const float*)d_in[3];
  const float* pos    = (const float*)d_in[4];
  const float* ln1_g  = (const float*)d_in[5];
  const float* ln1_b  = (const float*)d_in[6];
  const float* inp_w  = (const float*)d_in[7];
  const float* inp_b  = (const float*)d_in[8];
  const float* outp_w = (const float*)d_in[9];
  const float* outp_b = (const float*)d_in[10];
  const float* rt_w   = (const float*)d_in[11];
  const float* rt_b   = (const float*)d_in[12];
  const float* ew1    = (const float*)d_in[13];
  const float* eb1    = (const float*)d_in[14];
  const float* ew2    = (const float*)d_in[15];
  const float* eb2    = (const float*)d_in[16];
  const float* ln2_g  = (const float*)d_in[17];
  const float* ln2_b  = (const float*)d_in[18];
  const float* head_w = (const float*)d_in[19];
  const float* head_b = (const float*)d_in[20];
  float* out = (float*)d_out;
  char* w = (char*)d_ws;
  if (ws_size < WS_NEEDED) return;

  f16* convw    = (f16*)(w + OFF_CONVW);
  f16* kvw      = (f16*)(w + OFF_KVW);
  f16* ew1t     = (f16*)(w + OFF_EW1T);
  f16* ew2t     = (f16*)(w + OFF_EW2T);
  f16* headw16  = (f16*)(w + OFF_HEADW16);
  f16* xcls16   = (f16*)(w + OFF_XCLS16);
  float* qvec   = (float*)(w + OFF_Q);
  float* ocls   = (float*)(w + OFF_OCLS);
  float* o2cls  = (float*)(w + OFF_O2CLS);
  f16* hcls16   = (f16*)(w + OFF_HCLS16);
  float* maskw  = (float*)(w + OFF_MASKW);
  f16* ehbuf    = (f16*)(w + OFF_EH);
  float* epart  = (float*)(w + OFF_EPART);
  f16* hfin     = (f16*)(w + OFF_HFIN);
  f16* xh       = (f16*)(w + OFF_XH);
  f16* kvbuf    = (f16*)(w + OFF_KV);
  f16* aim      = (f16*)(w + OFF_AIM);

  // ---- weight prep ----
  cast_f16_k<<<dim3((294912 + 255) / 256), 256, 0, stream>>>(conv_w, convw, 294912);
  cast_f16_k<<<dim3((294912 + 255) / 256), 256, 0, stream>>>(inp_w + 384 * 384, kvw, 294912);
  cast_pad_k<<<dim3((1024 * 384 + 255) / 256), 256, 0, stream>>>(head_w, headw16);
  transpose_cast_k<<<dim3(48, 12, 4), 256, 0, stream>>>(ew1, ew1t, 384, 1536);
  transpose_cast_k<<<dim3(12, 48, 4), 256, 0, stream>>>(ew2, ew2t, 1536, 384);

  // ---- cls precompute + broadcast ----
  clsprep_k<<<dim3(1), 384, 0, stream>>>(cls_t, pos, ln1_g, ln1_b, inp_w, inp_b, xcls16, qvec);
  bcast_cls_k<<<dim3(128), 384, 0, stream>>>(xcls16, xh);

  // ---- im2col + fused embed GEMM + LN1 -> xh patch rows ----
  im2col_k<<<dim3(14, 3, 128), 256, 0, stream>>>(x, aim);
  embed_ln_k<<<dim3(392), 256, 0, stream>>>(aim, convw, conv_b, pos, ln1_g, ln1_b, xh);

  // ---- K,V projection (f16 out) ----
  gemm_kv_k<<<dim3(6, 197), 256, 0, stream>>>(xh, kvw, inp_b + 384, kvbuf);

  // ---- cls attention ----
  attn_cls_k<<<dim3(6, 128), 256, 0, stream>>>(qvec, kvbuf, ocls);

  // ---- out-proj (exact f32) ----
  rowproj_k<<<dim3(128), 384, 0, stream>>>(ocls, outp_w, outp_b, o2cls);

  // ---- LN (ln1 params) + router top-2 ----
  ln_router_k<<<dim3(128), 384, 0, stream>>>(
      o2cls, ln1_g, ln1_b, rt_w, rt_b, hcls16, maskw);

  // ---- MoE ----
  moe1_k<<<dim3(24, 4), 256, 0, stream>>>(hcls16, ew1t, eb1, ehbuf);
  moe2_k<<<dim3(6, 4, 4), 256, 0, stream>>>(ehbuf, ew2t, epart);
  combine_ln2_k<<<dim3(128), 384, 0, stream>>>(epart, eb2, maskw, ln2_g, ln2_b, hfin);

  // ---- head ----
  head_gemm_k<<<dim3(8), 256, 0, stream>>>(hfin, headw16, head_b, out);
  (void)in_sizes; (void)n_in; (void)out_size;
}

// Round 8
// 355.755 us; speedup vs baseline: 4.0258x; 1.0600x over previous
//
#include <hip/hip_runtime.h>
#include <cstdint>
#include <cstddef>

typedef _Float16 f16;
typedef _Float16 f16x8 __attribute__((ext_vector_type(8)));
typedef float    f32x4 __attribute__((ext_vector_type(4)));

// ---------------- problem constants ----------------
constexpr int NTOKC  = 197;
constexpr int TTOK   = 128 * 197;         // 25216
constexpr int EMB    = 384;
constexpr int HID    = 1536;

// ---------------- workspace layout (bytes) ----------------
constexpr size_t OFF_CONVW   = 0;                        // 384*768 f16
constexpr size_t OFF_KVW     = 589824;                   // 768*384 f16
constexpr size_t OFF_EW1T    = 1179648;                  // 4*1536*384 f16
constexpr size_t OFF_EW2T    = 5898240;                  // 4*384*1536 f16
constexpr size_t OFF_HEADW16 = 10616832;                 // 1024*384 f16
constexpr size_t OFF_XCLS16  = 11403264;                 // 384 f16
constexpr size_t OFF_Q       = 11404800;                 // 384 f32
constexpr size_t OFF_OCLS    = 11406336;                 // 128*384 f32
constexpr size_t OFF_O2CLS   = 11602944;                 // 128*384 f32
constexpr size_t OFF_HCLS16  = 11799552;                 // 128*384 f16
constexpr size_t OFF_MASKW   = 11897856;                 // 128*4 f32
constexpr size_t OFF_EH      = 11899904;                 // 4*128*1536 f16
constexpr size_t OFF_EPART   = 13472768;                 // 4kc*4e*128*384 f32
constexpr size_t OFF_HFIN    = 16618496;                 // 128*384 f16
constexpr size_t OFF_XH      = 16716800;                 // TTOK*384 f16
constexpr size_t OFF_KV      = 36082688;                 // TTOK*768 f16
constexpr size_t OFF_AIM     = 74814464;                 // 25088*768 f16
constexpr size_t WS_NEEDED   = 113349632;                // ~113 MB

// ---------------- global_load_lds helper ----------------
__device__ __forceinline__ void gload16(const void* g, void* l) {
  __builtin_amdgcn_global_load_lds(
      (__attribute__((address_space(1))) void*)(void*)g,
      (__attribute__((address_space(3))) void*)l, 16, 0, 0);
}

// ---------------- prep kernels ----------------
__global__ __launch_bounds__(256) void cast_f16_k(
    const float* __restrict__ in, f16* __restrict__ o, int n) {
  int i = blockIdx.x * 256 + threadIdx.x;
  if (i < n) o[i] = (f16)in[i];
}

__global__ __launch_bounds__(256) void cast_pad_k(
    const float* __restrict__ in, f16* __restrict__ o) {
  int i = blockIdx.x * 256 + threadIdx.x;
  if (i < 1024 * 384) {
    int row = i / 384;
    o[i] = (row < 1000) ? (f16)in[i] : (f16)0.f;
  }
}

__global__ __launch_bounds__(256) void transpose_cast_k(
    const float* __restrict__ in, f16* __restrict__ outp, int R, int C) {
  __shared__ float tile[32][33];
  int e = blockIdx.z;
  const float* pin = in + (size_t)e * R * C;
  f16* pout = outp + (size_t)e * R * C;
  int c0 = blockIdx.x * 32, r0 = blockIdx.y * 32;
  int tx = threadIdx.x & 31, ty = threadIdx.x >> 5;
#pragma unroll
  for (int i = 0; i < 4; i++)
    tile[ty + 8 * i][tx] = pin[(size_t)(r0 + ty + 8 * i) * C + c0 + tx];
  __syncthreads();
#pragma unroll
  for (int i = 0; i < 4; i++)
    pout[(size_t)(c0 + ty + 8 * i) * R + r0 + tx] = (f16)tile[tx][ty + 8 * i];
}

// ---------------- cls precompute: xcls = LN(cls+pos[0]); q = Wq.xcls + bq ----------
__global__ __launch_bounds__(384) void clsprep_k(
    const float* __restrict__ cls, const float* __restrict__ posw,
    const float* __restrict__ g, const float* __restrict__ bb,
    const float* __restrict__ Wq, const float* __restrict__ bq,
    f16* __restrict__ xcls16, float* __restrict__ qout) {
  __shared__ float xs[EMB];
  __shared__ float red[16];
  int t = threadIdx.x, lane = t & 63, wave = t >> 6;
  float v = cls[t] + posw[t];
  float s = v, sq = v * v;
#pragma unroll
  for (int off = 32; off; off >>= 1) {
    s += __shfl_xor(s, off);
    sq += __shfl_xor(sq, off);
  }
  if (lane == 0) { red[wave] = s; red[8 + wave] = sq; }
  __syncthreads();
  float S = 0.f, SQ = 0.f;
#pragma unroll
  for (int i = 0; i < 6; i++) { S += red[i]; SQ += red[8 + i]; }
  float m = S * (1.f / 384.f);
  float rs = rsqrtf(SQ * (1.f / 384.f) - m * m + 1e-5f);
  float y = (v - m) * rs * g[t] + bb[t];
  xs[t] = y;
  xcls16[t] = (f16)y;
  __syncthreads();
  const float4* w4 = (const float4*)(Wq + (size_t)t * EMB);
  const float4* s4 = (const float4*)xs;
  float a = bq[t];
#pragma unroll 8
  for (int i = 0; i < 96; i++) {
    float4 xx = s4[i], ww = w4[i];
    a += xx.x * ww.x + xx.y * ww.y + xx.z * ww.z + xx.w * ww.w;
  }
  qout[t] = a;
}

__global__ __launch_bounds__(384) void bcast_cls_k(
    const f16* __restrict__ xcls16, f16* __restrict__ xh) {
  int b = blockIdx.x, t = threadIdx.x;
  xh[(size_t)b * NTOKC * EMB + t] = xcls16[t];
}

// ---------------- im2col (f16) ----------------
__global__ __launch_bounds__(256) void im2col_k(
    const float* __restrict__ img, f16* __restrict__ A) {
  __shared__ float tile[16 * 224];
  int py = blockIdx.x, cch = blockIdx.y, b = blockIdx.z;
  const float* src = img + ((size_t)(b * 3 + cch) * 224 + py * 16) * 224;
  for (int i = threadIdx.x; i < 16 * 224; i += 256) tile[i] = src[i];
  __syncthreads();
  if (threadIdx.x < 224) {
    int px = threadIdx.x >> 4, ky = threadIdx.x & 15;
    size_t outb = ((size_t)(b * 196 + py * 14 + px)) * 768 + cch * 256 + ky * 16;
    f16 hv[16] __attribute__((aligned(16)));
#pragma unroll
    for (int t = 0; t < 16; t++) hv[t] = (f16)tile[ky * 224 + px * 16 + t];
    ((uint4*)(A + outb))[0] = ((uint4*)hv)[0];
    ((uint4*)(A + outb))[1] = ((uint4*)hv)[1];
  }
}

// ---------------- fused patch-embed GEMM + bias + pos + LN1 -> xh f16 -------------
// 1024-thr blocks (16 waves), block = 64 rows x 384 cols, K=768.
// wave w: rowgrp=w&3 (rows rowgrp*16..+16), colgrp=w>>2 (cols colgrp*96..+96).
// acc[6] per wave (24 VGPRs) -> high occupancy; LN via fr-butterfly + LDS partials.
__global__ __launch_bounds__(1024) void embed_ln_k(
    const f16* __restrict__ A, const f16* __restrict__ B,
    const float* __restrict__ bias, const float* __restrict__ posw,
    const float* __restrict__ g, const float* __restrict__ bb,
    f16* __restrict__ xh) {
  __shared__ f16 As[64 * 32];       // 4 KB
  __shared__ f16 Bs[384 * 32];      // 24 KB
  __shared__ float prm[3 * 384];    // bias | gamma | beta
  __shared__ float psum[64 * 4];
  __shared__ float pqsum[64 * 4];
  const int K = 768;
  const int tid = threadIdx.x;
  const int lane = tid & 63;
  const int wave = tid >> 6;        // 0..15
  const int rowgrp = wave & 3;
  const int colgrp = wave >> 2;
  const int m0 = (int)blockIdx.x * 64;
  const int fr = lane & 15;
  const int fq = lane >> 4;

  for (int i = tid; i < 384; i += 1024) {
    prm[i] = bias[i]; prm[384 + i] = g[i]; prm[768 + i] = bb[i];
  }

  f32x4 acc[6];
#pragma unroll
  for (int j = 0; j < 6; j++) acc[j] = f32x4{0.f, 0.f, 0.f, 0.f};

  const int sr = lane >> 2, sc = (lane & 3) * 8;
  const f16* ga = nullptr;
  const f16* gb0 = nullptr;
  const f16* gb1 = nullptr;
  f16* la = nullptr;
  f16* lb0 = nullptr;
  f16* lb1 = nullptr;
  if (wave < 4) {
    ga = A + (size_t)(m0 + wave * 16 + sr) * K + sc;
    la = As + wave * 16 * 32;
  } else {
    int brow = (wave - 4) * 32;
    gb0 = B + (size_t)(brow + sr) * K + sc;
    gb1 = gb0 + (size_t)16 * K;
    lb0 = Bs + brow * 32;
    lb1 = lb0 + 16 * 32;
  }

  for (int k0 = 0; k0 < K; k0 += 32) {
    if (wave < 4) { gload16(ga, la); ga += 32; }
    else { gload16(gb0, lb0); gload16(gb1, lb1); gb0 += 32; gb1 += 32; }
    __syncthreads();
    f16x8 af = *(const f16x8*)&As[(rowgrp * 16 + fr) * 32 + fq * 8];
#pragma unroll
    for (int j = 0; j < 6; j++) {
      f16x8 bf = *(const f16x8*)&Bs[(colgrp * 96 + j * 16 + fr) * 32 + fq * 8];
      acc[j] = __builtin_amdgcn_mfma_f32_16x16x32_f16(af, bf, acc[j], 0, 0, 0);
    }
    __syncthreads();
  }

  // ---- epilogue: bias+pos, LN partials ----
  float v[4][6];
#pragma unroll
  for (int rg = 0; rg < 4; rg++) {
    int lrow = rowgrp * 16 + fq * 4 + rg;
    int row = m0 + lrow;
    int bimg = row / 196;
    int pp = row - bimg * 196;
    const float* prow = posw + (size_t)(pp + 1) * EMB;
    float s = 0.f, sq = 0.f;
#pragma unroll
    for (int j = 0; j < 6; j++) {
      int col = colgrp * 96 + j * 16 + fr;
      float t = acc[j][rg] + prm[col] + prow[col];
      v[rg][j] = t;
      s += t; sq += t * t;
    }
#pragma unroll
    for (int off = 1; off < 16; off <<= 1) {
      s += __shfl_xor(s, off);
      sq += __shfl_xor(sq, off);
    }
    if (fr == 0) { psum[lrow * 4 + colgrp] = s; pqsum[lrow * 4 + colgrp] = sq; }
  }
  __syncthreads();

#pragma unroll
  for (int rg = 0; rg < 4; rg++) {
    int lrow = rowgrp * 16 + fq * 4 + rg;
    float S = psum[lrow * 4] + psum[lrow * 4 + 1] + psum[lrow * 4 + 2] + psum[lrow * 4 + 3];
    float SQ = pqsum[lrow * 4] + pqsum[lrow * 4 + 1] + pqsum[lrow * 4 + 2] + pqsum[lrow * 4 + 3];
    float m = S * (1.f / 384.f);
    float rs = rsqrtf(SQ * (1.f / 384.f) - m * m + 1e-5f);
    int row = m0 + lrow;
    int bimg = row / 196;
    int pp = row - bimg * 196;
    f16* orow = xh + ((size_t)bimg * NTOKC + pp + 1) * EMB;
#pragma unroll
    for (int j = 0; j < 6; j++) {
      int col = colgrp * 96 + j * 16 + fr;
      orow[col] = (f16)((v[rg][j] - m) * rs * prm[384 + col] + prm[768 + col]);
    }
  }
}

// ---------------- KV GEMM (f16 out), 128x64 tile, 4 waves of 64x32 --------------
// grid (12 n-tiles, 197 m-tiles) = 2364 blocks, 9456 waves.
__global__ __launch_bounds__(256) void gemm_kv_k(
    const f16* __restrict__ A, const f16* __restrict__ B,
    const float* __restrict__ bias, f16* __restrict__ Cout) {
  __shared__ f16 As[128 * 32];   // 8 KB
  __shared__ f16 Bs[64 * 32];    // 4 KB
  const int K = EMB, N = 768;
  const int tid = threadIdx.x;
  const int lane = tid & 63;
  const int wave = tid >> 6;
  const int m0 = (int)blockIdx.y * 128;
  const int n0 = (int)blockIdx.x * 64;
  const int wm = (wave & 1) * 64;
  const int wn = (wave >> 1) * 32;
  const int fr = lane & 15;
  const int fq = lane >> 4;

  f32x4 acc[4][2];
#pragma unroll
  for (int i = 0; i < 4; i++)
#pragma unroll
    for (int j = 0; j < 2; j++) acc[i][j] = f32x4{0.f, 0.f, 0.f, 0.f};

  const int sr = lane >> 2, sc = (lane & 3) * 8;
  const f16* ag = A + (size_t)(m0 + wave * 32 + sr) * K + sc;
  const f16* bg = B + (size_t)(n0 + wave * 16 + sr) * K + sc;
  const size_t rstep = (size_t)16 * K;
  f16* la = As + wave * 32 * 32;
  f16* lb = Bs + wave * 16 * 32;

  for (int k0 = 0; k0 < K; k0 += 32) {
    gload16(ag, la);  gload16(ag + rstep, la + 16 * 32);
    gload16(bg, lb);
    ag += 32; bg += 32;
    __syncthreads();
    f16x8 af[4], bf[2];
#pragma unroll
    for (int i = 0; i < 4; i++)
      af[i] = *(const f16x8*)&As[(wm + i * 16 + fr) * 32 + fq * 8];
#pragma unroll
    for (int j = 0; j < 2; j++)
      bf[j] = *(const f16x8*)&Bs[(wn + j * 16 + fr) * 32 + fq * 8];
#pragma unroll
    for (int i = 0; i < 4; i++)
#pragma unroll
      for (int j = 0; j < 2; j++)
        acc[i][j] = __builtin_amdgcn_mfma_f32_16x16x32_f16(af[i], bf[j], acc[i][j], 0, 0, 0);
    __syncthreads();
  }

#pragma unroll
  for (int i = 0; i < 4; i++)
#pragma unroll
    for (int j = 0; j < 2; j++)
#pragma unroll
      for (int rg = 0; rg < 4; rg++) {
        int gm = m0 + wm + i * 16 + fq * 4 + rg;
        int gn = n0 + wn + j * 16 + fr;
        Cout[(size_t)gm * N + gn] = (f16)(acc[i][j][rg] + bias[gn]);
      }
}

// ---------------- attention on cls token (f32 accumulate, f16 KV) ----------------
__global__ __launch_bounds__(256) void attn_cls_k(
    const float* __restrict__ qg, const f16* __restrict__ kv,
    float* __restrict__ ocls) {
  __shared__ float racc[64 * 64];
  __shared__ float rsum[64];
  const int h = blockIdx.x, b = blockIdx.y;
  const int tid = threadIdx.x;
  const int wave = tid >> 6, lane = tid & 63;
  const int r4 = lane >> 2, c = lane & 3;
  const int rowslot = wave * 16 + r4;

  float qv[16];
#pragma unroll
  for (int j = 0; j < 16; j++) qv[j] = qg[h * 64 + c * 16 + j];
  float acc[16];
#pragma unroll
  for (int j = 0; j < 16; j++) acc[j] = 0.f;
  float lsum = 0.f;

#pragma unroll
  for (int i = 0; i < 4; i++) {
    int row = rowslot + 64 * i;
    if (row < NTOKC) {
      const f16* kp = kv + ((size_t)b * NTOKC + row) * 768 + h * 64 + c * 16;
      f16x8 k0 = *(const f16x8*)kp;
      f16x8 k1 = *(const f16x8*)(kp + 8);
      float sc = 0.f;
#pragma unroll
      for (int j = 0; j < 8; j++) sc += qv[j] * (float)k0[j];
#pragma unroll
      for (int j = 0; j < 8; j++) sc += qv[8 + j] * (float)k1[j];
      sc += __shfl_xor(sc, 1);
      sc += __shfl_xor(sc, 2);
      float p = __expf(sc * 0.125f);
      lsum += p;
      const f16* vp = kp + 384;
      f16x8 v0 = *(const f16x8*)vp;
      f16x8 v1 = *(const f16x8*)(vp + 8);
#pragma unroll
      for (int j = 0; j < 8; j++) acc[j] += p * (float)v0[j];
#pragma unroll
      for (int j = 0; j < 8; j++) acc[8 + j] += p * (float)v1[j];
    }
  }
#pragma unroll
  for (int j = 0; j < 16; j++) racc[rowslot * 64 + c * 16 + j] = acc[j];
  if (c == 0) rsum[rowslot] = lsum;
  __syncthreads();

  if (tid < 64) {
    float o = 0.f, ls = 0.f;
#pragma unroll 8
    for (int r = 0; r < 64; r++) {
      o += racc[r * 64 + tid];
      ls += rsum[r];
    }
    ocls[(size_t)b * EMB + h * 64 + tid] = o / ls;
  }
}

// ---------------- cls-row out-proj (exact f32) ----------------
__global__ __launch_bounds__(384) void rowproj_k(
    const float* __restrict__ xf, const float* __restrict__ W,
    const float* __restrict__ bias, float* __restrict__ outp) {
  __shared__ float hx[EMB];
  int b = blockIdx.x, t = threadIdx.x;
  hx[t] = xf[(size_t)b * EMB + t];
  __syncthreads();
  const float4* w4 = (const float4*)(W + (size_t)t * EMB);
  const float4* s4 = (const float4*)hx;
  float a = bias[t];
#pragma unroll 8
  for (int i = 0; i < 96; i++) {
    float4 x = s4[i], w = w4[i];
    a += x.x * w.x + x.y * w.y + x.z * w.z + x.w * w.w;
  }
  outp[(size_t)b * EMB + t] = a;
}

// ---------------- fused LN (ln1 params) + router top-2 ----------------
__global__ __launch_bounds__(384) void ln_router_k(
    const float* __restrict__ o2cls, const float* __restrict__ g, const float* __restrict__ bb,
    const float* __restrict__ rw, const float* __restrict__ rb,
    f16* __restrict__ hcls16, float* __restrict__ maskw) {
  __shared__ float red[16];
  __shared__ float part[6][4];
  __shared__ float logits[4];
  int b = blockIdx.x, t = threadIdx.x;
  int lane = t & 63, wave = t >> 6;
  float v = o2cls[(size_t)b * EMB + t];
  float s = v, sq = v * v;
#pragma unroll
  for (int off = 32; off; off >>= 1) {
    s += __shfl_xor(s, off);
    sq += __shfl_xor(sq, off);
  }
  if (lane == 0) { red[wave] = s; red[8 + wave] = sq; }
  __syncthreads();
  float S = 0.f, SQ = 0.f;
#pragma unroll
  for (int i = 0; i < 6; i++) { S += red[i]; SQ += red[8 + i]; }
  float m = S * (1.f / 384.f);
  float rs = rsqrtf(SQ * (1.f / 384.f) - m * m + 1e-5f);
  float y = (v - m) * rs * g[t] + bb[t];
  hcls16[(size_t)b * EMB + t] = (f16)y;
  float p0 = y * rw[t];
  float p1 = y * rw[EMB + t];
  float p2 = y * rw[2 * EMB + t];
  float p3 = y * rw[3 * EMB + t];
#pragma unroll
  for (int off = 32; off; off >>= 1) {
    p0 += __shfl_xor(p0, off);
    p1 += __shfl_xor(p1, off);
    p2 += __shfl_xor(p2, off);
    p3 += __shfl_xor(p3, off);
  }
  if (lane == 0) { part[wave][0] = p0; part[wave][1] = p1; part[wave][2] = p2; part[wave][3] = p3; }
  __syncthreads();
  if (t < 4) {
    float a = rb[t];
#pragma unroll
    for (int i = 0; i < 6; i++) a += part[i][t];
    logits[t] = a;
  }
  __syncthreads();
  if (t == 0) {
    float l0 = logits[0], l1 = logits[1], l2 = logits[2], l3 = logits[3];
    int i1 = 0; float b1 = l0;
    if (l1 > b1) { b1 = l1; i1 = 1; }
    if (l2 > b1) { b1 = l2; i1 = 2; }
    if (l3 > b1) { b1 = l3; i1 = 3; }
    int i2 = -1; float b2 = 0.f;
    float lv[4] = {l0, l1, l2, l3};
#pragma unroll
    for (int i = 0; i < 4; i++) {
      if (i == i1) continue;
      if (i2 < 0 || lv[i] > b2) { i2 = i; b2 = lv[i]; }
    }
#pragma unroll
    for (int e = 0; e < 4; e++)
      maskw[(size_t)b * 4 + e] = (e == i1 || e == i2) ? 0.5f : 0.f;
  }
}

// ---------------- MoE GEMM1: hcls16[128x384] @ ew1t^T + GELU -> ehbuf f16 ---------
__global__ __launch_bounds__(256) void moe1_k(
    const f16* __restrict__ A, const f16* __restrict__ Bm,
    const float* __restrict__ bias, f16* __restrict__ outh) {
  __shared__ f16 As[128 * 32];
  __shared__ f16 Bs[64 * 32];
  const int K = EMB;
  const int tid = threadIdx.x;
  const int lane = tid & 63;
  const int wave = tid >> 6;
  const int e = (int)blockIdx.y;
  const int n0 = (int)blockIdx.x * 64;
  const int wm = (wave >> 1) * 64;
  const int wn = (wave & 1) * 32;
  const int fr = lane & 15;
  const int fq = lane >> 4;
  Bm += (size_t)e * HID * EMB;
  bias += (size_t)e * HID;

  f32x4 acc[4][2];
#pragma unroll
  for (int i = 0; i < 4; i++)
#pragma unroll
    for (int j = 0; j < 2; j++) acc[i][j] = f32x4{0.f, 0.f, 0.f, 0.f};

  const int sr = lane >> 2;
  const int sc = (lane & 3) * 8;
  const f16* ag = A + (size_t)(wave * 32 + sr) * K + sc;
  const f16* bg = Bm + (size_t)(n0 + wave * 16 + sr) * K + sc;
  const size_t rstep = (size_t)16 * K;
  f16* la = As + wave * 32 * 32;
  f16* lb = Bs + wave * 16 * 32;

  for (int k0 = 0; k0 < K; k0 += 32) {
    gload16(ag, la);  gload16(ag + rstep, la + 16 * 32);
    gload16(bg, lb);
    ag += 32; bg += 32;
    __syncthreads();
    f16x8 af[4], bf[2];
#pragma unroll
    for (int i = 0; i < 4; i++)
      af[i] = *(const f16x8*)&As[(wm + i * 16 + fr) * 32 + fq * 8];
#pragma unroll
    for (int j = 0; j < 2; j++)
      bf[j] = *(const f16x8*)&Bs[(wn + j * 16 + fr) * 32 + fq * 8];
#pragma unroll
    for (int i = 0; i < 4; i++)
#pragma unroll
      for (int j = 0; j < 2; j++)
        acc[i][j] = __builtin_amdgcn_mfma_f32_16x16x32_f16(af[i], bf[j], acc[i][j], 0, 0, 0);
    __syncthreads();
  }

#pragma unroll
  for (int i = 0; i < 4; i++)
#pragma unroll
    for (int j = 0; j < 2; j++)
#pragma unroll
      for (int rg = 0; rg < 4; rg++) {
        int gm = wm + i * 16 + fq * 4 + rg;
        int gn = n0 + wn + j * 16 + fr;
        float v = acc[i][j][rg] + bias[gn];
        float gl = 0.5f * v * (1.0f + erff(v * 0.70710678118654752f));
        outh[(size_t)e * 128 * HID + (size_t)gm * HID + gn] = (f16)gl;
      }
}

// ---------------- MoE GEMM2 split-K ----------------
__global__ __launch_bounds__(256) void moe2_k(
    const f16* __restrict__ EH, const f16* __restrict__ W2,
    float* __restrict__ part) {
  __shared__ f16 As[128 * 32];
  __shared__ f16 Bs[64 * 32];
  const int tid = threadIdx.x;
  const int lane = tid & 63;
  const int wave = tid >> 6;
  const int n0 = (int)blockIdx.x * 64;
  const int e = (int)blockIdx.y;
  const int kc = (int)blockIdx.z;
  const int wm = (wave >> 1) * 64;
  const int wn = (wave & 1) * 32;
  const int fr = lane & 15;
  const int fq = lane >> 4;
  const f16* A = EH + (size_t)e * 128 * HID + kc * 384;
  const f16* B = W2 + (size_t)e * EMB * HID + kc * 384;

  f32x4 acc[4][2];
#pragma unroll
  for (int i = 0; i < 4; i++)
#pragma unroll
    for (int j = 0; j < 2; j++) acc[i][j] = f32x4{0.f, 0.f, 0.f, 0.f};

  const int sr = lane >> 2;
  const int sc = (lane & 3) * 8;
  const f16* ag = A + (size_t)(wave * 32 + sr) * HID + sc;
  const f16* bg = B + (size_t)(n0 + wave * 16 + sr) * HID + sc;
  const size_t rstep = (size_t)16 * HID;
  f16* la = As + wave * 32 * 32;
  f16* lb = Bs + wave * 16 * 32;

  for (int k0 = 0; k0 < 384; k0 += 32) {
    gload16(ag, la);  gload16(ag + rstep, la + 16 * 32);
    gload16(bg, lb);
    ag += 32; bg += 32;
    __syncthreads();
    f16x8 af[4], bf[2];
#pragma unroll
    for (int i = 0; i < 4; i++)
      af[i] = *(const f16x8*)&As[(wm + i * 16 + fr) * 32 + fq * 8];
#pragma unroll
    for (int j = 0; j < 2; j++)
      bf[j] = *(const f16x8*)&Bs[(wn + j * 16 + fr) * 32 + fq * 8];
#pragma unroll
    for (int i = 0; i < 4; i++)
#pragma unroll
      for (int j = 0; j < 2; j++)
        acc[i][j] = __builtin_amdgcn_mfma_f32_16x16x32_f16(af[i], bf[j], acc[i][j], 0, 0, 0);
    __syncthreads();
  }

#pragma unroll
  for (int i = 0; i < 4; i++)
#pragma unroll
    for (int j = 0; j < 2; j++)
#pragma unroll
      for (int rg = 0; rg < 4; rg++) {
        int gm = wm + i * 16 + fq * 4 + rg;
        int gn = n0 + wn + j * 16 + fr;
        part[(((size_t)kc * 4 + e) * 128 + gm) * EMB + gn] = acc[i][j][rg];
      }
}

// ---------------- combine split-K + experts + LN2 -> f16 ----------------
__global__ __launch_bounds__(384) void combine_ln2_k(
    const float* __restrict__ part, const float* __restrict__ eb2,
    const float* __restrict__ maskw,
    const float* __restrict__ g, const float* __restrict__ bb,
    f16* __restrict__ hfin) {
  __shared__ float red[16];
  int b = blockIdx.x, t = threadIdx.x;
  int lane = t & 63, wave = t >> 6;
  float v = 0.f;
#pragma unroll
  for (int e = 0; e < 4; e++) {
    float s = eb2[e * EMB + t];
#pragma unroll
    for (int kc = 0; kc < 4; kc++)
      s += part[(((size_t)kc * 4 + e) * 128 + b) * EMB + t];
    v += maskw[b * 4 + e] * s;
  }
  float s = v, sq = v * v;
#pragma unroll
  for (int off = 32; off; off >>= 1) {
    s += __shfl_xor(s, off);
    sq += __shfl_xor(sq, off);
  }
  if (lane == 0) { red[wave] = s; red[8 + wave] = sq; }
  __syncthreads();
  float S = 0.f, SQ = 0.f;
#pragma unroll
  for (int i = 0; i < 6; i++) { S += red[i]; SQ += red[8 + i]; }
  float m = S * (1.f / 384.f);
  float rs = rsqrtf(SQ * (1.f / 384.f) - m * m + 1e-5f);
  hfin[(size_t)b * EMB + t] = (f16)((v - m) * rs * g[t] + bb[t]);
}

// ---------------- head GEMM ----------------
__global__ __launch_bounds__(256) void head_gemm_k(
    const f16* __restrict__ A, const f16* __restrict__ B,
    const float* __restrict__ hb, float* __restrict__ outp) {
  __shared__ f16 As[128 * 32];
  __shared__ f16 Bs[128 * 32];
  const int K = 384;
  const int tid = threadIdx.x;
  const int lane = tid & 63;
  const int wave = tid >> 6;
  const int n0 = (int)blockIdx.x * 128;
  const int wm = (wave >> 1) * 64;
  const int wn = (wave & 1) * 64;
  const int fr = lane & 15;
  const int fq = lane >> 4;

  f32x4 acc[4][4];
#pragma unroll
  for (int i = 0; i < 4; i++)
#pragma unroll
    for (int j = 0; j < 4; j++) acc[i][j] = f32x4{0.f, 0.f, 0.f, 0.f};

  const int srow = wave * 32 + (lane >> 2);
  const int scol = (lane & 3) * 8;
  const f16* ag = A + (size_t)srow * K + scol;
  const f16* bg = B + (size_t)(n0 + srow) * K + scol;
  const size_t rstep = (size_t)16 * K;
  f16* la = As + wave * 32 * 32;
  f16* lb = Bs + wave * 32 * 32;

  for (int k0 = 0; k0 < K; k0 += 32) {
    gload16(ag, la);          gload16(ag + rstep, la + 16 * 32);
    gload16(bg, lb);          gload16(bg + rstep, lb + 16 * 32);
    ag += 32; bg += 32;
    __syncthreads();
    f16x8 af[4], bf[4];
#pragma unroll
    for (int i = 0; i < 4; i++) {
      af[i] = *(const f16x8*)&As[(wm + i * 16 + fr) * 32 + fq * 8];
      bf[i] = *(const f16x8*)&Bs[(wn + i * 16 + fr) * 32 + fq * 8];
    }
#pragma unroll
    for (int i = 0; i < 4; i++)
#pragma unroll
      for (int j = 0; j < 4; j++)
        acc[i][j] = __builtin_amdgcn_mfma_f32_16x16x32_f16(af[i], bf[j], acc[i][j], 0, 0, 0);
    __syncthreads();
  }

#pragma unroll
  for (int i = 0; i < 4; i++)
#pragma unroll
    for (int j = 0; j < 4; j++)
#pragma unroll
      for (int rg = 0; rg < 4; rg++) {
        int gm = wm + i * 16 + fq * 4 + rg;
        int gn = n0 + wn + j * 16 + fr;
        if (gn < 1000)
          outp[(size_t)gm * 1000 + gn] = acc[i][j][rg] + hb[gn];
      }
}

// ---------------- host ----------------
extern "C" void kernel_launch(void* const* d_in, const int* in_sizes, int n_in,
                              void* d_out, int out_size, void* d_ws, size_t ws_size,
                              hipStream_t stream) {
  const float* x      = (const float*)d_in[0];
  const float* conv_w = (const float*)d_in[1];
  const float* conv_b = (const float*)d_in[2];
  const float* cls_t  = (const float*)d_in[3];
  const float* pos    = (const float*)d_in[4];
  const float* ln1_g  = (const float*)d_in[5];
  const float* ln1_b  = (const float*)d_in[6];
  const float* inp_w  = (const float*)d_in[7];
  const float* inp_b  = (const float*)d_in[8];
  const float* outp_w = (const float*)d_in[9];
  const float* outp_b = (const float*)d_in[10];
  const float* rt_w   = (const float*)d_in[11];
  const float* rt_b   = (const float*)d_in[12];
  const float* ew1    = (const float*)d_in[13];
  const float* eb1    = (const float*)d_in[14];
  const float* ew2    = (const float*)d_in[15];
  const float* eb2    = (const float*)d_in[16];
  const float* ln2_g  = (const float*)d_in[17];
  const float* ln2_b  = (const float*)d_in[18];
  const float* head_w = (const float*)d_in[19];
  const float* head_b = (const float*)d_in[20];
  float* out = (float*)d_out;
  char* w = (char*)d_ws;
  if (ws_size < WS_NEEDED) return;

  f16* convw    = (f16*)(w + OFF_CONVW);
  f16* kvw      = (f16*)(w + OFF_KVW);
  f16* ew1t     = (f16*)(w + OFF_EW1T);
  f16* ew2t     = (f16*)(w + OFF_EW2T);
  f16* headw16  = (f16*)(w + OFF_HEADW16);
  f16* xcls16   = (f16*)(w + OFF_XCLS16);
  float* qvec   = (float*)(w + OFF_Q);
  float* ocls   = (float*)(w + OFF_OCLS);
  float* o2cls  = (float*)(w + OFF_O2CLS);
  f16* hcls16   = (f16*)(w + OFF_HCLS16);
  float* maskw  = (float*)(w + OFF_MASKW);
  f16* ehbuf    = (f16*)(w + OFF_EH);
  float* epart  = (float*)(w + OFF_EPART);
  f16* hfin     = (f16*)(w + OFF_HFIN);
  f16* xh       = (f16*)(w + OFF_XH);
  f16* kvbuf    = (f16*)(w + OFF_KV);
  f16* aim      = (f16*)(w + OFF_AIM);

  // ---- weight prep ----
  cast_f16_k<<<dim3((294912 + 255) / 256), 256, 0, stream>>>(conv_w, convw, 294912);
  cast_f16_k<<<dim3((294912 + 255) / 256), 256, 0, stream>>>(inp_w + 384 * 384, kvw, 294912);
  cast_pad_k<<<dim3((1024 * 384 + 255) / 256), 256, 0, stream>>>(head_w, headw16);
  transpose_cast_k<<<dim3(48, 12, 4), 256, 0, stream>>>(ew1, ew1t, 384, 1536);
  transpose_cast_k<<<dim3(12, 48, 4), 256, 0, stream>>>(ew2, ew2t, 1536, 384);

  // ---- cls precompute + broadcast ----
  clsprep_k<<<dim3(1), 384, 0, stream>>>(cls_t, pos, ln1_g, ln1_b, inp_w, inp_b, xcls16, qvec);
  bcast_cls_k<<<dim3(128), 384, 0, stream>>>(xcls16, xh);

  // ---- im2col + fused embed GEMM + LN1 -> xh patch rows ----
  im2col_k<<<dim3(14, 3, 128), 256, 0, stream>>>(x, aim);
  embed_ln_k<<<dim3(392), 1024, 0, stream>>>(aim, convw, conv_b, pos, ln1_g, ln1_b, xh);

  // ---- K,V projection (f16 out) ----
  gemm_kv_k<<<dim3(12, 197), 256, 0, stream>>>(xh, kvw, inp_b + 384, kvbuf);

  // ---- cls attention ----
  attn_cls_k<<<dim3(6, 128), 256, 0, stream>>>(qvec, kvbuf, ocls);

  // ---- out-proj (exact f32) ----
  rowproj_k<<<dim3(128), 384, 0, stream>>>(ocls, outp_w, outp_b, o2cls);

  // ---- LN (ln1 params) + router top-2 ----
  ln_router_k<<<dim3(128), 384, 0, stream>>>(
      o2cls, ln1_g, ln1_b, rt_w, rt_b, hcls16, maskw);

  // ---- MoE ----
  moe1_k<<<dim3(24, 4), 256, 0, stream>>>(hcls16, ew1t, eb1, ehbuf);
  moe2_k<<<dim3(6, 4, 4), 256, 0, stream>>>(ehbuf, ew2t, epart);
  combine_ln2_k<<<dim3(128), 384, 0, stream>>>(epart, eb2, maskw, ln2_g, ln2_b, hfin);

  // ---- head ----
  head_gemm_k<<<dim3(8), 256, 0, stream>>>(hfin, headw16, head_b, out);
  (void)in_sizes; (void)n_in; (void)out_size;
}